// Round 10
// baseline (662.380 us; speedup 1.0000x reference)
//
#include <hip/hip_runtime.h>
#include <math.h>

#define B_ 16
#define N_ 1024
#define KNN 20
#define NPAIR (B_*N_)

typedef __attribute__((ext_vector_type(8))) short bf16x8;
typedef __attribute__((ext_vector_type(4))) float f32x4;

// ---------- helpers ----------
__device__ __forceinline__ unsigned fkey(float f) {
  unsigned u = __float_as_uint(f);
  return (u & 0x80000000u) ? ~u : (u | 0x80000000u);
}
__device__ __forceinline__ float fkeyinv(unsigned u) {
  unsigned b = (u & 0x80000000u) ? (u ^ 0x80000000u) : ~u;
  return __uint_as_float(b);
}
__device__ __forceinline__ unsigned short f2bf(float x) {  // RNE float->bf16
  unsigned u = __float_as_uint(x);
  unsigned r = (u + 0x7FFFu + ((u >> 16) & 1u)) >> 16;
  return (unsigned short)r;
}
__device__ __forceinline__ float bf2f(unsigned short u) {
  return __uint_as_float(((unsigned)u) << 16);
}

// Branchless (cndmask-chain) insertion into a descending sorted top-20.
__device__ __forceinline__ void topk_insert(float (&pdl)[KNN], int (&idl)[KNN], float d, int j) {
  pdl[KNN-1] = d; idl[KNN-1] = j;
  #pragma unroll
  for (int i = KNN-1; i > 0; i--) {
    float a = pdl[i-1], bv = pdl[i];
    int ai = idl[i-1], bi = idl[i];
    bool sw = bv > a;
    pdl[i-1] = sw ? bv : a;   pdl[i] = sw ? a  : bv;
    idl[i-1] = sw ? bi : ai;  idl[i] = sw ? ai : bi;
  }
}

// ---------- 1) prep: e2p of raw points + weight bf16 conversions ----------
__global__ void k_prep(const float* __restrict__ x, float* __restrict__ xp1,
                       const float* __restrict__ w2, const float* __restrict__ w3,
                       unsigned short* __restrict__ w2h, unsigned short* __restrict__ wt3h) {
  int i = blockIdx.x * 256 + threadIdx.x;
  if (i < NPAIR) {
    float a0 = x[i*3+0], a1 = x[i*3+1], a2 = x[i*3+2];
    float n = sqrtf(a0*a0 + a1*a1 + a2*a2);
    n = fmaxf(n, 1e-15f);
    float th = tanhf(0.1f * n);
    float sc = th / (0.1f * n);
    float ny = fmaxf(th * 10.0f, 1e-15f);
    float mxn = (1.0f - 4e-3f) / 0.1f;
    if (ny > mxn) sc *= mxn / ny;
    xp1[i*3+0] = sc*a0; xp1[i*3+1] = sc*a1; xp1[i*3+2] = sc*a2;
  }
  if (i < 192*128) w2h[i] = f2bf(w2[i]);
  wt3h[i] = f2bf(w3[i]);   // grid 1024*256 == 262144 == |w3|
}

// ---------- 2) knn on raw 3-d points: 8-way candidate split ----------
__global__ void __launch_bounds__(256) k_knn1_part(const float* __restrict__ x,
        float* __restrict__ pdpart, int* __restrict__ idxpart) {
  __shared__ float P[N_*3];
  __shared__ float XX[N_];
  int blk = blockIdx.x;
  int b = blk >> 5, rc = (blk >> 3) & 3, cc = blk & 7;
  const float* xb = x + b*N_*3;
  for (int e = threadIdx.x; e < N_*3; e += 256) P[e] = xb[e];
  __syncthreads();
  for (int j = threadIdx.x; j < N_; j += 256) {
    float q0 = P[j*3], q1 = P[j*3+1], q2 = P[j*3+2];
    XX[j] = q0*q0 + q1*q1 + q2*q2;
  }
  __syncthreads();
  int r = rc*256 + threadIdx.x;
  float q0 = P[r*3], q1 = P[r*3+1], q2 = P[r*3+2];
  float xxq = XX[r];
  float pdl[KNN]; int idl[KNN];
  #pragma unroll
  for (int i = 0; i < KNN; i++) { pdl[i] = -__builtin_inff(); idl[i] = 0; }
  int cbase = cc*128;
  for (int jj = 0; jj < 128; jj++) {
    int j = cbase + jj;
    float dot = q0*P[j*3] + q1*P[j*3+1] + q2*P[j*3+2];
    float d = 2.0f*dot - xxq - XX[j];
    if (d > pdl[KNN-1]) topk_insert(pdl, idl, d, j);
  }
  int p = b*N_ + r;
  float* pe = pdpart + (size_t)p*160 + cc*20;
  int* ie = idxpart + (size_t)p*160 + cc*20;
  #pragma unroll
  for (int i = 0; i < KNN; i++) { pe[i] = pdl[i]; ie[i] = idl[i]; }
}

// ---------- 3) conv1 fused ----------
__global__ void __launch_bounds__(256) k_conv1(const float* __restrict__ xp1, const int* __restrict__ idx1,
                        const float* __restrict__ w1, float* __restrict__ hmax1,
                        float* __restrict__ hmin1, double* __restrict__ stats1sh) {
  __shared__ float F[4][KNN][6];
  __shared__ float red[4][64][2];
  int g = threadIdx.x >> 6, lane = threadIdx.x & 63;
  float w[6];
  #pragma unroll
  for (int c = 0; c < 6; c++) w[c] = w1[lane*6 + c];
  float sum = 0.f, sumsq = 0.f;
  int pbase = blockIdx.x * 16;
  for (int it = 0; it < 4; ++it) {
    int p = pbase + it*4 + g;
    if (lane < KNN) {
      int nb = idx1[p*KNN + lane];
      int bb = p >> 10;
      const float* xc = xp1 + p*3;
      const float* ft = xp1 + (bb*N_ + nb)*3;
      float x0 = ft[0], x1 = ft[1], x2v = ft[2];
      float c0 = xc[0], c1 = xc[1], c2 = xc[2];
      float X2 = x0*x0 + x1*x1 + x2v*x2v;
      float Y2 = c0*c0 + c1*c1 + c2*c2;
      float XY = -(x0*c0 + x1*c1 + x2v*c2);
      float den = fmaxf(1.0f + 0.02f*XY + 1e-4f*X2*Y2, 1e-15f);
      float s1 = (1.0f + 0.02f*XY + 0.01f*Y2) / den;
      float s2 = (1.0f - 0.01f*X2) / den;
      F[g][lane][0] = s1*x0 - s2*c0;
      F[g][lane][1] = s1*x1 - s2*c1;
      F[g][lane][2] = s1*x2v - s2*c2;
      F[g][lane][3] = c0; F[g][lane][4] = c1; F[g][lane][5] = c2;
    }
    __syncthreads();
    float mx = -__builtin_inff(), mn = __builtin_inff();
    for (int k = 0; k < KNN; k++) {
      float h = 0.f;
      #pragma unroll
      for (int c = 0; c < 6; c++) h = fmaf(w[c], F[g][k][c], h);
      mx = fmaxf(mx, h); mn = fminf(mn, h);
      sum += h; sumsq += h*h;
    }
    hmax1[p*64 + lane] = mx;
    hmin1[p*64 + lane] = mn;
    __syncthreads();
  }
  red[g][lane][0] = sum; red[g][lane][1] = sumsq;
  __syncthreads();
  if (g == 0) {
    float s  = red[0][lane][0] + red[1][lane][0] + red[2][lane][0] + red[3][lane][0];
    float s2 = red[0][lane][1] + red[1][lane][1] + red[2][lane][1] + red[3][lane][1];
    double* dst = stats1sh + ((size_t)(blockIdx.x & 63)*64 + lane)*2;
    atomicAdd(dst, (double)s);
    atomicAdd(dst + 1, (double)s2);
  }
}

// ---------- BN stat reduce ----------
__global__ void k_bn_reduce(const double* __restrict__ sh, int nsh, int nch, double cnt,
                            const float* __restrict__ g, const float* __restrict__ bb,
                            float* __restrict__ scale, float* __restrict__ shift) {
  int o = blockIdx.x * blockDim.x + threadIdx.x;
  if (o >= nch) return;
  double s = 0.0, s2 = 0.0;
  for (int i = 0; i < nsh; i++) {
    s  += sh[((size_t)i*nch + o)*2];
    s2 += sh[((size_t)i*nch + o)*2 + 1];
  }
  double m = s / cnt;
  double v = s2 / cnt - m*m;
  float a = g[o] / sqrtf((float)v + 1e-5f);
  scale[o] = a;
  shift[o] = bb[o] - a * (float)m;
}

// ---------- 5) BN1 apply + relu + e2p + coalesced x1T transpose + |x1|^2 ----------
__global__ void __launch_bounds__(256) k_bn1_apply(const float* __restrict__ hmax1, const float* __restrict__ hmin1,
                            const float* __restrict__ scale1, const float* __restrict__ shift1,
                            float* __restrict__ xp2,
                            float* __restrict__ x1T, float* __restrict__ xx1) {
  int b = blockIdx.x >> 4, nc = blockIdx.x & 15;
  int c = threadIdx.x & 63, sub = threadIdx.x >> 6;
  int n0 = nc*64 + sub*16;
  float a = scale1[c], t = shift1[c];
  float xr[16];
  #pragma unroll
  for (int i = 0; i < 16; i++) {
    int p = b*1024 + n0 + i;
    float h = (a >= 0.f) ? hmax1[(size_t)p*64 + c] : hmin1[(size_t)p*64 + c];
    float x1 = fmaxf(fmaf(a, h, t), 0.f);
    xr[i] = x1;
    float n2 = x1*x1;
    #pragma unroll
    for (int off = 32; off > 0; off >>= 1) n2 += __shfl_xor(n2, off);
    if (c == 0) xx1[p] = n2;
    float n1 = fmaxf(sqrtf(n2), 1e-15f);
    float th = tanhf(0.1f * n1);
    float sc = th / (0.1f * n1);
    float ny = fmaxf(th * 10.0f, 1e-15f);
    float mxn = (1.0f - 4e-3f) / 0.1f;
    if (ny > mxn) sc *= mxn / ny;
    xp2[(size_t)p*64 + c] = sc * x1;
  }
  float* dst = x1T + ((size_t)(b*64 + c))*1024 + n0;
  #pragma unroll
  for (int q = 0; q < 4; q++) {
    float4 v; v.x = xr[q*4]; v.y = xr[q*4+1]; v.z = xr[q*4+2]; v.w = xr[q*4+3];
    *((float4*)(dst + q*4)) = v;
  }
}

// ---------- 6) knn2 v4: 8-way candidate split (2048 blocks), all-wave selection, in-block merge ----------
__global__ void __launch_bounds__(256) k_knn2g(const float* __restrict__ x1T,
        const float* __restrict__ xx1,
        float* __restrict__ pdpart, int* __restrict__ idxpart) {
  __shared__ __align__(16) float SM[8448];   // As @0 (64x68), BsD @4352 (64x64)
  float* As = SM;
  float* BsD = SM + 4352;
  int tid = threadIdx.x;
  int blk = blockIdx.x;
  int b = blk >> 7, qc = (blk >> 3) & 15, cc = blk & 7;
  int qbase = qc*64, ccbase = cc*128;
  int tx = tid & 15, ty = tid >> 4;
  int wave = tid >> 6, lane = tid & 63;
  #pragma unroll
  for (int r = 0; r < 4; r++) {
    int e = tid + r*256;
    int k = e >> 4, qf = e & 15;
    *((float4*)(As + k*68 + qf*4)) =
      *((const float4*)(x1T + ((size_t)(b*64 + k))*1024 + qbase + qf*4));
  }
  float pdl[KNN]; int idl[KNN];
  #pragma unroll
  for (int i = 0; i < KNN; i++) { pdl[i] = -__builtin_inff(); idl[i] = 0; }
  int cq = lane + (lane >> 2);

  for (int st = 0; st < 2; ++st) {
    int cb0 = ccbase + st*64;
    __syncthreads();
    #pragma unroll
    for (int r = 0; r < 4; r++) {
      int e = tid + r*256;
      int k = e >> 4, cf = e & 15;
      *((float4*)(BsD + k*64 + cf*4)) =
        *((const float4*)(x1T + ((size_t)(b*64 + k))*1024 + cb0 + cf*4));
    }
    float4 xxc = *((const float4*)(xx1 + b*1024 + cb0 + ty*4));
    __syncthreads();
    float acc[4][4];
    #pragma unroll
    for (int i = 0; i < 4; i++)
      #pragma unroll
      for (int j = 0; j < 4; j++) acc[i][j] = 0.f;
    #pragma unroll 4
    for (int k = 0; k < 64; k++) {
      float4 a4 = *((const float4*)(As + k*68 + tx*4));
      float4 b4 = *((const float4*)(BsD + k*64 + ty*4));
      float av[4] = {a4.x, a4.y, a4.z, a4.w};
      float bw[4] = {b4.x, b4.y, b4.z, b4.w};
      #pragma unroll
      for (int i = 0; i < 4; i++)
        #pragma unroll
        for (int j = 0; j < 4; j++) acc[i][j] = fmaf(av[i], bw[j], acc[i][j]);
    }
    __syncthreads();
    float xxv[4] = {xxc.x, xxc.y, xxc.z, xxc.w};
    #pragma unroll
    for (int i = 0; i < 4; i++) {
      int q = tx*4 + i;
      #pragma unroll
      for (int j = 0; j < 4; j++) {
        int c = ty*4 + j;
        BsD[q*64 + ((c + q + (q >> 2)) & 63)] = 2.0f*acc[i][j] - xxv[j];
      }
    }
    __syncthreads();
    #pragma unroll
    for (int j = 0; j < 16; j++) {
      int c = wave*16 + j;
      float d = BsD[lane*64 + ((c + cq) & 63)];
      if (d > pdl[KNN-1]) topk_insert(pdl, idl, d, cb0 + c);
    }
  }
  __syncthreads();
  // block merge: 4 wave-partials -> exact top-20 of this cc chunk
  float* L0pd = SM;            int* L0id = (int*)(SM + 1344);
  float* L1pd = SM + 2688;     int* L1id = (int*)(SM + 4032);
  float* Mpd  = SM + 5376;     int* Mid  = (int*)(SM + 6720);
  if (wave == 0) {
    #pragma unroll
    for (int i = 0; i < KNN; i++) { L0pd[lane*21 + i] = pdl[i]; L0id[lane*21 + i] = idl[i]; }
  } else if (wave == 1) {
    #pragma unroll
    for (int i = 0; i < KNN; i++) { L1pd[lane*21 + i] = pdl[i]; L1id[lane*21 + i] = idl[i]; }
  }
  __syncthreads();
  if (tid < 64) {
    int ia = 0, ib = 0;
    for (int t = 0; t < KNN; t++) {
      float pa = L0pd[tid*21 + ia], pb = L1pd[tid*21 + ib];
      int xa = L0id[tid*21 + ia], xb = L1id[tid*21 + ib];
      bool ta = (pa > pb) || (pa == pb && xa < xb);
      Mpd[tid*21 + t] = ta ? pa : pb;
      Mid[tid*21 + t] = ta ? xa : xb;
      if (ta) ia++; else ib++;
    }
  }
  __syncthreads();
  if (wave == 2) {
    #pragma unroll
    for (int i = 0; i < KNN; i++) { L0pd[lane*21 + i] = pdl[i]; L0id[lane*21 + i] = idl[i]; }
  } else if (wave == 3) {
    #pragma unroll
    for (int i = 0; i < KNN; i++) { L1pd[lane*21 + i] = pdl[i]; L1id[lane*21 + i] = idl[i]; }
  }
  __syncthreads();
  if (tid < 64) {
    int p = b*N_ + qbase + tid;
    float* pe = pdpart + (size_t)p*160 + cc*20;
    int* ie = idxpart + (size_t)p*160 + cc*20;
    int ia = 0, ib = 0, im = 0;
    for (int t = 0; t < KNN; t++) {
      float pa = L0pd[tid*21 + ia], pb = L1pd[tid*21 + ib], pm = Mpd[tid*21 + im];
      int xa = L0id[tid*21 + ia], xb = L1id[tid*21 + ib], xm = Mid[tid*21 + im];
      float bp = pm; int bx = xm; int sel = 2;
      if (pa > bp || (pa == bp && xa < bx)) { bp = pa; bx = xa; sel = 0; }
      if (pb > bp || (pb == bp && xb < bx)) { bp = pb; bx = xb; sel = 1; }
      pe[t] = bp; ie[t] = bx;
      if (sel == 0) ia++; else if (sel == 1) ib++; else im++;
    }
  }
}

// ---------- 7) generic merge of NCH sorted top-20 chunks ----------
template<int NCH>
__global__ void k_knn_merge(const float* __restrict__ pdpart, const int* __restrict__ idxpart,
                            int* __restrict__ idxo) {
  int p = blockIdx.x*blockDim.x + threadIdx.x;
  if (p >= NPAIR) return;
  const float* pe = pdpart + (size_t)p*(NCH*20);
  const int* ie = idxpart + (size_t)p*(NCH*20);
  int pos[NCH];
  #pragma unroll
  for (int c = 0; c < NCH; c++) pos[c] = 0;
  int* outp = idxo + p*KNN;
  for (int t = 0; t < KNN; t++) {
    float best = -__builtin_inff(); int bi = 0x7FFFFFFF; int bc = 0;
    #pragma unroll
    for (int c = 0; c < NCH; c++) {
      if (pos[c] < KNN) {
        float pv = pe[c*20 + pos[c]]; int iv = ie[c*20 + pos[c]];
        if (pv > best || (pv == best && iv < bi)) { best = pv; bi = iv; bc = c; }
      }
    }
    outp[t] = bi;
    #pragma unroll
    for (int c = 0; c < NCH; c++) if (bc == c) pos[c]++;
  }
}

// ---------- 9) conv2 via bf16 MFMA (unchanged from R9) ----------
__global__ void __launch_bounds__(256) k_conv2m(const float* __restrict__ xp2,
    const int* __restrict__ idx2, const unsigned short* __restrict__ w2h,
    float* __restrict__ hmax2, float* __restrict__ hmin2, double* __restrict__ stats2sh) {
  __shared__ __align__(16) short Abf[80*136];
  __shared__ float s1s[80], s2s[80];
  __shared__ int nbr[80];
  int tid = threadIdx.x;
  int p0 = blockIdx.x * 4;
  int b = p0 >> 10;
  if (tid < 80) nbr[tid] = idx2[p0*KNN + tid];
  __syncthreads();
  for (int e = tid; e < 80*16; e += 256) {
    int r = e >> 4, qq = e & 15;
    float4 f = *((const float4*)(xp2 + (size_t)(b*N_ + nbr[r])*64) + qq);
    float4 cv = *((const float4*)(xp2 + (size_t)(p0 + r/20)*64) + qq);
    ushort4 fb, cb;
    fb.x = f2bf(f.x); fb.y = f2bf(f.y); fb.z = f2bf(f.z); fb.w = f2bf(f.w);
    cb.x = f2bf(cv.x); cb.y = f2bf(cv.y); cb.z = f2bf(cv.z); cb.w = f2bf(cv.w);
    *((ushort4*)(Abf + r*136 + qq*4)) = fb;
    *((ushort4*)(Abf + r*136 + 64 + qq*4)) = cb;
  }
  __syncthreads();
  if (tid < 160) {
    int r = tid >> 1, h = tid & 1;
    const unsigned short* Ar = (const unsigned short*)(Abf + r*136) + h*32;
    const unsigned short* Xr = (const unsigned short*)(Abf + r*136 + 64) + h*32;
    float X2 = 0.f, XY = 0.f, Y2 = 0.f;
    for (int c2 = 0; c2 < 32; c2++) {
      float f = bf2f(Ar[c2]), xcv = bf2f(Xr[c2]);
      X2 = fmaf(f, f, X2); XY = fmaf(-f, xcv, XY); Y2 = fmaf(xcv, xcv, Y2);
    }
    X2 += __shfl_xor(X2, 1); XY += __shfl_xor(XY, 1); Y2 += __shfl_xor(Y2, 1);
    if (h == 0) {
      float den = fmaxf(1.0f + 0.02f*XY + 1e-4f*X2*Y2, 1e-15f);
      s1s[r] = (1.0f + 0.02f*XY + 0.01f*Y2) / den;
      s2s[r] = (1.0f - 0.01f*X2) / den;
    }
  }
  __syncthreads();
  for (int e = tid; e < 80*16; e += 256) {
    int r = e >> 4, qq = e & 15;
    ushort4 fr = *((const ushort4*)(Abf + r*136 + qq*4));
    ushort4 xr4 = *((const ushort4*)(Abf + r*136 + 64 + qq*4));
    float s1 = s1s[r], s2 = s2s[r];
    ushort4 mo;
    mo.x = f2bf(s1*bf2f(fr.x) - s2*bf2f(xr4.x));
    mo.y = f2bf(s1*bf2f(fr.y) - s2*bf2f(xr4.y));
    mo.z = f2bf(s1*bf2f(fr.z) - s2*bf2f(xr4.z));
    mo.w = f2bf(s1*bf2f(fr.w) - s2*bf2f(xr4.w));
    *((ushort4*)(Abf + r*136 + qq*4)) = mo;
  }
  __syncthreads();
  int wave = tid >> 6, lane = tid & 63;
  int quad = lane >> 4, lm = lane & 15;
  int colbase = wave*48;
  f32x4 acc[5][3];
  #pragma unroll
  for (int rt = 0; rt < 5; rt++)
    #pragma unroll
    for (int cj = 0; cj < 3; cj++) acc[rt][cj] = (f32x4){0.f, 0.f, 0.f, 0.f};
  #pragma unroll
  for (int kt = 0; kt < 4; kt++) {
    int k0 = kt*32 + quad*8;
    bf16x8 bf[3];
    #pragma unroll
    for (int cj = 0; cj < 3; cj++)
      bf[cj] = *((const bf16x8*)(w2h + (size_t)(colbase + cj*16 + lm)*128 + k0));
    bf16x8 af[5];
    #pragma unroll
    for (int rt = 0; rt < 5; rt++)
      af[rt] = *((const bf16x8*)(Abf + (rt*16 + lm)*136 + k0));
    #pragma unroll
    for (int rt = 0; rt < 5; rt++)
      #pragma unroll
      for (int cj = 0; cj < 3; cj++)
        acc[rt][cj] = __builtin_amdgcn_mfma_f32_16x16x32_bf16(af[rt], bf[cj], acc[rt][cj], 0, 0, 0);
  }
  float* Df = (float*)Abf;
  for (int cj = 0; cj < 3; cj++) {
    __syncthreads();
    #pragma unroll
    for (int rt = 0; rt < 5; rt++) {
      #pragma unroll
      for (int reg = 0; reg < 4; reg++) {
        int row = rt*16 + quad*4 + reg;
        Df[row*68 + wave*16 + lm] = acc[rt][cj][reg];
      }
    }
    __syncthreads();
    if (tid < 64) {
      int o = (tid >> 4)*48 + cj*16 + (tid & 15);
      float s = 0.f, s2 = 0.f;
      float mx[4], mn[4];
      #pragma unroll
      for (int g = 0; g < 4; g++) { mx[g] = -__builtin_inff(); mn[g] = __builtin_inff(); }
      int r = 0;
      #pragma unroll
      for (int g = 0; g < 4; g++) {
        #pragma unroll
        for (int kk = 0; kk < KNN; kk++, r++) {
          float h = Df[r*68 + tid];
          s += h; s2 += h*h;
          mx[g] = fmaxf(mx[g], h); mn[g] = fminf(mn[g], h);
        }
      }
      double* dst = stats2sh + ((size_t)(blockIdx.x & 63)*192 + o)*2;
      atomicAdd(dst, (double)s); atomicAdd(dst + 1, (double)s2);
      #pragma unroll
      for (int g = 0; g < 4; g++) {
        hmax2[(size_t)(p0 + g)*192 + o] = mx[g];
        hmin2[(size_t)(p0 + g)*192 + o] = mn[g];
      }
    }
  }
}

// ---------- 11) conv3 via bf16 MFMA, v2: A-tile staged directly from BN1/BN2 max/min ----------
// Eliminates bn2_apply + feat3h entirely.
__global__ void __launch_bounds__(256) k_conv3m(
   const float* __restrict__ hmax1, const float* __restrict__ hmin1,
   const float* __restrict__ scale1, const float* __restrict__ shift1,
   const float* __restrict__ hmax2, const float* __restrict__ hmin2,
   const float* __restrict__ scale2, const float* __restrict__ shift2,
   const unsigned short* __restrict__ wt3h, double* __restrict__ stats3sh,
   unsigned* __restrict__ hmax3u, unsigned* __restrict__ hmin3u) {
  __shared__ short As[64*264];
  int tid = threadIdx.x;
  int mt = blockIdx.x >> 2, cb = blockIdx.x & 3;
  int rowbase = mt*64;
  int b = rowbase >> 10;
  int c4 = tid & 63;   // column-quad id: cols c4*4 .. c4*4+3
  float4 sc, sh;
  if (c4 < 16) {
    sc = *((const float4*)(scale1 + c4*4));
    sh = *((const float4*)(shift1 + c4*4));
  } else {
    sc = *((const float4*)(scale2 + (c4*4 - 64)));
    sh = *((const float4*)(shift2 + (c4*4 - 64)));
  }
  #pragma unroll 4
  for (int i = 0; i < 16; i++) {
    int r = (tid >> 6) + i*4;
    int p = rowbase + r;
    float4 hx, hn;
    if (c4 < 16) {
      hx = *((const float4*)(hmax1 + (size_t)p*64 + c4*4));
      hn = *((const float4*)(hmin1 + (size_t)p*64 + c4*4));
    } else {
      hx = *((const float4*)(hmax2 + (size_t)p*192 + (c4*4 - 64)));
      hn = *((const float4*)(hmin2 + (size_t)p*192 + (c4*4 - 64)));
    }
    ushort4 o4;
    o4.x = f2bf(fmaxf(fmaf(sc.x, (sc.x >= 0.f ? hx.x : hn.x), sh.x), 0.f));
    o4.y = f2bf(fmaxf(fmaf(sc.y, (sc.y >= 0.f ? hx.y : hn.y), sh.y), 0.f));
    o4.z = f2bf(fmaxf(fmaf(sc.z, (sc.z >= 0.f ? hx.z : hn.z), sh.z), 0.f));
    o4.w = f2bf(fmaxf(fmaf(sc.w, (sc.w >= 0.f ? hx.w : hn.w), sh.w), 0.f));
    *((ushort4*)(As + r*264 + c4*4)) = o4;
  }
  __syncthreads();
  int wave = tid >> 6, lane = tid & 63;
  int quad = lane >> 4, lm = lane & 15;
  int colbase = cb*256 + wave*64;
  f32x4 acc[4][4];
  #pragma unroll
  for (int ri = 0; ri < 4; ri++)
    #pragma unroll
    for (int cj = 0; cj < 4; cj++) acc[ri][cj] = (f32x4){0.f, 0.f, 0.f, 0.f};
  for (int kt = 0; kt < 8; kt++) {
    int k0 = kt*32 + quad*8;
    bf16x8 bf[4];
    #pragma unroll
    for (int cj = 0; cj < 4; cj++)
      bf[cj] = *((const bf16x8*)(wt3h + (size_t)(colbase + cj*16 + lm)*256 + k0));
    bf16x8 af[4];
    #pragma unroll
    for (int ri = 0; ri < 4; ri++)
      af[ri] = *((const bf16x8*)(As + (ri*16 + lm)*264 + k0));
    #pragma unroll
    for (int ri = 0; ri < 4; ri++)
      #pragma unroll
      for (int cj = 0; cj < 4; cj++)
        acc[ri][cj] = __builtin_amdgcn_mfma_f32_16x16x32_bf16(af[ri], bf[cj], acc[ri][cj], 0, 0, 0);
  }
  #pragma unroll
  for (int cj = 0; cj < 4; cj++) {
    float s = 0.f, s2 = 0.f, mx = -__builtin_inff(), mn = __builtin_inff();
    #pragma unroll
    for (int ri = 0; ri < 4; ri++) {
      #pragma unroll
      for (int reg = 0; reg < 4; reg++) {
        float h = acc[ri][cj][reg];
        s += h; s2 += h*h; mx = fmaxf(mx, h); mn = fminf(mn, h);
      }
    }
    s  += __shfl_xor(s, 16);  s  += __shfl_xor(s, 32);
    s2 += __shfl_xor(s2, 16); s2 += __shfl_xor(s2, 32);
    mx = fmaxf(mx, __shfl_xor(mx, 16)); mx = fmaxf(mx, __shfl_xor(mx, 32));
    mn = fminf(mn, __shfl_xor(mn, 16)); mn = fminf(mn, __shfl_xor(mn, 32));
    if (lane < 16) {
      int col = colbase + cj*16 + lane;
      double* dst = stats3sh + ((size_t)(blockIdx.x & 63)*1024 + col)*2;
      atomicAdd(dst, (double)s);
      atomicAdd(dst + 1, (double)s2);
      atomicMax(hmax3u + b*1024 + col, fkey(mx));
      atomicMin(hmin3u + b*1024 + col, fkey(mn));
    }
  }
}

// ---------- 12) head ----------
__device__ float blk_reduce(float v, float* red, int tid) {
  red[tid] = v; __syncthreads();
  for (int st = 128; st > 0; st >>= 1) {
    if (tid < st) red[tid] += red[tid + st];
    __syncthreads();
  }
  float r = red[0]; __syncthreads();
  return r;
}

__global__ void __launch_bounds__(256) k_head(const unsigned* __restrict__ hmax3u, const unsigned* __restrict__ hmin3u,
    const float* __restrict__ scale3, const float* __restrict__ shift3,
    const float* __restrict__ fc1w, const float* __restrict__ fc1b,
    const float* __restrict__ ln1g, const float* __restrict__ ln1b,
    const float* __restrict__ fc2w, const float* __restrict__ fc2b,
    const float* __restrict__ ln2g, const float* __restrict__ ln2b,
    const float* __restrict__ outw, const float* __restrict__ outb,
    float* __restrict__ out) {
  __shared__ __align__(16) float V[1024];
  __shared__ __align__(16) float H1[512];
  __shared__ __align__(16) float H2[256];
  __shared__ float red[256];
  int b = blockIdx.x, tid = threadIdx.x;
  for (int o = tid; o < 1024; o += 256) {
    float a = scale3[o];
    unsigned u = (a >= 0.f) ? hmax3u[b*1024 + o] : hmin3u[b*1024 + o];
    float h = fkeyinv(u);
    V[o] = fmaxf(fmaf(a, h, shift3[o]), 0.f);
  }
  __syncthreads();
  float h1v[2];
  #pragma unroll
  for (int ii = 0; ii < 2; ii++) {
    int o = tid + ii*256;
    const float4* wr = (const float4*)(fc1w + (size_t)o*1024);
    float s = 0.f;
    for (int c4 = 0; c4 < 256; c4++) {
      float4 w = wr[c4]; float4 vv = ((const float4*)V)[c4];
      s = fmaf(w.x, vv.x, s); s = fmaf(w.y, vv.y, s);
      s = fmaf(w.z, vv.z, s); s = fmaf(w.w, vv.w, s);
    }
    h1v[ii] = s + fc1b[o];
  }
  float s = h1v[0] + h1v[1];
  float s2 = h1v[0]*h1v[0] + h1v[1]*h1v[1];
  s = blk_reduce(s, red, tid);
  s2 = blk_reduce(s2, red, tid);
  float m = s / 512.f;
  float var = s2 / 512.f - m*m;
  float inv = 1.0f / sqrtf(var + 1e-5f);
  #pragma unroll
  for (int ii = 0; ii < 2; ii++) {
    int o = tid + ii*256;
    H1[o] = fmaxf((h1v[ii] - m)*inv*ln1g[o] + ln1b[o], 0.f);
  }
  __syncthreads();
  float h2v;
  {
    const float4* wr = (const float4*)(fc2w + (size_t)tid*512);
    float t = 0.f;
    for (int c4 = 0; c4 < 128; c4++) {
      float4 w = wr[c4]; float4 vv = ((const float4*)H1)[c4];
      t = fmaf(w.x, vv.x, t); t = fmaf(w.y, vv.y, t);
      t = fmaf(w.z, vv.z, t); t = fmaf(w.w, vv.w, t);
    }
    h2v = t + fc2b[tid];
  }
  float ss = blk_reduce(h2v, red, tid);
  float ss2 = blk_reduce(h2v*h2v, red, tid);
  float m2 = ss / 256.f;
  float var2 = ss2 / 256.f - m2*m2;
  float inv2 = 1.0f / sqrtf(var2 + 1e-5f);
  H2[tid] = fmaxf((h2v - m2)*inv2*ln2g[tid] + ln2b[tid], 0.f);
  __syncthreads();
  if (tid < 40) {
    const float4* wr = (const float4*)(outw + (size_t)tid*256);
    float t = 0.f;
    for (int c4 = 0; c4 < 64; c4++) {
      float4 w = wr[c4]; float4 vv = ((const float4*)H2)[c4];
      t = fmaf(w.x, vv.x, t); t = fmaf(w.y, vv.y, t);
      t = fmaf(w.z, vv.z, t); t = fmaf(w.w, vv.w, t);
    }
    red[tid] = t + outb[tid];
  }
  __syncthreads();
  if (tid == 0) {
    float mx = -__builtin_inff();
    for (int i2 = 0; i2 < 40; i2++) mx = fmaxf(mx, red[i2]);
    float se = 0.f;
    for (int i2 = 0; i2 < 40; i2++) se += expf(red[i2] - mx);
    float lse = mx + logf(se);
    for (int i2 = 0; i2 < 40; i2++) out[b*40 + i2] = red[i2] - lse;
  }
}

extern "C" void kernel_launch(void* const* d_in, const int* in_sizes, int n_in,
                              void* d_out, int out_size, void* d_ws, size_t ws_size,
                              hipStream_t stream) {
  (void)in_sizes; (void)n_in; (void)out_size; (void)ws_size;
  const float* x    = (const float*)d_in[0];
  const float* w1   = (const float*)d_in[1];
  const float* bn1g = (const float*)d_in[2];
  const float* bn1b = (const float*)d_in[3];
  const float* w2   = (const float*)d_in[4];
  const float* bn2g = (const float*)d_in[5];
  const float* bn2b = (const float*)d_in[6];
  const float* w3   = (const float*)d_in[7];
  const float* bn3g = (const float*)d_in[8];
  const float* bn3b = (const float*)d_in[9];
  const float* fc1w = (const float*)d_in[10];
  const float* fc1b = (const float*)d_in[11];
  const float* ln1g = (const float*)d_in[12];
  const float* ln1b = (const float*)d_in[13];
  const float* fc2w = (const float*)d_in[14];
  const float* fc2b = (const float*)d_in[15];
  const float* ln2g = (const float*)d_in[16];
  const float* ln2b = (const float*)d_in[17];
  const float* outw = (const float*)d_in[18];
  const float* outb = (const float*)d_in[19];
  float* out = (float*)d_out;

  float* ws = (float*)d_ws;
  size_t off = 0;
  float* xp1   = ws + off; off += 49152;
  int*   idx1  = (int*)(ws + off); off += 327680;
  float* hmax1 = ws + off; off += 1048576;
  float* hmin1 = ws + off; off += 1048576;
  float* xp2   = ws + off; off += 1048576;
  float* hmax2 = ws + off; off += 3145728;   // also pdpart (knn partials, <=160/query)
  float* hmin2 = ws + off; off += 3145728;   // also idxpart
  int*   idx2  = (int*)(ws + off); off += 327680;
  unsigned short* w2h = (unsigned short*)(ws + off); off += 24576;
  unsigned short* wt3h = (unsigned short*)(ws + off); off += 131072;
  float* x1T   = ws + off; off += 1048576;
  float* xx1   = ws + off; off += 16384;
  float* scale1 = ws + off; off += 64;
  float* shift1 = ws + off; off += 64;
  float* scale2 = ws + off; off += 192;
  float* shift2 = ws + off; off += 192;
  float* scale3 = ws + off; off += 1024;
  float* shift3 = ws + off; off += 1024;
  double* stats1sh = (double*)(ws + off);
  double* stats2sh = stats1sh + 64*64*2;
  double* stats3sh = stats2sh + 64*192*2;
  unsigned* hmax3u = (unsigned*)(stats3sh + (size_t)64*1024*2);
  unsigned* hmin3u = hmax3u + 16384;
  float* pdpart = hmax2;
  int*   idxpart = (int*)hmin2;

  size_t zero_bytes = ((size_t)64*64*2 + (size_t)64*192*2 + (size_t)64*1024*2)*8 + (size_t)16384*4;
  hipMemsetAsync(stats1sh, 0, zero_bytes, stream);
  hipMemsetAsync(hmin3u, 0xFF, (size_t)16384*4, stream);

  k_prep<<<1024, 256, 0, stream>>>(x, xp1, w2, w3, w2h, wt3h);
  k_knn1_part<<<512, 256, 0, stream>>>(x, pdpart, idxpart);
  k_knn_merge<8><<<256, 64, 0, stream>>>(pdpart, idxpart, idx1);
  k_conv1<<<1024, 256, 0, stream>>>(xp1, idx1, w1, hmax1, hmin1, stats1sh);
  k_bn_reduce<<<1, 64, 0, stream>>>(stats1sh, 64, 64, 327680.0, bn1g, bn1b, scale1, shift1);
  k_bn1_apply<<<256, 256, 0, stream>>>(hmax1, hmin1, scale1, shift1, xp2, x1T, xx1);
  k_knn2g<<<2048, 256, 0, stream>>>(x1T, xx1, pdpart, idxpart);
  k_knn_merge<8><<<256, 64, 0, stream>>>(pdpart, idxpart, idx2);
  k_conv2m<<<4096, 256, 0, stream>>>(xp2, idx2, w2h, hmax2, hmin2, stats2sh);
  k_bn_reduce<<<1, 192, 0, stream>>>(stats2sh, 64, 192, 327680.0, bn2g, bn2b, scale2, shift2);
  k_conv3m<<<1024, 256, 0, stream>>>(hmax1, hmin1, scale1, shift1, hmax2, hmin2, scale2, shift2,
                                     wt3h, stats3sh, hmax3u, hmin3u);
  k_bn_reduce<<<4, 256, 0, stream>>>(stats3sh, 64, 1024, 16384.0, bn3g, bn3b, scale3, shift3);
  k_head<<<16, 256, 0, stream>>>(hmax3u, hmin3u, scale3, shift3,
                                 fc1w, fc1b, ln1g, ln1b,
                                 fc2w, fc2b, ln2g, ln2b,
                                 outw, outb, out);
}

// Round 11
// 619.895 us; speedup vs baseline: 1.0685x; 1.0685x over previous
//
#include <hip/hip_runtime.h>
#include <math.h>

#define B_ 16
#define N_ 1024
#define KNN 20
#define NPAIR (B_*N_)

typedef __attribute__((ext_vector_type(8))) short bf16x8;
typedef __attribute__((ext_vector_type(4))) float f32x4;

// ---------- helpers ----------
__device__ __forceinline__ unsigned fkey(float f) {
  unsigned u = __float_as_uint(f);
  return (u & 0x80000000u) ? ~u : (u | 0x80000000u);
}
__device__ __forceinline__ float fkeyinv(unsigned u) {
  unsigned b = (u & 0x80000000u) ? (u ^ 0x80000000u) : ~u;
  return __uint_as_float(b);
}
__device__ __forceinline__ unsigned short f2bf(float x) {  // RNE float->bf16
  unsigned u = __float_as_uint(x);
  unsigned r = (u + 0x7FFFu + ((u >> 16) & 1u)) >> 16;
  return (unsigned short)r;
}
__device__ __forceinline__ float bf2f(unsigned short u) {
  return __uint_as_float(((unsigned)u) << 16);
}

// Branchless (cndmask-chain) insertion into a descending sorted top-20.
__device__ __forceinline__ void topk_insert(float (&pdl)[KNN], int (&idl)[KNN], float d, int j) {
  pdl[KNN-1] = d; idl[KNN-1] = j;
  #pragma unroll
  for (int i = KNN-1; i > 0; i--) {
    float a = pdl[i-1], bv = pdl[i];
    int ai = idl[i-1], bi = idl[i];
    bool sw = bv > a;
    pdl[i-1] = sw ? bv : a;   pdl[i] = sw ? a  : bv;
    idl[i-1] = sw ? bi : ai;  idl[i] = sw ? ai : bi;
  }
}

// ---------- 1) prep: e2p of raw points + weight bf16 conversions ----------
__global__ void k_prep(const float* __restrict__ x, float* __restrict__ xp1,
                       const float* __restrict__ w2, const float* __restrict__ w3,
                       unsigned short* __restrict__ w2h, unsigned short* __restrict__ wt3h) {
  int i = blockIdx.x * 256 + threadIdx.x;
  if (i < NPAIR) {
    float a0 = x[i*3+0], a1 = x[i*3+1], a2 = x[i*3+2];
    float n = sqrtf(a0*a0 + a1*a1 + a2*a2);
    n = fmaxf(n, 1e-15f);
    float th = tanhf(0.1f * n);
    float sc = th / (0.1f * n);
    float ny = fmaxf(th * 10.0f, 1e-15f);
    float mxn = (1.0f - 4e-3f) / 0.1f;
    if (ny > mxn) sc *= mxn / ny;
    xp1[i*3+0] = sc*a0; xp1[i*3+1] = sc*a1; xp1[i*3+2] = sc*a2;
  }
  if (i < 192*128) w2h[i] = f2bf(w2[i]);
  wt3h[i] = f2bf(w3[i]);
}

// ---------- 2) knn on raw 3-d points: 8-way candidate split ----------
__global__ void __launch_bounds__(256) k_knn1_part(const float* __restrict__ x,
        float* __restrict__ pdpart, int* __restrict__ idxpart) {
  __shared__ float P[N_*3];
  __shared__ float XX[N_];
  int blk = blockIdx.x;
  int b = blk >> 5, rc = (blk >> 3) & 3, cc = blk & 7;
  const float* xb = x + b*N_*3;
  for (int e = threadIdx.x; e < N_*3; e += 256) P[e] = xb[e];
  __syncthreads();
  for (int j = threadIdx.x; j < N_; j += 256) {
    float q0 = P[j*3], q1 = P[j*3+1], q2 = P[j*3+2];
    XX[j] = q0*q0 + q1*q1 + q2*q2;
  }
  __syncthreads();
  int r = rc*256 + threadIdx.x;
  float q0 = P[r*3], q1 = P[r*3+1], q2 = P[r*3+2];
  float xxq = XX[r];
  float pdl[KNN]; int idl[KNN];
  #pragma unroll
  for (int i = 0; i < KNN; i++) { pdl[i] = -__builtin_inff(); idl[i] = 0; }
  int cbase = cc*128;
  for (int jj = 0; jj < 128; jj++) {
    int j = cbase + jj;
    float dot = q0*P[j*3] + q1*P[j*3+1] + q2*P[j*3+2];
    float d = 2.0f*dot - xxq - XX[j];
    if (d > pdl[KNN-1]) topk_insert(pdl, idl, d, j);
  }
  int p = b*N_ + r;
  float* pe = pdpart + (size_t)p*160 + cc*20;
  int* ie = idxpart + (size_t)p*160 + cc*20;
  #pragma unroll
  for (int i = 0; i < KNN; i++) { pe[i] = pdl[i]; ie[i] = idl[i]; }
}

// ---------- 3) conv1 fused ----------
__global__ void __launch_bounds__(256) k_conv1(const float* __restrict__ xp1, const int* __restrict__ idx1,
                        const float* __restrict__ w1, float* __restrict__ hmax1,
                        float* __restrict__ hmin1, double* __restrict__ stats1sh) {
  __shared__ float F[4][KNN][6];
  __shared__ float red[4][64][2];
  int g = threadIdx.x >> 6, lane = threadIdx.x & 63;
  float w[6];
  #pragma unroll
  for (int c = 0; c < 6; c++) w[c] = w1[lane*6 + c];
  float sum = 0.f, sumsq = 0.f;
  int pbase = blockIdx.x * 16;
  for (int it = 0; it < 4; ++it) {
    int p = pbase + it*4 + g;
    if (lane < KNN) {
      int nb = idx1[p*KNN + lane];
      int bb = p >> 10;
      const float* xc = xp1 + p*3;
      const float* ft = xp1 + (bb*N_ + nb)*3;
      float x0 = ft[0], x1 = ft[1], x2v = ft[2];
      float c0 = xc[0], c1 = xc[1], c2 = xc[2];
      float X2 = x0*x0 + x1*x1 + x2v*x2v;
      float Y2 = c0*c0 + c1*c1 + c2*c2;
      float XY = -(x0*c0 + x1*c1 + x2v*c2);
      float den = fmaxf(1.0f + 0.02f*XY + 1e-4f*X2*Y2, 1e-15f);
      float s1 = (1.0f + 0.02f*XY + 0.01f*Y2) / den;
      float s2 = (1.0f - 0.01f*X2) / den;
      F[g][lane][0] = s1*x0 - s2*c0;
      F[g][lane][1] = s1*x1 - s2*c1;
      F[g][lane][2] = s1*x2v - s2*c2;
      F[g][lane][3] = c0; F[g][lane][4] = c1; F[g][lane][5] = c2;
    }
    __syncthreads();
    float mx = -__builtin_inff(), mn = __builtin_inff();
    for (int k = 0; k < KNN; k++) {
      float h = 0.f;
      #pragma unroll
      for (int c = 0; c < 6; c++) h = fmaf(w[c], F[g][k][c], h);
      mx = fmaxf(mx, h); mn = fminf(mn, h);
      sum += h; sumsq += h*h;
    }
    hmax1[p*64 + lane] = mx;
    hmin1[p*64 + lane] = mn;
    __syncthreads();
  }
  red[g][lane][0] = sum; red[g][lane][1] = sumsq;
  __syncthreads();
  if (g == 0) {
    float s  = red[0][lane][0] + red[1][lane][0] + red[2][lane][0] + red[3][lane][0];
    float s2 = red[0][lane][1] + red[1][lane][1] + red[2][lane][1] + red[3][lane][1];
    double* dst = stats1sh + ((size_t)(blockIdx.x & 63)*64 + lane)*2;
    atomicAdd(dst, (double)s);
    atomicAdd(dst + 1, (double)s2);
  }
}

// ---------- BN stat reduce ----------
__global__ void k_bn_reduce(const double* __restrict__ sh, int nsh, int nch, double cnt,
                            const float* __restrict__ g, const float* __restrict__ bb,
                            float* __restrict__ scale, float* __restrict__ shift) {
  int o = blockIdx.x * blockDim.x + threadIdx.x;
  if (o >= nch) return;
  double s = 0.0, s2 = 0.0;
  for (int i = 0; i < nsh; i++) {
    s  += sh[((size_t)i*nch + o)*2];
    s2 += sh[((size_t)i*nch + o)*2 + 1];
  }
  double m = s / cnt;
  double v = s2 / cnt - m*m;
  float a = g[o] / sqrtf((float)v + 1e-5f);
  scale[o] = a;
  shift[o] = bb[o] - a * (float)m;
}

// ---------- 5) BN1 apply + relu + e2p + coalesced x1T transpose + |x1|^2 ----------
__global__ void __launch_bounds__(256) k_bn1_apply(const float* __restrict__ hmax1, const float* __restrict__ hmin1,
                            const float* __restrict__ scale1, const float* __restrict__ shift1,
                            float* __restrict__ xp2,
                            float* __restrict__ x1T, float* __restrict__ xx1) {
  int b = blockIdx.x >> 4, nc = blockIdx.x & 15;
  int c = threadIdx.x & 63, sub = threadIdx.x >> 6;
  int n0 = nc*64 + sub*16;
  float a = scale1[c], t = shift1[c];
  float xr[16];
  #pragma unroll
  for (int i = 0; i < 16; i++) {
    int p = b*1024 + n0 + i;
    float h = (a >= 0.f) ? hmax1[(size_t)p*64 + c] : hmin1[(size_t)p*64 + c];
    float x1 = fmaxf(fmaf(a, h, t), 0.f);
    xr[i] = x1;
    float n2 = x1*x1;
    #pragma unroll
    for (int off = 32; off > 0; off >>= 1) n2 += __shfl_xor(n2, off);
    if (c == 0) xx1[p] = n2;
    float n1 = fmaxf(sqrtf(n2), 1e-15f);
    float th = tanhf(0.1f * n1);
    float sc = th / (0.1f * n1);
    float ny = fmaxf(th * 10.0f, 1e-15f);
    float mxn = (1.0f - 4e-3f) / 0.1f;
    if (ny > mxn) sc *= mxn / ny;
    xp2[(size_t)p*64 + c] = sc * x1;
  }
  float* dst = x1T + ((size_t)(b*64 + c))*1024 + n0;
  #pragma unroll
  for (int q = 0; q < 4; q++) {
    float4 v; v.x = xr[q*4]; v.y = xr[q*4+1]; v.z = xr[q*4+2]; v.w = xr[q*4+3];
    *((float4*)(dst + q*4)) = v;
  }
}

// ---------- 6) knn2 v3 (R9 config): 4-way split, 1024 blocks, all-wave selection, in-block merge ----------
__global__ void __launch_bounds__(256) k_knn2g(const float* __restrict__ x1T,
        const float* __restrict__ xx1,
        float* __restrict__ pdpart, int* __restrict__ idxpart) {
  __shared__ __align__(16) float SM[8448];   // As @0 (64x68), BsD @4352 (64x64)
  float* As = SM;
  float* BsD = SM + 4352;
  int tid = threadIdx.x;
  int blk = blockIdx.x;
  int b = blk >> 6, qc = (blk >> 2) & 15, cc = blk & 3;
  int qbase = qc*64, ccbase = cc*256;
  int tx = tid & 15, ty = tid >> 4;
  int wave = tid >> 6, lane = tid & 63;
  #pragma unroll
  for (int r = 0; r < 4; r++) {
    int e = tid + r*256;
    int k = e >> 4, qf = e & 15;
    *((float4*)(As + k*68 + qf*4)) =
      *((const float4*)(x1T + ((size_t)(b*64 + k))*1024 + qbase + qf*4));
  }
  float pdl[KNN]; int idl[KNN];
  #pragma unroll
  for (int i = 0; i < KNN; i++) { pdl[i] = -__builtin_inff(); idl[i] = 0; }
  int cq = lane + (lane >> 2);

  for (int st = 0; st < 4; ++st) {
    int cb0 = ccbase + st*64;
    __syncthreads();
    #pragma unroll
    for (int r = 0; r < 4; r++) {
      int e = tid + r*256;
      int k = e >> 4, cf = e & 15;
      *((float4*)(BsD + k*64 + cf*4)) =
        *((const float4*)(x1T + ((size_t)(b*64 + k))*1024 + cb0 + cf*4));
    }
    float4 xxc = *((const float4*)(xx1 + b*1024 + cb0 + ty*4));
    __syncthreads();
    float acc[4][4];
    #pragma unroll
    for (int i = 0; i < 4; i++)
      #pragma unroll
      for (int j = 0; j < 4; j++) acc[i][j] = 0.f;
    #pragma unroll 4
    for (int k = 0; k < 64; k++) {
      float4 a4 = *((const float4*)(As + k*68 + tx*4));
      float4 b4 = *((const float4*)(BsD + k*64 + ty*4));
      float av[4] = {a4.x, a4.y, a4.z, a4.w};
      float bw[4] = {b4.x, b4.y, b4.z, b4.w};
      #pragma unroll
      for (int i = 0; i < 4; i++)
        #pragma unroll
        for (int j = 0; j < 4; j++) acc[i][j] = fmaf(av[i], bw[j], acc[i][j]);
    }
    __syncthreads();
    float xxv[4] = {xxc.x, xxc.y, xxc.z, xxc.w};
    #pragma unroll
    for (int i = 0; i < 4; i++) {
      int q = tx*4 + i;
      #pragma unroll
      for (int j = 0; j < 4; j++) {
        int c = ty*4 + j;
        BsD[q*64 + ((c + q + (q >> 2)) & 63)] = 2.0f*acc[i][j] - xxv[j];
      }
    }
    __syncthreads();
    #pragma unroll
    for (int j = 0; j < 16; j++) {
      int c = wave*16 + j;
      float d = BsD[lane*64 + ((c + cq) & 63)];
      if (d > pdl[KNN-1]) topk_insert(pdl, idl, d, cb0 + c);
    }
  }
  __syncthreads();
  // block merge: 4 wave-partials -> exact top-20 of this cc chunk
  float* L0pd = SM;            int* L0id = (int*)(SM + 1344);
  float* L1pd = SM + 2688;     int* L1id = (int*)(SM + 4032);
  float* Mpd  = SM + 5376;     int* Mid  = (int*)(SM + 6720);
  if (wave == 0) {
    #pragma unroll
    for (int i = 0; i < KNN; i++) { L0pd[lane*21 + i] = pdl[i]; L0id[lane*21 + i] = idl[i]; }
  } else if (wave == 1) {
    #pragma unroll
    for (int i = 0; i < KNN; i++) { L1pd[lane*21 + i] = pdl[i]; L1id[lane*21 + i] = idl[i]; }
  }
  __syncthreads();
  if (tid < 64) {
    int ia = 0, ib = 0;
    for (int t = 0; t < KNN; t++) {
      float pa = L0pd[tid*21 + ia], pb = L1pd[tid*21 + ib];
      int xa = L0id[tid*21 + ia], xb = L1id[tid*21 + ib];
      bool ta = (pa > pb) || (pa == pb && xa < xb);
      Mpd[tid*21 + t] = ta ? pa : pb;
      Mid[tid*21 + t] = ta ? xa : xb;
      if (ta) ia++; else ib++;
    }
  }
  __syncthreads();
  if (wave == 2) {
    #pragma unroll
    for (int i = 0; i < KNN; i++) { L0pd[lane*21 + i] = pdl[i]; L0id[lane*21 + i] = idl[i]; }
  } else if (wave == 3) {
    #pragma unroll
    for (int i = 0; i < KNN; i++) { L1pd[lane*21 + i] = pdl[i]; L1id[lane*21 + i] = idl[i]; }
  }
  __syncthreads();
  if (tid < 64) {
    int p = b*N_ + qbase + tid;
    float* pe = pdpart + (size_t)p*80 + cc*20;
    int* ie = idxpart + (size_t)p*80 + cc*20;
    int ia = 0, ib = 0, im = 0;
    for (int t = 0; t < KNN; t++) {
      float pa = L0pd[tid*21 + ia], pb = L1pd[tid*21 + ib], pm = Mpd[tid*21 + im];
      int xa = L0id[tid*21 + ia], xb = L1id[tid*21 + ib], xm = Mid[tid*21 + im];
      float bp = pm; int bx = xm; int sel = 2;
      if (pa > bp || (pa == bp && xa < bx)) { bp = pa; bx = xa; sel = 0; }
      if (pb > bp || (pb == bp && xb < bx)) { bp = pb; bx = xb; sel = 1; }
      pe[t] = bp; ie[t] = bx;
      if (sel == 0) ia++; else if (sel == 1) ib++; else im++;
    }
  }
}

// ---------- 7) generic merge of NCH sorted top-20 chunks ----------
template<int NCH>
__global__ void k_knn_merge(const float* __restrict__ pdpart, const int* __restrict__ idxpart,
                            int* __restrict__ idxo) {
  int p = blockIdx.x*blockDim.x + threadIdx.x;
  if (p >= NPAIR) return;
  const float* pe = pdpart + (size_t)p*(NCH*20);
  const int* ie = idxpart + (size_t)p*(NCH*20);
  int pos[NCH];
  #pragma unroll
  for (int c = 0; c < NCH; c++) pos[c] = 0;
  int* outp = idxo + p*KNN;
  for (int t = 0; t < KNN; t++) {
    float best = -__builtin_inff(); int bi = 0x7FFFFFFF; int bc = 0;
    #pragma unroll
    for (int c = 0; c < NCH; c++) {
      if (pos[c] < KNN) {
        float pv = pe[c*20 + pos[c]]; int iv = ie[c*20 + pos[c]];
        if (pv > best || (pv == best && iv < bi)) { best = pv; bi = iv; bc = c; }
      }
    }
    outp[t] = bi;
    #pragma unroll
    for (int c = 0; c < NCH; c++) if (bc == c) pos[c]++;
  }
}

// ---------- 9) conv2 via bf16 MFMA v3: permuted rows (quad == pair), register epilogue ----------
// phys row r = rt*16 + q*4 + reg  <->  logical L = 20*q + 4*rt + reg  (q=(r>>2)&3, rt=r>>4, reg=r&3)
// Each lane's 20 D values = pair 'quad', k = rt*4+reg: max/min over k is in-register.
__global__ void __launch_bounds__(256) k_conv2m(const float* __restrict__ xp2,
    const int* __restrict__ idx2, const unsigned short* __restrict__ w2h,
    float* __restrict__ hmax2, float* __restrict__ hmin2, double* __restrict__ stats2sh) {
  __shared__ __align__(16) short Abf[80*136];    // 21760 B
  __shared__ float s1s[80], s2s[80];
  __shared__ int nbr[80];                        // logical order
  int tid = threadIdx.x;
  int p0 = blockIdx.x * 4;
  int b = p0 >> 10;
  if (tid < 80) nbr[tid] = idx2[p0*KNN + tid];
  __syncthreads();
  // stage (permuted): phys row r holds logical row L
  for (int e = tid; e < 80*16; e += 256) {
    int r = e >> 4, qq = e & 15;
    int q = (r >> 2) & 3;
    int L = 20*q + 4*(r >> 4) + (r & 3);
    float4 f = *((const float4*)(xp2 + (size_t)(b*N_ + nbr[L])*64) + qq);
    float4 cv = *((const float4*)(xp2 + (size_t)(p0 + q)*64) + qq);
    ushort4 fb, cb;
    fb.x = f2bf(f.x); fb.y = f2bf(f.y); fb.z = f2bf(f.z); fb.w = f2bf(f.w);
    cb.x = f2bf(cv.x); cb.y = f2bf(cv.y); cb.z = f2bf(cv.z); cb.w = f2bf(cv.w);
    *((ushort4*)(Abf + r*136 + qq*4)) = fb;
    *((ushort4*)(Abf + r*136 + 64 + qq*4)) = cb;
  }
  __syncthreads();
  // mobius scalars per phys row (row-local)
  if (tid < 160) {
    int r = tid >> 1, h = tid & 1;
    const unsigned short* Ar = (const unsigned short*)(Abf + r*136) + h*32;
    const unsigned short* Xr = (const unsigned short*)(Abf + r*136 + 64) + h*32;
    float X2 = 0.f, XY = 0.f, Y2 = 0.f;
    for (int c2 = 0; c2 < 32; c2++) {
      float f = bf2f(Ar[c2]), xcv = bf2f(Xr[c2]);
      X2 = fmaf(f, f, X2); XY = fmaf(-f, xcv, XY); Y2 = fmaf(xcv, xcv, Y2);
    }
    X2 += __shfl_xor(X2, 1); XY += __shfl_xor(XY, 1); Y2 += __shfl_xor(Y2, 1);
    if (h == 0) {
      float den = fmaxf(1.0f + 0.02f*XY + 1e-4f*X2*Y2, 1e-15f);
      s1s[r] = (1.0f + 0.02f*XY + 0.01f*Y2) / den;
      s2s[r] = (1.0f - 0.01f*X2) / den;
    }
  }
  __syncthreads();
  // in-place mobius transform of first half
  for (int e = tid; e < 80*16; e += 256) {
    int r = e >> 4, qq = e & 15;
    ushort4 fr = *((const ushort4*)(Abf + r*136 + qq*4));
    ushort4 xr4 = *((const ushort4*)(Abf + r*136 + 64 + qq*4));
    float s1 = s1s[r], s2 = s2s[r];
    ushort4 mo;
    mo.x = f2bf(s1*bf2f(fr.x) - s2*bf2f(xr4.x));
    mo.y = f2bf(s1*bf2f(fr.y) - s2*bf2f(xr4.y));
    mo.z = f2bf(s1*bf2f(fr.z) - s2*bf2f(xr4.z));
    mo.w = f2bf(s1*bf2f(fr.w) - s2*bf2f(xr4.w));
    *((ushort4*)(Abf + r*136 + qq*4)) = mo;
  }
  __syncthreads();
  // MFMA GEMM: per wave 48 cols x 80 rows, K=128
  int wave = tid >> 6, lane = tid & 63;
  int quad = lane >> 4, lm = lane & 15;
  int colbase = wave*48;
  f32x4 acc[5][3];
  #pragma unroll
  for (int rt = 0; rt < 5; rt++)
    #pragma unroll
    for (int cj = 0; cj < 3; cj++) acc[rt][cj] = (f32x4){0.f, 0.f, 0.f, 0.f};
  #pragma unroll
  for (int kt = 0; kt < 4; kt++) {
    int k0 = kt*32 + quad*8;
    bf16x8 bf[3];
    #pragma unroll
    for (int cj = 0; cj < 3; cj++)
      bf[cj] = *((const bf16x8*)(w2h + (size_t)(colbase + cj*16 + lm)*128 + k0));
    bf16x8 af[5];
    #pragma unroll
    for (int rt = 0; rt < 5; rt++)
      af[rt] = *((const bf16x8*)(Abf + (rt*16 + lm)*136 + k0));
    #pragma unroll
    for (int rt = 0; rt < 5; rt++)
      #pragma unroll
      for (int cj = 0; cj < 3; cj++)
        acc[rt][cj] = __builtin_amdgcn_mfma_f32_16x16x32_bf16(af[rt], bf[cj], acc[rt][cj], 0, 0, 0);
  }
  // register epilogue: this lane's 20 values per cj are pair 'quad'
  #pragma unroll
  for (int cj = 0; cj < 3; cj++) {
    int o = colbase + cj*16 + lm;
    float s = 0.f, s2 = 0.f, mx = -__builtin_inff(), mn = __builtin_inff();
    #pragma unroll
    for (int rt = 0; rt < 5; rt++) {
      #pragma unroll
      for (int reg = 0; reg < 4; reg++) {
        float h = acc[rt][cj][reg];
        s += h; s2 += h*h;
        mx = fmaxf(mx, h); mn = fminf(mn, h);
      }
    }
    hmax2[(size_t)(p0 + quad)*192 + o] = mx;
    hmin2[(size_t)(p0 + quad)*192 + o] = mn;
    // stats: combine over quads (all 80 rows)
    s  += __shfl_xor(s, 16);  s  += __shfl_xor(s, 32);
    s2 += __shfl_xor(s2, 16); s2 += __shfl_xor(s2, 32);
    if (lane < 16) {
      double* dst = stats2sh + ((size_t)(blockIdx.x & 63)*192 + o)*2;
      atomicAdd(dst, (double)s); atomicAdd(dst + 1, (double)s2);
    }
  }
}

// ---------- 11) conv3 via bf16 MFMA, A-tile staged directly from BN1/BN2 max/min ----------
__global__ void __launch_bounds__(256) k_conv3m(
   const float* __restrict__ hmax1, const float* __restrict__ hmin1,
   const float* __restrict__ scale1, const float* __restrict__ shift1,
   const float* __restrict__ hmax2, const float* __restrict__ hmin2,
   const float* __restrict__ scale2, const float* __restrict__ shift2,
   const unsigned short* __restrict__ wt3h, double* __restrict__ stats3sh,
   unsigned* __restrict__ hmax3u, unsigned* __restrict__ hmin3u) {
  __shared__ short As[64*264];
  int tid = threadIdx.x;
  int mt = blockIdx.x >> 2, cb = blockIdx.x & 3;
  int rowbase = mt*64;
  int b = rowbase >> 10;
  int c4 = tid & 63;
  float4 sc, sh;
  if (c4 < 16) {
    sc = *((const float4*)(scale1 + c4*4));
    sh = *((const float4*)(shift1 + c4*4));
  } else {
    sc = *((const float4*)(scale2 + (c4*4 - 64)));
    sh = *((const float4*)(shift2 + (c4*4 - 64)));
  }
  #pragma unroll 4
  for (int i = 0; i < 16; i++) {
    int r = (tid >> 6) + i*4;
    int p = rowbase + r;
    float4 hx, hn;
    if (c4 < 16) {
      hx = *((const float4*)(hmax1 + (size_t)p*64 + c4*4));
      hn = *((const float4*)(hmin1 + (size_t)p*64 + c4*4));
    } else {
      hx = *((const float4*)(hmax2 + (size_t)p*192 + (c4*4 - 64)));
      hn = *((const float4*)(hmin2 + (size_t)p*192 + (c4*4 - 64)));
    }
    ushort4 o4;
    o4.x = f2bf(fmaxf(fmaf(sc.x, (sc.x >= 0.f ? hx.x : hn.x), sh.x), 0.f));
    o4.y = f2bf(fmaxf(fmaf(sc.y, (sc.y >= 0.f ? hx.y : hn.y), sh.y), 0.f));
    o4.z = f2bf(fmaxf(fmaf(sc.z, (sc.z >= 0.f ? hx.z : hn.z), sh.z), 0.f));
    o4.w = f2bf(fmaxf(fmaf(sc.w, (sc.w >= 0.f ? hx.w : hn.w), sh.w), 0.f));
    *((ushort4*)(As + r*264 + c4*4)) = o4;
  }
  __syncthreads();
  int wave = tid >> 6, lane = tid & 63;
  int quad = lane >> 4, lm = lane & 15;
  int colbase = cb*256 + wave*64;
  f32x4 acc[4][4];
  #pragma unroll
  for (int ri = 0; ri < 4; ri++)
    #pragma unroll
    for (int cj = 0; cj < 4; cj++) acc[ri][cj] = (f32x4){0.f, 0.f, 0.f, 0.f};
  for (int kt = 0; kt < 8; kt++) {
    int k0 = kt*32 + quad*8;
    bf16x8 bf[4];
    #pragma unroll
    for (int cj = 0; cj < 4; cj++)
      bf[cj] = *((const bf16x8*)(wt3h + (size_t)(colbase + cj*16 + lm)*256 + k0));
    bf16x8 af[4];
    #pragma unroll
    for (int ri = 0; ri < 4; ri++)
      af[ri] = *((const bf16x8*)(As + (ri*16 + lm)*264 + k0));
    #pragma unroll
    for (int ri = 0; ri < 4; ri++)
      #pragma unroll
      for (int cj = 0; cj < 4; cj++)
        acc[ri][cj] = __builtin_amdgcn_mfma_f32_16x16x32_bf16(af[ri], bf[cj], acc[ri][cj], 0, 0, 0);
  }
  #pragma unroll
  for (int cj = 0; cj < 4; cj++) {
    float s = 0.f, s2 = 0.f, mx = -__builtin_inff(), mn = __builtin_inff();
    #pragma unroll
    for (int ri = 0; ri < 4; ri++) {
      #pragma unroll
      for (int reg = 0; reg < 4; reg++) {
        float h = acc[ri][cj][reg];
        s += h; s2 += h*h; mx = fmaxf(mx, h); mn = fminf(mn, h);
      }
    }
    s  += __shfl_xor(s, 16);  s  += __shfl_xor(s, 32);
    s2 += __shfl_xor(s2, 16); s2 += __shfl_xor(s2, 32);
    mx = fmaxf(mx, __shfl_xor(mx, 16)); mx = fmaxf(mx, __shfl_xor(mx, 32));
    mn = fminf(mn, __shfl_xor(mn, 16)); mn = fminf(mn, __shfl_xor(mn, 32));
    if (lane < 16) {
      int col = colbase + cj*16 + lane;
      double* dst = stats3sh + ((size_t)(blockIdx.x & 63)*1024 + col)*2;
      atomicAdd(dst, (double)s);
      atomicAdd(dst + 1, (double)s2);
      atomicMax(hmax3u + b*1024 + col, fkey(mx));
      atomicMin(hmin3u + b*1024 + col, fkey(mn));
    }
  }
}

// ---------- 12) head ----------
__device__ float blk_reduce(float v, float* red, int tid) {
  red[tid] = v; __syncthreads();
  for (int st = 128; st > 0; st >>= 1) {
    if (tid < st) red[tid] += red[tid + st];
    __syncthreads();
  }
  float r = red[0]; __syncthreads();
  return r;
}

__global__ void __launch_bounds__(256) k_head(const unsigned* __restrict__ hmax3u, const unsigned* __restrict__ hmin3u,
    const float* __restrict__ scale3, const float* __restrict__ shift3,
    const float* __restrict__ fc1w, const float* __restrict__ fc1b,
    const float* __restrict__ ln1g, const float* __restrict__ ln1b,
    const float* __restrict__ fc2w, const float* __restrict__ fc2b,
    const float* __restrict__ ln2g, const float* __restrict__ ln2b,
    const float* __restrict__ outw, const float* __restrict__ outb,
    float* __restrict__ out) {
  __shared__ __align__(16) float V[1024];
  __shared__ __align__(16) float H1[512];
  __shared__ __align__(16) float H2[256];
  __shared__ float red[256];
  int b = blockIdx.x, tid = threadIdx.x;
  for (int o = tid; o < 1024; o += 256) {
    float a = scale3[o];
    unsigned u = (a >= 0.f) ? hmax3u[b*1024 + o] : hmin3u[b*1024 + o];
    float h = fkeyinv(u);
    V[o] = fmaxf(fmaf(a, h, shift3[o]), 0.f);
  }
  __syncthreads();
  float h1v[2];
  #pragma unroll
  for (int ii = 0; ii < 2; ii++) {
    int o = tid + ii*256;
    const float4* wr = (const float4*)(fc1w + (size_t)o*1024);
    float s = 0.f;
    for (int c4 = 0; c4 < 256; c4++) {
      float4 w = wr[c4]; float4 vv = ((const float4*)V)[c4];
      s = fmaf(w.x, vv.x, s); s = fmaf(w.y, vv.y, s);
      s = fmaf(w.z, vv.z, s); s = fmaf(w.w, vv.w, s);
    }
    h1v[ii] = s + fc1b[o];
  }
  float s = h1v[0] + h1v[1];
  float s2 = h1v[0]*h1v[0] + h1v[1]*h1v[1];
  s = blk_reduce(s, red, tid);
  s2 = blk_reduce(s2, red, tid);
  float m = s / 512.f;
  float var = s2 / 512.f - m*m;
  float inv = 1.0f / sqrtf(var + 1e-5f);
  #pragma unroll
  for (int ii = 0; ii < 2; ii++) {
    int o = tid + ii*256;
    H1[o] = fmaxf((h1v[ii] - m)*inv*ln1g[o] + ln1b[o], 0.f);
  }
  __syncthreads();
  float h2v;
  {
    const float4* wr = (const float4*)(fc2w + (size_t)tid*512);
    float t = 0.f;
    for (int c4 = 0; c4 < 128; c4++) {
      float4 w = wr[c4]; float4 vv = ((const float4*)H1)[c4];
      t = fmaf(w.x, vv.x, t); t = fmaf(w.y, vv.y, t);
      t = fmaf(w.z, vv.z, t); t = fmaf(w.w, vv.w, t);
    }
    h2v = t + fc2b[tid];
  }
  float ss = blk_reduce(h2v, red, tid);
  float ss2 = blk_reduce(h2v*h2v, red, tid);
  float m2 = ss / 256.f;
  float var2 = ss2 / 256.f - m2*m2;
  float inv2 = 1.0f / sqrtf(var2 + 1e-5f);
  H2[tid] = fmaxf((h2v - m2)*inv2*ln2g[tid] + ln2b[tid], 0.f);
  __syncthreads();
  if (tid < 40) {
    const float4* wr = (const float4*)(outw + (size_t)tid*256);
    float t = 0.f;
    for (int c4 = 0; c4 < 64; c4++) {
      float4 w = wr[c4]; float4 vv = ((const float4*)H2)[c4];
      t = fmaf(w.x, vv.x, t); t = fmaf(w.y, vv.y, t);
      t = fmaf(w.z, vv.z, t); t = fmaf(w.w, vv.w, t);
    }
    red[tid] = t + outb[tid];
  }
  __syncthreads();
  if (tid == 0) {
    float mx = -__builtin_inff();
    for (int i2 = 0; i2 < 40; i2++) mx = fmaxf(mx, red[i2]);
    float se = 0.f;
    for (int i2 = 0; i2 < 40; i2++) se += expf(red[i2] - mx);
    float lse = mx + logf(se);
    for (int i2 = 0; i2 < 40; i2++) out[b*40 + i2] = red[i2] - lse;
  }
}

extern "C" void kernel_launch(void* const* d_in, const int* in_sizes, int n_in,
                              void* d_out, int out_size, void* d_ws, size_t ws_size,
                              hipStream_t stream) {
  (void)in_sizes; (void)n_in; (void)out_size; (void)ws_size;
  const float* x    = (const float*)d_in[0];
  const float* w1   = (const float*)d_in[1];
  const float* bn1g = (const float*)d_in[2];
  const float* bn1b = (const float*)d_in[3];
  const float* w2   = (const float*)d_in[4];
  const float* bn2g = (const float*)d_in[5];
  const float* bn2b = (const float*)d_in[6];
  const float* w3   = (const float*)d_in[7];
  const float* bn3g = (const float*)d_in[8];
  const float* bn3b = (const float*)d_in[9];
  const float* fc1w = (const float*)d_in[10];
  const float* fc1b = (const float*)d_in[11];
  const float* ln1g = (const float*)d_in[12];
  const float* ln1b = (const float*)d_in[13];
  const float* fc2w = (const float*)d_in[14];
  const float* fc2b = (const float*)d_in[15];
  const float* ln2g = (const float*)d_in[16];
  const float* ln2b = (const float*)d_in[17];
  const float* outw = (const float*)d_in[18];
  const float* outb = (const float*)d_in[19];
  float* out = (float*)d_out;

  float* ws = (float*)d_ws;
  size_t off = 0;
  float* xp1   = ws + off; off += 49152;
  int*   idx1  = (int*)(ws + off); off += 327680;
  float* hmax1 = ws + off; off += 1048576;
  float* hmin1 = ws + off; off += 1048576;
  float* xp2   = ws + off; off += 1048576;
  float* hmax2 = ws + off; off += 3145728;   // also pdpart (knn partials)
  float* hmin2 = ws + off; off += 3145728;   // also idxpart
  int*   idx2  = (int*)(ws + off); off += 327680;
  unsigned short* w2h = (unsigned short*)(ws + off); off += 24576;
  unsigned short* wt3h = (unsigned short*)(ws + off); off += 131072;
  float* x1T   = ws + off; off += 1048576;
  float* xx1   = ws + off; off += 16384;
  float* scale1 = ws + off; off += 64;
  float* shift1 = ws + off; off += 64;
  float* scale2 = ws + off; off += 192;
  float* shift2 = ws + off; off += 192;
  float* scale3 = ws + off; off += 1024;
  float* shift3 = ws + off; off += 1024;
  double* stats1sh = (double*)(ws + off);
  double* stats2sh = stats1sh + 64*64*2;
  double* stats3sh = stats2sh + 64*192*2;
  unsigned* hmax3u = (unsigned*)(stats3sh + (size_t)64*1024*2);
  unsigned* hmin3u = hmax3u + 16384;
  float* pdpart = hmax2;
  int*   idxpart = (int*)hmin2;

  size_t zero_bytes = ((size_t)64*64*2 + (size_t)64*192*2 + (size_t)64*1024*2)*8 + (size_t)16384*4;
  hipMemsetAsync(stats1sh, 0, zero_bytes, stream);
  hipMemsetAsync(hmin3u, 0xFF, (size_t)16384*4, stream);

  k_prep<<<1024, 256, 0, stream>>>(x, xp1, w2, w3, w2h, wt3h);
  k_knn1_part<<<512, 256, 0, stream>>>(x, pdpart, idxpart);
  k_knn_merge<8><<<256, 64, 0, stream>>>(pdpart, idxpart, idx1);
  k_conv1<<<1024, 256, 0, stream>>>(xp1, idx1, w1, hmax1, hmin1, stats1sh);
  k_bn_reduce<<<1, 64, 0, stream>>>(stats1sh, 64, 64, 327680.0, bn1g, bn1b, scale1, shift1);
  k_bn1_apply<<<256, 256, 0, stream>>>(hmax1, hmin1, scale1, shift1, xp2, x1T, xx1);
  k_knn2g<<<1024, 256, 0, stream>>>(x1T, xx1, pdpart, idxpart);
  k_knn_merge<4><<<256, 64, 0, stream>>>(pdpart, idxpart, idx2);
  k_conv2m<<<4096, 256, 0, stream>>>(xp2, idx2, w2h, hmax2, hmin2, stats2sh);
  k_bn_reduce<<<1, 192, 0, stream>>>(stats2sh, 64, 192, 327680.0, bn2g, bn2b, scale2, shift2);
  k_conv3m<<<1024, 256, 0, stream>>>(hmax1, hmin1, scale1, shift1, hmax2, hmin2, scale2, shift2,
                                     wt3h, stats3sh, hmax3u, hmin3u);
  k_bn_reduce<<<4, 256, 0, stream>>>(stats3sh, 64, 1024, 16384.0, bn3g, bn3b, scale3, shift3);
  k_head<<<16, 256, 0, stream>>>(hmax3u, hmin3u, scale3, shift3,
                                 fc1w, fc1b, ln1g, ln1b,
                                 fc2w, fc2b, ln2g, ln2b,
                                 outw, outb, out);
}

// Round 12
// 499.679 us; speedup vs baseline: 1.3256x; 1.2406x over previous
//
#include <hip/hip_runtime.h>
#include <math.h>

#define B_ 16
#define N_ 1024
#define KNN 20
#define NPAIR (B_*N_)

typedef __attribute__((ext_vector_type(8))) short bf16x8;
typedef __attribute__((ext_vector_type(4))) float f32x4;

// ---------- helpers ----------
__device__ __forceinline__ unsigned fkey(float f) {
  unsigned u = __float_as_uint(f);
  return (u & 0x80000000u) ? ~u : (u | 0x80000000u);
}
__device__ __forceinline__ float fkeyinv(unsigned u) {
  unsigned b = (u & 0x80000000u) ? (u ^ 0x80000000u) : ~u;
  return __uint_as_float(b);
}
__device__ __forceinline__ unsigned short f2bf(float x) {  // RNE float->bf16
  unsigned u = __float_as_uint(x);
  unsigned r = (u + 0x7FFFu + ((u >> 16) & 1u)) >> 16;
  return (unsigned short)r;
}
__device__ __forceinline__ float bf2f(unsigned short u) {
  return __uint_as_float(((unsigned)u) << 16);
}
// packed knn key: top 22 bits of fkey(d) | (1023 - idx). u32 '>' == dist desc, idx asc.
__device__ __forceinline__ unsigned knnkey(float d, int idx) {
  return (fkey(d) & 0xFFFFFC00u) | (unsigned)(1023 - idx);
}

// Branchless sorted-insert (descending) of packed u32 key: 2 ops/stage.
__device__ __forceinline__ void topk_insert_u32(unsigned (&kl)[KNN], unsigned nk) {
  kl[KNN-1] = nk;
  #pragma unroll
  for (int i = KNN-1; i > 0; i--) {
    unsigned hi = max(kl[i-1], kl[i]);
    unsigned lo = min(kl[i-1], kl[i]);
    kl[i-1] = hi; kl[i] = lo;
  }
}

// ---------- 1) prep: e2p of raw points + weight bf16 conversions ----------
__global__ void k_prep(const float* __restrict__ x, float* __restrict__ xp1,
                       const float* __restrict__ w2, const float* __restrict__ w3,
                       unsigned short* __restrict__ w2h, unsigned short* __restrict__ wt3h) {
  int i = blockIdx.x * 256 + threadIdx.x;
  if (i < NPAIR) {
    float a0 = x[i*3+0], a1 = x[i*3+1], a2 = x[i*3+2];
    float n = sqrtf(a0*a0 + a1*a1 + a2*a2);
    n = fmaxf(n, 1e-15f);
    float th = tanhf(0.1f * n);
    float sc = th / (0.1f * n);
    float ny = fmaxf(th * 10.0f, 1e-15f);
    float mxn = (1.0f - 4e-3f) / 0.1f;
    if (ny > mxn) sc *= mxn / ny;
    xp1[i*3+0] = sc*a0; xp1[i*3+1] = sc*a1; xp1[i*3+2] = sc*a2;
  }
  if (i < 192*128) w2h[i] = f2bf(w2[i]);
  wt3h[i] = f2bf(w3[i]);
}

// ---------- 2) knn on raw 3-d points: 8-way candidate split, packed keys ----------
__global__ void __launch_bounds__(256) k_knn1_part(const float* __restrict__ x,
        unsigned* __restrict__ keypart) {
  __shared__ float P[N_*3];
  __shared__ float XX[N_];
  int blk = blockIdx.x;
  int b = blk >> 5, rc = (blk >> 3) & 3, cc = blk & 7;
  const float* xb = x + b*N_*3;
  for (int e = threadIdx.x; e < N_*3; e += 256) P[e] = xb[e];
  __syncthreads();
  for (int j = threadIdx.x; j < N_; j += 256) {
    float q0 = P[j*3], q1 = P[j*3+1], q2 = P[j*3+2];
    XX[j] = q0*q0 + q1*q1 + q2*q2;
  }
  __syncthreads();
  int r = rc*256 + threadIdx.x;
  float q0 = P[r*3], q1 = P[r*3+1], q2 = P[r*3+2];
  float xxq = XX[r];
  unsigned kl[KNN];
  #pragma unroll
  for (int i = 0; i < KNN; i++) kl[i] = 0u;
  int cbase = cc*128;
  for (int jj = 0; jj < 128; jj++) {
    int j = cbase + jj;
    float dot = q0*P[j*3] + q1*P[j*3+1] + q2*P[j*3+2];
    float d = 2.0f*dot - xxq - XX[j];
    unsigned nk = knnkey(d, j);
    if (nk > kl[KNN-1]) topk_insert_u32(kl, nk);
  }
  int p = b*N_ + r;
  unsigned* pe = keypart + (size_t)p*160 + cc*20;
  #pragma unroll
  for (int i = 0; i < KNN; i++) pe[i] = kl[i];
}

// ---------- 3) conv1 fused ----------
__global__ void __launch_bounds__(256) k_conv1(const float* __restrict__ xp1, const int* __restrict__ idx1,
                        const float* __restrict__ w1, float* __restrict__ hmax1,
                        float* __restrict__ hmin1, double* __restrict__ stats1sh) {
  __shared__ float F[4][KNN][6];
  __shared__ float red[4][64][2];
  int g = threadIdx.x >> 6, lane = threadIdx.x & 63;
  float w[6];
  #pragma unroll
  for (int c = 0; c < 6; c++) w[c] = w1[lane*6 + c];
  float sum = 0.f, sumsq = 0.f;
  int pbase = blockIdx.x * 16;
  for (int it = 0; it < 4; ++it) {
    int p = pbase + it*4 + g;
    if (lane < KNN) {
      int nb = idx1[p*KNN + lane];
      int bb = p >> 10;
      const float* xc = xp1 + p*3;
      const float* ft = xp1 + (bb*N_ + nb)*3;
      float x0 = ft[0], x1 = ft[1], x2v = ft[2];
      float c0 = xc[0], c1 = xc[1], c2 = xc[2];
      float X2 = x0*x0 + x1*x1 + x2v*x2v;
      float Y2 = c0*c0 + c1*c1 + c2*c2;
      float XY = -(x0*c0 + x1*c1 + x2v*c2);
      float den = fmaxf(1.0f + 0.02f*XY + 1e-4f*X2*Y2, 1e-15f);
      float s1 = (1.0f + 0.02f*XY + 0.01f*Y2) / den;
      float s2 = (1.0f - 0.01f*X2) / den;
      F[g][lane][0] = s1*x0 - s2*c0;
      F[g][lane][1] = s1*x1 - s2*c1;
      F[g][lane][2] = s1*x2v - s2*c2;
      F[g][lane][3] = c0; F[g][lane][4] = c1; F[g][lane][5] = c2;
    }
    __syncthreads();
    float mx = -__builtin_inff(), mn = __builtin_inff();
    for (int k = 0; k < KNN; k++) {
      float h = 0.f;
      #pragma unroll
      for (int c = 0; c < 6; c++) h = fmaf(w[c], F[g][k][c], h);
      mx = fmaxf(mx, h); mn = fminf(mn, h);
      sum += h; sumsq += h*h;
    }
    hmax1[p*64 + lane] = mx;
    hmin1[p*64 + lane] = mn;
    __syncthreads();
  }
  red[g][lane][0] = sum; red[g][lane][1] = sumsq;
  __syncthreads();
  if (g == 0) {
    float s  = red[0][lane][0] + red[1][lane][0] + red[2][lane][0] + red[3][lane][0];
    float s2 = red[0][lane][1] + red[1][lane][1] + red[2][lane][1] + red[3][lane][1];
    double* dst = stats1sh + ((size_t)(blockIdx.x & 63)*64 + lane)*2;
    atomicAdd(dst, (double)s);
    atomicAdd(dst + 1, (double)s2);
  }
}

// ---------- BN stat reduce ----------
__global__ void k_bn_reduce(const double* __restrict__ sh, int nsh, int nch, double cnt,
                            const float* __restrict__ g, const float* __restrict__ bb,
                            float* __restrict__ scale, float* __restrict__ shift) {
  int o = blockIdx.x * blockDim.x + threadIdx.x;
  if (o >= nch) return;
  double s = 0.0, s2 = 0.0;
  for (int i = 0; i < nsh; i++) {
    s  += sh[((size_t)i*nch + o)*2];
    s2 += sh[((size_t)i*nch + o)*2 + 1];
  }
  double m = s / cnt;
  double v = s2 / cnt - m*m;
  float a = g[o] / sqrtf((float)v + 1e-5f);
  scale[o] = a;
  shift[o] = bb[o] - a * (float)m;
}

// ---------- 5) BN1 apply + relu + e2p + coalesced x1T transpose + |x1|^2 ----------
__global__ void __launch_bounds__(256) k_bn1_apply(const float* __restrict__ hmax1, const float* __restrict__ hmin1,
                            const float* __restrict__ scale1, const float* __restrict__ shift1,
                            float* __restrict__ xp2,
                            float* __restrict__ x1T, float* __restrict__ xx1) {
  int b = blockIdx.x >> 4, nc = blockIdx.x & 15;
  int c = threadIdx.x & 63, sub = threadIdx.x >> 6;
  int n0 = nc*64 + sub*16;
  float a = scale1[c], t = shift1[c];
  float xr[16];
  #pragma unroll
  for (int i = 0; i < 16; i++) {
    int p = b*1024 + n0 + i;
    float h = (a >= 0.f) ? hmax1[(size_t)p*64 + c] : hmin1[(size_t)p*64 + c];
    float x1 = fmaxf(fmaf(a, h, t), 0.f);
    xr[i] = x1;
    float n2 = x1*x1;
    #pragma unroll
    for (int off = 32; off > 0; off >>= 1) n2 += __shfl_xor(n2, off);
    if (c == 0) xx1[p] = n2;
    float n1 = fmaxf(sqrtf(n2), 1e-15f);
    float th = tanhf(0.1f * n1);
    float sc = th / (0.1f * n1);
    float ny = fmaxf(th * 10.0f, 1e-15f);
    float mxn = (1.0f - 4e-3f) / 0.1f;
    if (ny > mxn) sc *= mxn / ny;
    xp2[(size_t)p*64 + c] = sc * x1;
  }
  float* dst = x1T + ((size_t)(b*64 + c))*1024 + n0;
  #pragma unroll
  for (int q = 0; q < 4; q++) {
    float4 v; v.x = xr[q*4]; v.y = xr[q*4+1]; v.z = xr[q*4+2]; v.w = xr[q*4+3];
    *((float4*)(dst + q*4)) = v;
  }
}

// ---------- 6) knn2 v5: 4-way split, packed-u32 selection, 32 KB LDS (5 blocks/CU) ----------
__global__ void __launch_bounds__(256) k_knn2g(const float* __restrict__ x1T,
        const float* __restrict__ xx1, unsigned* __restrict__ keypart) {
  __shared__ __align__(16) float SM[8192];   // As @0 (64x64), BsD @4096 (64x64)
  float* As = SM;
  float* BsD = SM + 4096;
  int tid = threadIdx.x;
  int blk = blockIdx.x;
  int b = blk >> 6, qc = (blk >> 2) & 15, cc = blk & 3;
  int qbase = qc*64, ccbase = cc*256;
  int tx = tid & 15, ty = tid >> 4;
  int wave = tid >> 6, lane = tid & 63;
  #pragma unroll
  for (int r = 0; r < 4; r++) {
    int e = tid + r*256;
    int k = e >> 4, qf = e & 15;
    *((float4*)(As + k*64 + qf*4)) =
      *((const float4*)(x1T + ((size_t)(b*64 + k))*1024 + qbase + qf*4));
  }
  unsigned kl[KNN];
  #pragma unroll
  for (int i = 0; i < KNN; i++) kl[i] = 0u;
  int cq = lane + (lane >> 2);

  for (int st = 0; st < 4; ++st) {
    int cb0 = ccbase + st*64;
    __syncthreads();
    #pragma unroll
    for (int r = 0; r < 4; r++) {
      int e = tid + r*256;
      int k = e >> 4, cf = e & 15;
      *((float4*)(BsD + k*64 + cf*4)) =
        *((const float4*)(x1T + ((size_t)(b*64 + k))*1024 + cb0 + cf*4));
    }
    float4 xxc = *((const float4*)(xx1 + b*1024 + cb0 + ty*4));
    __syncthreads();
    float acc[4][4];
    #pragma unroll
    for (int i = 0; i < 4; i++)
      #pragma unroll
      for (int j = 0; j < 4; j++) acc[i][j] = 0.f;
    #pragma unroll 4
    for (int k = 0; k < 64; k++) {
      float4 a4 = *((const float4*)(As + k*64 + tx*4));
      float4 b4 = *((const float4*)(BsD + k*64 + ty*4));
      float av[4] = {a4.x, a4.y, a4.z, a4.w};
      float bw[4] = {b4.x, b4.y, b4.z, b4.w};
      #pragma unroll
      for (int i = 0; i < 4; i++)
        #pragma unroll
        for (int j = 0; j < 4; j++) acc[i][j] = fmaf(av[i], bw[j], acc[i][j]);
    }
    __syncthreads();
    float xxv[4] = {xxc.x, xxc.y, xxc.z, xxc.w};
    #pragma unroll
    for (int i = 0; i < 4; i++) {
      int q = tx*4 + i;
      #pragma unroll
      for (int j = 0; j < 4; j++) {
        int c = ty*4 + j;
        BsD[q*64 + ((c + q + (q >> 2)) & 63)] = 2.0f*acc[i][j] - xxv[j];
      }
    }
    __syncthreads();
    #pragma unroll
    for (int j = 0; j < 16; j++) {
      int c = wave*16 + j;
      float d = BsD[lane*64 + ((c + cq) & 63)];
      unsigned nk = knnkey(d, cb0 + c);
      if (nk > kl[KNN-1]) topk_insert_u32(kl, nk);
    }
  }
  __syncthreads();
  // block merge (u32): 4 wave-partials -> exact top-20 of this cc chunk
  unsigned* U = (unsigned*)SM;
  unsigned* L0 = U;             // 64*21
  unsigned* L1 = U + 1344;
  unsigned* M  = U + 2688;
  if (wave == 0) {
    #pragma unroll
    for (int i = 0; i < KNN; i++) L0[lane*21 + i] = kl[i];
  } else if (wave == 1) {
    #pragma unroll
    for (int i = 0; i < KNN; i++) L1[lane*21 + i] = kl[i];
  }
  __syncthreads();
  if (tid < 64) {
    int ia = 0, ib = 0;
    for (int t = 0; t < KNN; t++) {
      unsigned pa = L0[tid*21 + ia], pb = L1[tid*21 + ib];
      bool ta = pa > pb;
      M[tid*21 + t] = ta ? pa : pb;
      if (ta) ia++; else ib++;
    }
  }
  __syncthreads();
  if (wave == 2) {
    #pragma unroll
    for (int i = 0; i < KNN; i++) L0[lane*21 + i] = kl[i];
  } else if (wave == 3) {
    #pragma unroll
    for (int i = 0; i < KNN; i++) L1[lane*21 + i] = kl[i];
  }
  __syncthreads();
  if (tid < 64) {
    int p = b*N_ + qbase + tid;
    unsigned* pe = keypart + (size_t)p*80 + cc*20;
    int ia = 0, ib = 0, im = 0;
    for (int t = 0; t < KNN; t++) {
      unsigned pa = L0[tid*21 + ia], pb = L1[tid*21 + ib], pm = M[tid*21 + im];
      unsigned bp = pm; int sel = 2;
      if (pa > bp) { bp = pa; sel = 0; }
      if (pb > bp) { bp = pb; sel = 1; }
      pe[t] = bp;
      if (sel == 0) ia++; else if (sel == 1) ib++; else im++;
    }
  }
}

// ---------- 7) generic merge of NCH sorted top-20 u32-key chunks -> indices ----------
template<int NCH>
__global__ void k_knn_merge(const unsigned* __restrict__ keypart, int* __restrict__ idxo) {
  int p = blockIdx.x*blockDim.x + threadIdx.x;
  if (p >= NPAIR) return;
  const unsigned* pe = keypart + (size_t)p*(NCH*20);
  int pos[NCH];
  #pragma unroll
  for (int c = 0; c < NCH; c++) pos[c] = 0;
  int* outp = idxo + p*KNN;
  for (int t = 0; t < KNN; t++) {
    unsigned best = 0u; int bc = 0;
    #pragma unroll
    for (int c = 0; c < NCH; c++) {
      if (pos[c] < KNN) {
        unsigned v = pe[c*20 + pos[c]];
        if (v > best) { best = v; bc = c; }
      }
    }
    outp[t] = 1023 - (int)(best & 1023u);
    #pragma unroll
    for (int c = 0; c < NCH; c++) if (bc == c) pos[c]++;
  }
}

// ---------- 9) conv2 via bf16 MFMA v3: permuted rows (quad == pair), register epilogue ----------
__global__ void __launch_bounds__(256) k_conv2m(const float* __restrict__ xp2,
    const int* __restrict__ idx2, const unsigned short* __restrict__ w2h,
    float* __restrict__ hmax2, float* __restrict__ hmin2, double* __restrict__ stats2sh) {
  __shared__ __align__(16) short Abf[80*136];    // 21760 B
  __shared__ float s1s[80], s2s[80];
  __shared__ int nbr[80];                        // logical order
  int tid = threadIdx.x;
  int p0 = blockIdx.x * 4;
  int b = p0 >> 10;
  if (tid < 80) nbr[tid] = idx2[p0*KNN + tid];
  __syncthreads();
  for (int e = tid; e < 80*16; e += 256) {
    int r = e >> 4, qq = e & 15;
    int q = (r >> 2) & 3;
    int L = 20*q + 4*(r >> 4) + (r & 3);
    float4 f = *((const float4*)(xp2 + (size_t)(b*N_ + nbr[L])*64) + qq);
    float4 cv = *((const float4*)(xp2 + (size_t)(p0 + q)*64) + qq);
    ushort4 fb, cb;
    fb.x = f2bf(f.x); fb.y = f2bf(f.y); fb.z = f2bf(f.z); fb.w = f2bf(f.w);
    cb.x = f2bf(cv.x); cb.y = f2bf(cv.y); cb.z = f2bf(cv.z); cb.w = f2bf(cv.w);
    *((ushort4*)(Abf + r*136 + qq*4)) = fb;
    *((ushort4*)(Abf + r*136 + 64 + qq*4)) = cb;
  }
  __syncthreads();
  if (tid < 160) {
    int r = tid >> 1, h = tid & 1;
    const unsigned short* Ar = (const unsigned short*)(Abf + r*136) + h*32;
    const unsigned short* Xr = (const unsigned short*)(Abf + r*136 + 64) + h*32;
    float X2 = 0.f, XY = 0.f, Y2 = 0.f;
    for (int c2 = 0; c2 < 32; c2++) {
      float f = bf2f(Ar[c2]), xcv = bf2f(Xr[c2]);
      X2 = fmaf(f, f, X2); XY = fmaf(-f, xcv, XY); Y2 = fmaf(xcv, xcv, Y2);
    }
    X2 += __shfl_xor(X2, 1); XY += __shfl_xor(XY, 1); Y2 += __shfl_xor(Y2, 1);
    if (h == 0) {
      float den = fmaxf(1.0f + 0.02f*XY + 1e-4f*X2*Y2, 1e-15f);
      s1s[r] = (1.0f + 0.02f*XY + 0.01f*Y2) / den;
      s2s[r] = (1.0f - 0.01f*X2) / den;
    }
  }
  __syncthreads();
  for (int e = tid; e < 80*16; e += 256) {
    int r = e >> 4, qq = e & 15;
    ushort4 fr = *((const ushort4*)(Abf + r*136 + qq*4));
    ushort4 xr4 = *((const ushort4*)(Abf + r*136 + 64 + qq*4));
    float s1 = s1s[r], s2 = s2s[r];
    ushort4 mo;
    mo.x = f2bf(s1*bf2f(fr.x) - s2*bf2f(xr4.x));
    mo.y = f2bf(s1*bf2f(fr.y) - s2*bf2f(xr4.y));
    mo.z = f2bf(s1*bf2f(fr.z) - s2*bf2f(xr4.z));
    mo.w = f2bf(s1*bf2f(fr.w) - s2*bf2f(xr4.w));
    *((ushort4*)(Abf + r*136 + qq*4)) = mo;
  }
  __syncthreads();
  int wave = tid >> 6, lane = tid & 63;
  int quad = lane >> 4, lm = lane & 15;
  int colbase = wave*48;
  f32x4 acc[5][3];
  #pragma unroll
  for (int rt = 0; rt < 5; rt++)
    #pragma unroll
    for (int cj = 0; cj < 3; cj++) acc[rt][cj] = (f32x4){0.f, 0.f, 0.f, 0.f};
  #pragma unroll
  for (int kt = 0; kt < 4; kt++) {
    int k0 = kt*32 + quad*8;
    bf16x8 bf[3];
    #pragma unroll
    for (int cj = 0; cj < 3; cj++)
      bf[cj] = *((const bf16x8*)(w2h + (size_t)(colbase + cj*16 + lm)*128 + k0));
    bf16x8 af[5];
    #pragma unroll
    for (int rt = 0; rt < 5; rt++)
      af[rt] = *((const bf16x8*)(Abf + (rt*16 + lm)*136 + k0));
    #pragma unroll
    for (int rt = 0; rt < 5; rt++)
      #pragma unroll
      for (int cj = 0; cj < 3; cj++)
        acc[rt][cj] = __builtin_amdgcn_mfma_f32_16x16x32_bf16(af[rt], bf[cj], acc[rt][cj], 0, 0, 0);
  }
  #pragma unroll
  for (int cj = 0; cj < 3; cj++) {
    int o = colbase + cj*16 + lm;
    float s = 0.f, s2 = 0.f, mx = -__builtin_inff(), mn = __builtin_inff();
    #pragma unroll
    for (int rt = 0; rt < 5; rt++) {
      #pragma unroll
      for (int reg = 0; reg < 4; reg++) {
        float h = acc[rt][cj][reg];
        s += h; s2 += h*h;
        mx = fmaxf(mx, h); mn = fminf(mn, h);
      }
    }
    hmax2[(size_t)(p0 + quad)*192 + o] = mx;
    hmin2[(size_t)(p0 + quad)*192 + o] = mn;
    s  += __shfl_xor(s, 16);  s  += __shfl_xor(s, 32);
    s2 += __shfl_xor(s2, 16); s2 += __shfl_xor(s2, 32);
    if (lane < 16) {
      double* dst = stats2sh + ((size_t)(blockIdx.x & 63)*192 + o)*2;
      atomicAdd(dst, (double)s); atomicAdd(dst + 1, (double)s2);
    }
  }
}

// ---------- 11) conv3 via bf16 MFMA, A-tile staged directly from BN1/BN2 max/min ----------
__global__ void __launch_bounds__(256) k_conv3m(
   const float* __restrict__ hmax1, const float* __restrict__ hmin1,
   const float* __restrict__ scale1, const float* __restrict__ shift1,
   const float* __restrict__ hmax2, const float* __restrict__ hmin2,
   const float* __restrict__ scale2, const float* __restrict__ shift2,
   const unsigned short* __restrict__ wt3h, double* __restrict__ stats3sh,
   unsigned* __restrict__ hmax3u, unsigned* __restrict__ hmin3u) {
  __shared__ short As[64*264];
  int tid = threadIdx.x;
  int mt = blockIdx.x >> 2, cb = blockIdx.x & 3;
  int rowbase = mt*64;
  int b = rowbase >> 10;
  int c4 = tid & 63;
  float4 sc, sh;
  if (c4 < 16) {
    sc = *((const float4*)(scale1 + c4*4));
    sh = *((const float4*)(shift1 + c4*4));
  } else {
    sc = *((const float4*)(scale2 + (c4*4 - 64)));
    sh = *((const float4*)(shift2 + (c4*4 - 64)));
  }
  #pragma unroll 4
  for (int i = 0; i < 16; i++) {
    int r = (tid >> 6) + i*4;
    int p = rowbase + r;
    float4 hx, hn;
    if (c4 < 16) {
      hx = *((const float4*)(hmax1 + (size_t)p*64 + c4*4));
      hn = *((const float4*)(hmin1 + (size_t)p*64 + c4*4));
    } else {
      hx = *((const float4*)(hmax2 + (size_t)p*192 + (c4*4 - 64)));
      hn = *((const float4*)(hmin2 + (size_t)p*192 + (c4*4 - 64)));
    }
    ushort4 o4;
    o4.x = f2bf(fmaxf(fmaf(sc.x, (sc.x >= 0.f ? hx.x : hn.x), sh.x), 0.f));
    o4.y = f2bf(fmaxf(fmaf(sc.y, (sc.y >= 0.f ? hx.y : hn.y), sh.y), 0.f));
    o4.z = f2bf(fmaxf(fmaf(sc.z, (sc.z >= 0.f ? hx.z : hn.z), sh.z), 0.f));
    o4.w = f2bf(fmaxf(fmaf(sc.w, (sc.w >= 0.f ? hx.w : hn.w), sh.w), 0.f));
    *((ushort4*)(As + r*264 + c4*4)) = o4;
  }
  __syncthreads();
  int wave = tid >> 6, lane = tid & 63;
  int quad = lane >> 4, lm = lane & 15;
  int colbase = cb*256 + wave*64;
  f32x4 acc[4][4];
  #pragma unroll
  for (int ri = 0; ri < 4; ri++)
    #pragma unroll
    for (int cj = 0; cj < 4; cj++) acc[ri][cj] = (f32x4){0.f, 0.f, 0.f, 0.f};
  for (int kt = 0; kt < 8; kt++) {
    int k0 = kt*32 + quad*8;
    bf16x8 bf[4];
    #pragma unroll
    for (int cj = 0; cj < 4; cj++)
      bf[cj] = *((const bf16x8*)(wt3h + (size_t)(colbase + cj*16 + lm)*256 + k0));
    bf16x8 af[4];
    #pragma unroll
    for (int ri = 0; ri < 4; ri++)
      af[ri] = *((const bf16x8*)(As + (ri*16 + lm)*264 + k0));
    #pragma unroll
    for (int ri = 0; ri < 4; ri++)
      #pragma unroll
      for (int cj = 0; cj < 4; cj++)
        acc[ri][cj] = __builtin_amdgcn_mfma_f32_16x16x32_bf16(af[ri], bf[cj], acc[ri][cj], 0, 0, 0);
  }
  #pragma unroll
  for (int cj = 0; cj < 4; cj++) {
    float s = 0.f, s2 = 0.f, mx = -__builtin_inff(), mn = __builtin_inff();
    #pragma unroll
    for (int ri = 0; ri < 4; ri++) {
      #pragma unroll
      for (int reg = 0; reg < 4; reg++) {
        float h = acc[ri][cj][reg];
        s += h; s2 += h*h; mx = fmaxf(mx, h); mn = fminf(mn, h);
      }
    }
    s  += __shfl_xor(s, 16);  s  += __shfl_xor(s, 32);
    s2 += __shfl_xor(s2, 16); s2 += __shfl_xor(s2, 32);
    mx = fmaxf(mx, __shfl_xor(mx, 16)); mx = fmaxf(mx, __shfl_xor(mx, 32));
    mn = fminf(mn, __shfl_xor(mn, 16)); mn = fminf(mn, __shfl_xor(mn, 32));
    if (lane < 16) {
      int col = colbase + cj*16 + lane;
      double* dst = stats3sh + ((size_t)(blockIdx.x & 63)*1024 + col)*2;
      atomicAdd(dst, (double)s);
      atomicAdd(dst + 1, (double)s2);
      atomicMax(hmax3u + b*1024 + col, fkey(mx));
      atomicMin(hmin3u + b*1024 + col, fkey(mn));
    }
  }
}

// ---------- 12) head ----------
__device__ float blk_reduce(float v, float* red, int tid) {
  red[tid] = v; __syncthreads();
  for (int st = 128; st > 0; st >>= 1) {
    if (tid < st) red[tid] += red[tid + st];
    __syncthreads();
  }
  float r = red[0]; __syncthreads();
  return r;
}

__global__ void __launch_bounds__(256) k_head(const unsigned* __restrict__ hmax3u, const unsigned* __restrict__ hmin3u,
    const float* __restrict__ scale3, const float* __restrict__ shift3,
    const float* __restrict__ fc1w, const float* __restrict__ fc1b,
    const float* __restrict__ ln1g, const float* __restrict__ ln1b,
    const float* __restrict__ fc2w, const float* __restrict__ fc2b,
    const float* __restrict__ ln2g, const float* __restrict__ ln2b,
    const float* __restrict__ outw, const float* __restrict__ outb,
    float* __restrict__ out) {
  __shared__ __align__(16) float V[1024];
  __shared__ __align__(16) float H1[512];
  __shared__ __align__(16) float H2[256];
  __shared__ float red[256];
  int b = blockIdx.x, tid = threadIdx.x;
  for (int o = tid; o < 1024; o += 256) {
    float a = scale3[o];
    unsigned u = (a >= 0.f) ? hmax3u[b*1024 + o] : hmin3u[b*1024 + o];
    float h = fkeyinv(u);
    V[o] = fmaxf(fmaf(a, h, shift3[o]), 0.f);
  }
  __syncthreads();
  float h1v[2];
  #pragma unroll
  for (int ii = 0; ii < 2; ii++) {
    int o = tid + ii*256;
    const float4* wr = (const float4*)(fc1w + (size_t)o*1024);
    float s = 0.f;
    for (int c4 = 0; c4 < 256; c4++) {
      float4 w = wr[c4]; float4 vv = ((const float4*)V)[c4];
      s = fmaf(w.x, vv.x, s); s = fmaf(w.y, vv.y, s);
      s = fmaf(w.z, vv.z, s); s = fmaf(w.w, vv.w, s);
    }
    h1v[ii] = s + fc1b[o];
  }
  float s = h1v[0] + h1v[1];
  float s2 = h1v[0]*h1v[0] + h1v[1]*h1v[1];
  s = blk_reduce(s, red, tid);
  s2 = blk_reduce(s2, red, tid);
  float m = s / 512.f;
  float var = s2 / 512.f - m*m;
  float inv = 1.0f / sqrtf(var + 1e-5f);
  #pragma unroll
  for (int ii = 0; ii < 2; ii++) {
    int o = tid + ii*256;
    H1[o] = fmaxf((h1v[ii] - m)*inv*ln1g[o] + ln1b[o], 0.f);
  }
  __syncthreads();
  float h2v;
  {
    const float4* wr = (const float4*)(fc2w + (size_t)tid*512);
    float t = 0.f;
    for (int c4 = 0; c4 < 128; c4++) {
      float4 w = wr[c4]; float4 vv = ((const float4*)H1)[c4];
      t = fmaf(w.x, vv.x, t); t = fmaf(w.y, vv.y, t);
      t = fmaf(w.z, vv.z, t); t = fmaf(w.w, vv.w, t);
    }
    h2v = t + fc2b[tid];
  }
  float ss = blk_reduce(h2v, red, tid);
  float ss2 = blk_reduce(h2v*h2v, red, tid);
  float m2 = ss / 256.f;
  float var2 = ss2 / 256.f - m2*m2;
  float inv2 = 1.0f / sqrtf(var2 + 1e-5f);
  H2[tid] = fmaxf((h2v - m2)*inv2*ln2g[tid] + ln2b[tid], 0.f);
  __syncthreads();
  if (tid < 40) {
    const float4* wr = (const float4*)(outw + (size_t)tid*256);
    float t = 0.f;
    for (int c4 = 0; c4 < 64; c4++) {
      float4 w = wr[c4]; float4 vv = ((const float4*)H2)[c4];
      t = fmaf(w.x, vv.x, t); t = fmaf(w.y, vv.y, t);
      t = fmaf(w.z, vv.z, t); t = fmaf(w.w, vv.w, t);
    }
    red[tid] = t + outb[tid];
  }
  __syncthreads();
  if (tid == 0) {
    float mx = -__builtin_inff();
    for (int i2 = 0; i2 < 40; i2++) mx = fmaxf(mx, red[i2]);
    float se = 0.f;
    for (int i2 = 0; i2 < 40; i2++) se += expf(red[i2] - mx);
    float lse = mx + logf(se);
    for (int i2 = 0; i2 < 40; i2++) out[b*40 + i2] = red[i2] - lse;
  }
}

extern "C" void kernel_launch(void* const* d_in, const int* in_sizes, int n_in,
                              void* d_out, int out_size, void* d_ws, size_t ws_size,
                              hipStream_t stream) {
  (void)in_sizes; (void)n_in; (void)out_size; (void)ws_size;
  const float* x    = (const float*)d_in[0];
  const float* w1   = (const float*)d_in[1];
  const float* bn1g = (const float*)d_in[2];
  const float* bn1b = (const float*)d_in[3];
  const float* w2   = (const float*)d_in[4];
  const float* bn2g = (const float*)d_in[5];
  const float* bn2b = (const float*)d_in[6];
  const float* w3   = (const float*)d_in[7];
  const float* bn3g = (const float*)d_in[8];
  const float* bn3b = (const float*)d_in[9];
  const float* fc1w = (const float*)d_in[10];
  const float* fc1b = (const float*)d_in[11];
  const float* ln1g = (const float*)d_in[12];
  const float* ln1b = (const float*)d_in[13];
  const float* fc2w = (const float*)d_in[14];
  const float* fc2b = (const float*)d_in[15];
  const float* ln2g = (const float*)d_in[16];
  const float* ln2b = (const float*)d_in[17];
  const float* outw = (const float*)d_in[18];
  const float* outb = (const float*)d_in[19];
  float* out = (float*)d_out;

  float* ws = (float*)d_ws;
  size_t off = 0;
  float* xp1   = ws + off; off += 49152;
  int*   idx1  = (int*)(ws + off); off += 327680;
  float* hmax1 = ws + off; off += 1048576;
  float* hmin1 = ws + off; off += 1048576;
  float* xp2   = ws + off; off += 1048576;
  float* hmax2 = ws + off; off += 3145728;   // also keypart (knn partials)
  float* hmin2 = ws + off; off += 3145728;
  int*   idx2  = (int*)(ws + off); off += 327680;
  unsigned short* w2h = (unsigned short*)(ws + off); off += 24576;
  unsigned short* wt3h = (unsigned short*)(ws + off); off += 131072;
  float* x1T   = ws + off; off += 1048576;
  float* xx1   = ws + off; off += 16384;
  float* scale1 = ws + off; off += 64;
  float* shift1 = ws + off; off += 64;
  float* scale2 = ws + off; off += 192;
  float* shift2 = ws + off; off += 192;
  float* scale3 = ws + off; off += 1024;
  float* shift3 = ws + off; off += 1024;
  double* stats1sh = (double*)(ws + off);
  double* stats2sh = stats1sh + 64*64*2;
  double* stats3sh = stats2sh + 64*192*2;
  unsigned* hmax3u = (unsigned*)(stats3sh + (size_t)64*1024*2);
  unsigned* hmin3u = hmax3u + 16384;
  unsigned* keypart = (unsigned*)hmax2;

  size_t zero_bytes = ((size_t)64*64*2 + (size_t)64*192*2 + (size_t)64*1024*2)*8 + (size_t)16384*4;
  hipMemsetAsync(stats1sh, 0, zero_bytes, stream);
  hipMemsetAsync(hmin3u, 0xFF, (size_t)16384*4, stream);

  k_prep<<<1024, 256, 0, stream>>>(x, xp1, w2, w3, w2h, wt3h);
  k_knn1_part<<<512, 256, 0, stream>>>(x, keypart);
  k_knn_merge<8><<<256, 64, 0, stream>>>(keypart, idx1);
  k_conv1<<<1024, 256, 0, stream>>>(xp1, idx1, w1, hmax1, hmin1, stats1sh);
  k_bn_reduce<<<1, 64, 0, stream>>>(stats1sh, 64, 64, 327680.0, bn1g, bn1b, scale1, shift1);
  k_bn1_apply<<<256, 256, 0, stream>>>(hmax1, hmin1, scale1, shift1, xp2, x1T, xx1);
  k_knn2g<<<1024, 256, 0, stream>>>(x1T, xx1, keypart);
  k_knn_merge<4><<<256, 64, 0, stream>>>(keypart, idx2);
  k_conv2m<<<4096, 256, 0, stream>>>(xp2, idx2, w2h, hmax2, hmin2, stats2sh);
  k_bn_reduce<<<1, 192, 0, stream>>>(stats2sh, 64, 192, 327680.0, bn2g, bn2b, scale2, shift2);
  k_conv3m<<<1024, 256, 0, stream>>>(hmax1, hmin1, scale1, shift1, hmax2, hmin2, scale2, shift2,
                                     wt3h, stats3sh, hmax3u, hmin3u);
  k_bn_reduce<<<4, 256, 0, stream>>>(stats3sh, 64, 1024, 16384.0, bn3g, bn3b, scale3, shift3);
  k_head<<<16, 256, 0, stream>>>(hmax3u, hmin3u, scale3, shift3,
                                 fc1w, fc1b, ln1g, ln1b,
                                 fc2w, fc2b, ln2g, ln2b,
                                 outw, outb, out);
}

// Round 13
// 432.852 us; speedup vs baseline: 1.5303x; 1.1544x over previous
//
#include <hip/hip_runtime.h>
#include <math.h>

#define B_ 16
#define N_ 1024
#define KNN 20
#define NPAIR (B_*N_)

typedef __attribute__((ext_vector_type(8))) short bf16x8;
typedef __attribute__((ext_vector_type(4))) float f32x4;

// ---------- helpers ----------
__device__ __forceinline__ unsigned fkey(float f) {
  unsigned u = __float_as_uint(f);
  return (u & 0x80000000u) ? ~u : (u | 0x80000000u);
}
__device__ __forceinline__ float fkeyinv(unsigned u) {
  unsigned b = (u & 0x80000000u) ? (u ^ 0x80000000u) : ~u;
  return __uint_as_float(b);
}
__device__ __forceinline__ unsigned short f2bf(float x) {  // RNE float->bf16
  unsigned u = __float_as_uint(x);
  unsigned r = (u + 0x7FFFu + ((u >> 16) & 1u)) >> 16;
  return (unsigned short)r;
}
__device__ __forceinline__ float bf2f(unsigned short u) {
  return __uint_as_float(((unsigned)u) << 16);
}
// packed knn key: top 22 bits of fkey(d) | (1023 - idx). u32 '>' == dist desc, idx asc.
__device__ __forceinline__ unsigned knnkey(float d, int idx) {
  return (fkey(d) & 0xFFFFFC00u) | (unsigned)(1023 - idx);
}

// Branchless sorted-insert (descending) of packed u32 key: 2 ops/stage.
__device__ __forceinline__ void topk_insert_u32(unsigned (&kl)[KNN], unsigned nk) {
  kl[KNN-1] = nk;
  #pragma unroll
  for (int i = KNN-1; i > 0; i--) {
    unsigned hi = max(kl[i-1], kl[i]);
    unsigned lo = min(kl[i-1], kl[i]);
    kl[i-1] = hi; kl[i] = lo;
  }
}

// ---------- 1) prep: e2p of raw points + weight bf16 conversions ----------
__global__ void k_prep(const float* __restrict__ x, float* __restrict__ xp1,
                       const float* __restrict__ w2, const float* __restrict__ w3,
                       unsigned short* __restrict__ w2h, unsigned short* __restrict__ wt3h) {
  int i = blockIdx.x * 256 + threadIdx.x;
  if (i < NPAIR) {
    float a0 = x[i*3+0], a1 = x[i*3+1], a2 = x[i*3+2];
    float n = sqrtf(a0*a0 + a1*a1 + a2*a2);
    n = fmaxf(n, 1e-15f);
    float th = tanhf(0.1f * n);
    float sc = th / (0.1f * n);
    float ny = fmaxf(th * 10.0f, 1e-15f);
    float mxn = (1.0f - 4e-3f) / 0.1f;
    if (ny > mxn) sc *= mxn / ny;
    xp1[i*3+0] = sc*a0; xp1[i*3+1] = sc*a1; xp1[i*3+2] = sc*a2;
  }
  if (i < 192*128) w2h[i] = f2bf(w2[i]);
  wt3h[i] = f2bf(w3[i]);
}

// ---------- 2) knn on raw 3-d points: 8-way candidate split, packed keys ----------
__global__ void __launch_bounds__(256) k_knn1_part(const float* __restrict__ x,
        unsigned* __restrict__ keypart) {
  __shared__ float P[N_*3];
  __shared__ float XX[N_];
  int blk = blockIdx.x;
  int b = blk >> 5, rc = (blk >> 3) & 3, cc = blk & 7;
  const float* xb = x + b*N_*3;
  for (int e = threadIdx.x; e < N_*3; e += 256) P[e] = xb[e];
  __syncthreads();
  for (int j = threadIdx.x; j < N_; j += 256) {
    float q0 = P[j*3], q1 = P[j*3+1], q2 = P[j*3+2];
    XX[j] = q0*q0 + q1*q1 + q2*q2;
  }
  __syncthreads();
  int r = rc*256 + threadIdx.x;
  float q0 = P[r*3], q1 = P[r*3+1], q2 = P[r*3+2];
  float xxq = XX[r];
  unsigned kl[KNN];
  #pragma unroll
  for (int i = 0; i < KNN; i++) kl[i] = 0u;
  int cbase = cc*128;
  for (int jj = 0; jj < 128; jj++) {
    int j = cbase + jj;
    float dot = q0*P[j*3] + q1*P[j*3+1] + q2*P[j*3+2];
    float d = 2.0f*dot - xxq - XX[j];
    unsigned nk = knnkey(d, j);
    if (nk > kl[KNN-1]) topk_insert_u32(kl, nk);
  }
  int p = b*N_ + r;
  unsigned* pe = keypart + (size_t)p*160 + cc*20;
  #pragma unroll
  for (int i = 0; i < KNN; i++) pe[i] = kl[i];
}

// ---------- 3) conv1 fused ----------
__global__ void __launch_bounds__(256) k_conv1(const float* __restrict__ xp1, const int* __restrict__ idx1,
                        const float* __restrict__ w1, float* __restrict__ hmax1,
                        float* __restrict__ hmin1, double* __restrict__ stats1sh) {
  __shared__ float F[4][KNN][6];
  __shared__ float red[4][64][2];
  int g = threadIdx.x >> 6, lane = threadIdx.x & 63;
  float w[6];
  #pragma unroll
  for (int c = 0; c < 6; c++) w[c] = w1[lane*6 + c];
  float sum = 0.f, sumsq = 0.f;
  int pbase = blockIdx.x * 16;
  for (int it = 0; it < 4; ++it) {
    int p = pbase + it*4 + g;
    if (lane < KNN) {
      int nb = idx1[p*KNN + lane];
      int bb = p >> 10;
      const float* xc = xp1 + p*3;
      const float* ft = xp1 + (bb*N_ + nb)*3;
      float x0 = ft[0], x1 = ft[1], x2v = ft[2];
      float c0 = xc[0], c1 = xc[1], c2 = xc[2];
      float X2 = x0*x0 + x1*x1 + x2v*x2v;
      float Y2 = c0*c0 + c1*c1 + c2*c2;
      float XY = -(x0*c0 + x1*c1 + x2v*c2);
      float den = fmaxf(1.0f + 0.02f*XY + 1e-4f*X2*Y2, 1e-15f);
      float s1 = (1.0f + 0.02f*XY + 0.01f*Y2) / den;
      float s2 = (1.0f - 0.01f*X2) / den;
      F[g][lane][0] = s1*x0 - s2*c0;
      F[g][lane][1] = s1*x1 - s2*c1;
      F[g][lane][2] = s1*x2v - s2*c2;
      F[g][lane][3] = c0; F[g][lane][4] = c1; F[g][lane][5] = c2;
    }
    __syncthreads();
    float mx = -__builtin_inff(), mn = __builtin_inff();
    for (int k = 0; k < KNN; k++) {
      float h = 0.f;
      #pragma unroll
      for (int c = 0; c < 6; c++) h = fmaf(w[c], F[g][k][c], h);
      mx = fmaxf(mx, h); mn = fminf(mn, h);
      sum += h; sumsq += h*h;
    }
    hmax1[p*64 + lane] = mx;
    hmin1[p*64 + lane] = mn;
    __syncthreads();
  }
  red[g][lane][0] = sum; red[g][lane][1] = sumsq;
  __syncthreads();
  if (g == 0) {
    float s  = red[0][lane][0] + red[1][lane][0] + red[2][lane][0] + red[3][lane][0];
    float s2 = red[0][lane][1] + red[1][lane][1] + red[2][lane][1] + red[3][lane][1];
    double* dst = stats1sh + ((size_t)(blockIdx.x & 63)*64 + lane)*2;
    atomicAdd(dst, (double)s);
    atomicAdd(dst + 1, (double)s2);
  }
}

// ---------- BN stat reduce ----------
__global__ void k_bn_reduce(const double* __restrict__ sh, int nsh, int nch, double cnt,
                            const float* __restrict__ g, const float* __restrict__ bb,
                            float* __restrict__ scale, float* __restrict__ shift) {
  int o = blockIdx.x * blockDim.x + threadIdx.x;
  if (o >= nch) return;
  double s = 0.0, s2 = 0.0;
  for (int i = 0; i < nsh; i++) {
    s  += sh[((size_t)i*nch + o)*2];
    s2 += sh[((size_t)i*nch + o)*2 + 1];
  }
  double m = s / cnt;
  double v = s2 / cnt - m*m;
  float a = g[o] / sqrtf((float)v + 1e-5f);
  scale[o] = a;
  shift[o] = bb[o] - a * (float)m;
}

// ---------- 5) BN1 apply + relu + e2p + coalesced x1T transpose + |x1|^2 ----------
__global__ void __launch_bounds__(256) k_bn1_apply(const float* __restrict__ hmax1, const float* __restrict__ hmin1,
                            const float* __restrict__ scale1, const float* __restrict__ shift1,
                            float* __restrict__ xp2,
                            float* __restrict__ x1T, float* __restrict__ xx1) {
  int b = blockIdx.x >> 4, nc = blockIdx.x & 15;
  int c = threadIdx.x & 63, sub = threadIdx.x >> 6;
  int n0 = nc*64 + sub*16;
  float a = scale1[c], t = shift1[c];
  float xr[16];
  #pragma unroll
  for (int i = 0; i < 16; i++) {
    int p = b*1024 + n0 + i;
    float h = (a >= 0.f) ? hmax1[(size_t)p*64 + c] : hmin1[(size_t)p*64 + c];
    float x1 = fmaxf(fmaf(a, h, t), 0.f);
    xr[i] = x1;
    float n2 = x1*x1;
    #pragma unroll
    for (int off = 32; off > 0; off >>= 1) n2 += __shfl_xor(n2, off);
    if (c == 0) xx1[p] = n2;
    float n1 = fmaxf(sqrtf(n2), 1e-15f);
    float th = tanhf(0.1f * n1);
    float sc = th / (0.1f * n1);
    float ny = fmaxf(th * 10.0f, 1e-15f);
    float mxn = (1.0f - 4e-3f) / 0.1f;
    if (ny > mxn) sc *= mxn / ny;
    xp2[(size_t)p*64 + c] = sc * x1;
  }
  float* dst = x1T + ((size_t)(b*64 + c))*1024 + n0;
  #pragma unroll
  for (int q = 0; q < 4; q++) {
    float4 v; v.x = xr[q*4]; v.y = xr[q*4+1]; v.z = xr[q*4+2]; v.w = xr[q*4+3];
    *((float4*)(dst + q*4)) = v;
  }
}

// ---------- 6) knn2 v5: 4-way split, packed-u32 selection ----------
__global__ void __launch_bounds__(256) k_knn2g(const float* __restrict__ x1T,
        const float* __restrict__ xx1, unsigned* __restrict__ keypart) {
  __shared__ __align__(16) float SM[8192];   // As @0 (64x64), BsD @4096 (64x64)
  float* As = SM;
  float* BsD = SM + 4096;
  int tid = threadIdx.x;
  int blk = blockIdx.x;
  int b = blk >> 6, qc = (blk >> 2) & 15, cc = blk & 3;
  int qbase = qc*64, ccbase = cc*256;
  int tx = tid & 15, ty = tid >> 4;
  int wave = tid >> 6, lane = tid & 63;
  #pragma unroll
  for (int r = 0; r < 4; r++) {
    int e = tid + r*256;
    int k = e >> 4, qf = e & 15;
    *((float4*)(As + k*64 + qf*4)) =
      *((const float4*)(x1T + ((size_t)(b*64 + k))*1024 + qbase + qf*4));
  }
  unsigned kl[KNN];
  #pragma unroll
  for (int i = 0; i < KNN; i++) kl[i] = 0u;
  int cq = lane + (lane >> 2);

  for (int st = 0; st < 4; ++st) {
    int cb0 = ccbase + st*64;
    __syncthreads();
    #pragma unroll
    for (int r = 0; r < 4; r++) {
      int e = tid + r*256;
      int k = e >> 4, cf = e & 15;
      *((float4*)(BsD + k*64 + cf*4)) =
        *((const float4*)(x1T + ((size_t)(b*64 + k))*1024 + cb0 + cf*4));
    }
    float4 xxc = *((const float4*)(xx1 + b*1024 + cb0 + ty*4));
    __syncthreads();
    float acc[4][4];
    #pragma unroll
    for (int i = 0; i < 4; i++)
      #pragma unroll
      for (int j = 0; j < 4; j++) acc[i][j] = 0.f;
    #pragma unroll 4
    for (int k = 0; k < 64; k++) {
      float4 a4 = *((const float4*)(As + k*64 + tx*4));
      float4 b4 = *((const float4*)(BsD + k*64 + ty*4));
      float av[4] = {a4.x, a4.y, a4.z, a4.w};
      float bw[4] = {b4.x, b4.y, b4.z, b4.w};
      #pragma unroll
      for (int i = 0; i < 4; i++)
        #pragma unroll
        for (int j = 0; j < 4; j++) acc[i][j] = fmaf(av[i], bw[j], acc[i][j]);
    }
    __syncthreads();
    float xxv[4] = {xxc.x, xxc.y, xxc.z, xxc.w};
    #pragma unroll
    for (int i = 0; i < 4; i++) {
      int q = tx*4 + i;
      #pragma unroll
      for (int j = 0; j < 4; j++) {
        int c = ty*4 + j;
        BsD[q*64 + ((c + q + (q >> 2)) & 63)] = 2.0f*acc[i][j] - xxv[j];
      }
    }
    __syncthreads();
    #pragma unroll
    for (int j = 0; j < 16; j++) {
      int c = wave*16 + j;
      float d = BsD[lane*64 + ((c + cq) & 63)];
      unsigned nk = knnkey(d, cb0 + c);
      if (nk > kl[KNN-1]) topk_insert_u32(kl, nk);
    }
  }
  __syncthreads();
  unsigned* U = (unsigned*)SM;
  unsigned* L0 = U;
  unsigned* L1 = U + 1344;
  unsigned* M  = U + 2688;
  if (wave == 0) {
    #pragma unroll
    for (int i = 0; i < KNN; i++) L0[lane*21 + i] = kl[i];
  } else if (wave == 1) {
    #pragma unroll
    for (int i = 0; i < KNN; i++) L1[lane*21 + i] = kl[i];
  }
  __syncthreads();
  if (tid < 64) {
    int ia = 0, ib = 0;
    for (int t = 0; t < KNN; t++) {
      unsigned pa = L0[tid*21 + ia], pb = L1[tid*21 + ib];
      bool ta = pa > pb;
      M[tid*21 + t] = ta ? pa : pb;
      if (ta) ia++; else ib++;
    }
  }
  __syncthreads();
  if (wave == 2) {
    #pragma unroll
    for (int i = 0; i < KNN; i++) L0[lane*21 + i] = kl[i];
  } else if (wave == 3) {
    #pragma unroll
    for (int i = 0; i < KNN; i++) L1[lane*21 + i] = kl[i];
  }
  __syncthreads();
  if (tid < 64) {
    int p = b*N_ + qbase + tid;
    unsigned* pe = keypart + (size_t)p*80 + cc*20;
    int ia = 0, ib = 0, im = 0;
    for (int t = 0; t < KNN; t++) {
      unsigned pa = L0[tid*21 + ia], pb = L1[tid*21 + ib], pm = M[tid*21 + im];
      unsigned bp = pm; int sel = 2;
      if (pa > bp) { bp = pa; sel = 0; }
      if (pb > bp) { bp = pb; sel = 1; }
      pe[t] = bp;
      if (sel == 0) ia++; else if (sel == 1) ib++; else im++;
    }
  }
}

// ---------- 7) generic merge of NCH sorted top-20 u32-key chunks -> indices ----------
template<int NCH>
__global__ void k_knn_merge(const unsigned* __restrict__ keypart, int* __restrict__ idxo) {
  int p = blockIdx.x*blockDim.x + threadIdx.x;
  if (p >= NPAIR) return;
  const unsigned* pe = keypart + (size_t)p*(NCH*20);
  int pos[NCH];
  #pragma unroll
  for (int c = 0; c < NCH; c++) pos[c] = 0;
  int* outp = idxo + p*KNN;
  for (int t = 0; t < KNN; t++) {
    unsigned best = 0u; int bc = 0;
    #pragma unroll
    for (int c = 0; c < NCH; c++) {
      if (pos[c] < KNN) {
        unsigned v = pe[c*20 + pos[c]];
        if (v > best) { best = v; bc = c; }
      }
    }
    outp[t] = 1023 - (int)(best & 1023u);
    #pragma unroll
    for (int c = 0; c < NCH; c++) if (bc == c) pos[c]++;
  }
}

// ---------- 9) conv2 via bf16 MFMA v3: permuted rows (quad == pair), register epilogue ----------
__global__ void __launch_bounds__(256) k_conv2m(const float* __restrict__ xp2,
    const int* __restrict__ idx2, const unsigned short* __restrict__ w2h,
    float* __restrict__ hmax2, float* __restrict__ hmin2, double* __restrict__ stats2sh) {
  __shared__ __align__(16) short Abf[80*136];
  __shared__ float s1s[80], s2s[80];
  __shared__ int nbr[80];
  int tid = threadIdx.x;
  int p0 = blockIdx.x * 4;
  int b = p0 >> 10;
  if (tid < 80) nbr[tid] = idx2[p0*KNN + tid];
  __syncthreads();
  for (int e = tid; e < 80*16; e += 256) {
    int r = e >> 4, qq = e & 15;
    int q = (r >> 2) & 3;
    int L = 20*q + 4*(r >> 4) + (r & 3);
    float4 f = *((const float4*)(xp2 + (size_t)(b*N_ + nbr[L])*64) + qq);
    float4 cv = *((const float4*)(xp2 + (size_t)(p0 + q)*64) + qq);
    ushort4 fb, cb;
    fb.x = f2bf(f.x); fb.y = f2bf(f.y); fb.z = f2bf(f.z); fb.w = f2bf(f.w);
    cb.x = f2bf(cv.x); cb.y = f2bf(cv.y); cb.z = f2bf(cv.z); cb.w = f2bf(cv.w);
    *((ushort4*)(Abf + r*136 + qq*4)) = fb;
    *((ushort4*)(Abf + r*136 + 64 + qq*4)) = cb;
  }
  __syncthreads();
  if (tid < 160) {
    int r = tid >> 1, h = tid & 1;
    const unsigned short* Ar = (const unsigned short*)(Abf + r*136) + h*32;
    const unsigned short* Xr = (const unsigned short*)(Abf + r*136 + 64) + h*32;
    float X2 = 0.f, XY = 0.f, Y2 = 0.f;
    for (int c2 = 0; c2 < 32; c2++) {
      float f = bf2f(Ar[c2]), xcv = bf2f(Xr[c2]);
      X2 = fmaf(f, f, X2); XY = fmaf(-f, xcv, XY); Y2 = fmaf(xcv, xcv, Y2);
    }
    X2 += __shfl_xor(X2, 1); XY += __shfl_xor(XY, 1); Y2 += __shfl_xor(Y2, 1);
    if (h == 0) {
      float den = fmaxf(1.0f + 0.02f*XY + 1e-4f*X2*Y2, 1e-15f);
      s1s[r] = (1.0f + 0.02f*XY + 0.01f*Y2) / den;
      s2s[r] = (1.0f - 0.01f*X2) / den;
    }
  }
  __syncthreads();
  for (int e = tid; e < 80*16; e += 256) {
    int r = e >> 4, qq = e & 15;
    ushort4 fr = *((const ushort4*)(Abf + r*136 + qq*4));
    ushort4 xr4 = *((const ushort4*)(Abf + r*136 + 64 + qq*4));
    float s1 = s1s[r], s2 = s2s[r];
    ushort4 mo;
    mo.x = f2bf(s1*bf2f(fr.x) - s2*bf2f(xr4.x));
    mo.y = f2bf(s1*bf2f(fr.y) - s2*bf2f(xr4.y));
    mo.z = f2bf(s1*bf2f(fr.z) - s2*bf2f(xr4.z));
    mo.w = f2bf(s1*bf2f(fr.w) - s2*bf2f(xr4.w));
    *((ushort4*)(Abf + r*136 + qq*4)) = mo;
  }
  __syncthreads();
  int wave = tid >> 6, lane = tid & 63;
  int quad = lane >> 4, lm = lane & 15;
  int colbase = wave*48;
  f32x4 acc[5][3];
  #pragma unroll
  for (int rt = 0; rt < 5; rt++)
    #pragma unroll
    for (int cj = 0; cj < 3; cj++) acc[rt][cj] = (f32x4){0.f, 0.f, 0.f, 0.f};
  #pragma unroll
  for (int kt = 0; kt < 4; kt++) {
    int k0 = kt*32 + quad*8;
    bf16x8 bf[3];
    #pragma unroll
    for (int cj = 0; cj < 3; cj++)
      bf[cj] = *((const bf16x8*)(w2h + (size_t)(colbase + cj*16 + lm)*128 + k0));
    bf16x8 af[5];
    #pragma unroll
    for (int rt = 0; rt < 5; rt++)
      af[rt] = *((const bf16x8*)(Abf + (rt*16 + lm)*136 + k0));
    #pragma unroll
    for (int rt = 0; rt < 5; rt++)
      #pragma unroll
      for (int cj = 0; cj < 3; cj++)
        acc[rt][cj] = __builtin_amdgcn_mfma_f32_16x16x32_bf16(af[rt], bf[cj], acc[rt][cj], 0, 0, 0);
  }
  #pragma unroll
  for (int cj = 0; cj < 3; cj++) {
    int o = colbase + cj*16 + lm;
    float s = 0.f, s2 = 0.f, mx = -__builtin_inff(), mn = __builtin_inff();
    #pragma unroll
    for (int rt = 0; rt < 5; rt++) {
      #pragma unroll
      for (int reg = 0; reg < 4; reg++) {
        float h = acc[rt][cj][reg];
        s += h; s2 += h*h;
        mx = fmaxf(mx, h); mn = fminf(mn, h);
      }
    }
    hmax2[(size_t)(p0 + quad)*192 + o] = mx;
    hmin2[(size_t)(p0 + quad)*192 + o] = mn;
    s  += __shfl_xor(s, 16);  s  += __shfl_xor(s, 32);
    s2 += __shfl_xor(s2, 16); s2 += __shfl_xor(s2, 32);
    if (lane < 16) {
      double* dst = stats2sh + ((size_t)(blockIdx.x & 63)*192 + o)*2;
      atomicAdd(dst, (double)s); atomicAdd(dst + 1, (double)s2);
    }
  }
}

// ---------- 11) conv3 via bf16 MFMA, A-tile staged directly from BN1/BN2 max/min ----------
__global__ void __launch_bounds__(256) k_conv3m(
   const float* __restrict__ hmax1, const float* __restrict__ hmin1,
   const float* __restrict__ scale1, const float* __restrict__ shift1,
   const float* __restrict__ hmax2, const float* __restrict__ hmin2,
   const float* __restrict__ scale2, const float* __restrict__ shift2,
   const unsigned short* __restrict__ wt3h, double* __restrict__ stats3sh,
   unsigned* __restrict__ hmax3u, unsigned* __restrict__ hmin3u) {
  __shared__ short As[64*264];
  int tid = threadIdx.x;
  int mt = blockIdx.x >> 2, cb = blockIdx.x & 3;
  int rowbase = mt*64;
  int b = rowbase >> 10;
  int c4 = tid & 63;
  float4 sc, sh;
  if (c4 < 16) {
    sc = *((const float4*)(scale1 + c4*4));
    sh = *((const float4*)(shift1 + c4*4));
  } else {
    sc = *((const float4*)(scale2 + (c4*4 - 64)));
    sh = *((const float4*)(shift2 + (c4*4 - 64)));
  }
  #pragma unroll 4
  for (int i = 0; i < 16; i++) {
    int r = (tid >> 6) + i*4;
    int p = rowbase + r;
    float4 hx, hn;
    if (c4 < 16) {
      hx = *((const float4*)(hmax1 + (size_t)p*64 + c4*4));
      hn = *((const float4*)(hmin1 + (size_t)p*64 + c4*4));
    } else {
      hx = *((const float4*)(hmax2 + (size_t)p*192 + (c4*4 - 64)));
      hn = *((const float4*)(hmin2 + (size_t)p*192 + (c4*4 - 64)));
    }
    ushort4 o4;
    o4.x = f2bf(fmaxf(fmaf(sc.x, (sc.x >= 0.f ? hx.x : hn.x), sh.x), 0.f));
    o4.y = f2bf(fmaxf(fmaf(sc.y, (sc.y >= 0.f ? hx.y : hn.y), sh.y), 0.f));
    o4.z = f2bf(fmaxf(fmaf(sc.z, (sc.z >= 0.f ? hx.z : hn.z), sh.z), 0.f));
    o4.w = f2bf(fmaxf(fmaf(sc.w, (sc.w >= 0.f ? hx.w : hn.w), sh.w), 0.f));
    *((ushort4*)(As + r*264 + c4*4)) = o4;
  }
  __syncthreads();
  int wave = tid >> 6, lane = tid & 63;
  int quad = lane >> 4, lm = lane & 15;
  int colbase = cb*256 + wave*64;
  f32x4 acc[4][4];
  #pragma unroll
  for (int ri = 0; ri < 4; ri++)
    #pragma unroll
    for (int cj = 0; cj < 4; cj++) acc[ri][cj] = (f32x4){0.f, 0.f, 0.f, 0.f};
  for (int kt = 0; kt < 8; kt++) {
    int k0 = kt*32 + quad*8;
    bf16x8 bf[4];
    #pragma unroll
    for (int cj = 0; cj < 4; cj++)
      bf[cj] = *((const bf16x8*)(wt3h + (size_t)(colbase + cj*16 + lm)*256 + k0));
    bf16x8 af[4];
    #pragma unroll
    for (int ri = 0; ri < 4; ri++)
      af[ri] = *((const bf16x8*)(As + (ri*16 + lm)*264 + k0));
    #pragma unroll
    for (int ri = 0; ri < 4; ri++)
      #pragma unroll
      for (int cj = 0; cj < 4; cj++)
        acc[ri][cj] = __builtin_amdgcn_mfma_f32_16x16x32_bf16(af[ri], bf[cj], acc[ri][cj], 0, 0, 0);
  }
  #pragma unroll
  for (int cj = 0; cj < 4; cj++) {
    float s = 0.f, s2 = 0.f, mx = -__builtin_inff(), mn = __builtin_inff();
    #pragma unroll
    for (int ri = 0; ri < 4; ri++) {
      #pragma unroll
      for (int reg = 0; reg < 4; reg++) {
        float h = acc[ri][cj][reg];
        s += h; s2 += h*h; mx = fmaxf(mx, h); mn = fminf(mn, h);
      }
    }
    s  += __shfl_xor(s, 16);  s  += __shfl_xor(s, 32);
    s2 += __shfl_xor(s2, 16); s2 += __shfl_xor(s2, 32);
    mx = fmaxf(mx, __shfl_xor(mx, 16)); mx = fmaxf(mx, __shfl_xor(mx, 32));
    mn = fminf(mn, __shfl_xor(mn, 16)); mn = fminf(mn, __shfl_xor(mn, 32));
    if (lane < 16) {
      int col = colbase + cj*16 + lane;
      double* dst = stats3sh + ((size_t)(blockIdx.x & 63)*1024 + col)*2;
      atomicAdd(dst, (double)s);
      atomicAdd(dst + 1, (double)s2);
      atomicMax(hmax3u + b*1024 + col, fkey(mx));
      atomicMin(hmin3u + b*1024 + col, fkey(mn));
    }
  }
}

// ---------- 12) head, split for weight-read parallelism ----------
__device__ float blk_reduce(float v, float* red, int tid) {
  red[tid] = v; __syncthreads();
  for (int st = 128; st > 0; st >>= 1) {
    if (tid < st) red[tid] += red[tid + st];
    __syncthreads();
  }
  float r = red[0]; __syncthreads();
  return r;
}

// head1: fc1 (pre-LN). grid 512 = 16 b x 32 o-chunks of 16.
__global__ void __launch_bounds__(256) k_head1(const unsigned* __restrict__ hmax3u,
    const unsigned* __restrict__ hmin3u,
    const float* __restrict__ scale3, const float* __restrict__ shift3,
    const float* __restrict__ fc1w, const float* __restrict__ fc1b,
    float* __restrict__ h1buf) {
  __shared__ __align__(16) float V[1024];
  int b = blockIdx.x >> 5, oc = blockIdx.x & 31;
  int tid = threadIdx.x;
  for (int o = tid; o < 1024; o += 256) {
    float a = scale3[o];
    unsigned u = (a >= 0.f) ? hmax3u[b*1024 + o] : hmin3u[b*1024 + o];
    V[o] = fmaxf(fmaf(a, fkeyinv(u), shift3[o]), 0.f);
  }
  __syncthreads();
  int ty = tid >> 4, tx = tid & 15;
  int o = oc*16 + ty;
  const float4* wr = (const float4*)(fc1w + (size_t)o*1024) + tx*16;
  const float4* vv = (const float4*)V + tx*16;
  float s = 0.f;
  #pragma unroll
  for (int i = 0; i < 16; i++) {
    float4 w = wr[i]; float4 v = vv[i];
    s = fmaf(w.x, v.x, s); s = fmaf(w.y, v.y, s);
    s = fmaf(w.z, v.z, s); s = fmaf(w.w, v.w, s);
  }
  s += __shfl_xor(s, 1); s += __shfl_xor(s, 2);
  s += __shfl_xor(s, 4); s += __shfl_xor(s, 8);
  if (tx == 0) h1buf[b*512 + o] = s + fc1b[o];
}

// head2: LN1+relu+fc2 (pre-LN). grid 128 = 16 b x 8 o-chunks of 32.
__global__ void __launch_bounds__(256) k_head2(const float* __restrict__ h1buf,
    const float* __restrict__ ln1g, const float* __restrict__ ln1b,
    const float* __restrict__ fc2w, const float* __restrict__ fc2b,
    float* __restrict__ h2buf) {
  __shared__ __align__(16) float H1[512];
  __shared__ float red[256];
  int b = blockIdx.x >> 3, oc = blockIdx.x & 7;
  int tid = threadIdx.x;
  float v0 = h1buf[b*512 + tid], v1 = h1buf[b*512 + 256 + tid];
  float s = blk_reduce(v0 + v1, red, tid);
  float s2 = blk_reduce(v0*v0 + v1*v1, red, tid);
  float m = s / 512.f;
  float var = s2 / 512.f - m*m;
  float inv = 1.0f / sqrtf(var + 1e-5f);
  H1[tid] = fmaxf((v0 - m)*inv*ln1g[tid] + ln1b[tid], 0.f);
  H1[256 + tid] = fmaxf((v1 - m)*inv*ln1g[256 + tid] + ln1b[256 + tid], 0.f);
  __syncthreads();
  int ty = tid >> 3, tx = tid & 7;
  int o = oc*32 + ty;
  const float4* wr = (const float4*)(fc2w + (size_t)o*512) + tx*16;
  const float4* vv = (const float4*)H1 + tx*16;
  float t = 0.f;
  #pragma unroll
  for (int i = 0; i < 16; i++) {
    float4 w = wr[i]; float4 v = vv[i];
    t = fmaf(w.x, v.x, t); t = fmaf(w.y, v.y, t);
    t = fmaf(w.z, v.z, t); t = fmaf(w.w, v.w, t);
  }
  t += __shfl_xor(t, 1); t += __shfl_xor(t, 2); t += __shfl_xor(t, 4);
  if (tx == 0) h2buf[b*256 + o] = t + fc2b[o];
}

// head3: LN2+relu+out-proj+log_softmax. grid 16.
__global__ void __launch_bounds__(256) k_head3(const float* __restrict__ h2buf,
    const float* __restrict__ ln2g, const float* __restrict__ ln2b,
    const float* __restrict__ outw, const float* __restrict__ outb,
    float* __restrict__ out) {
  __shared__ __align__(16) float H2[256];
  __shared__ float red[256];
  int b = blockIdx.x, tid = threadIdx.x;
  float h2v = h2buf[b*256 + tid];
  float ss = blk_reduce(h2v, red, tid);
  float ss2 = blk_reduce(h2v*h2v, red, tid);
  float m2 = ss / 256.f;
  float var2 = ss2 / 256.f - m2*m2;
  float inv2 = 1.0f / sqrtf(var2 + 1e-5f);
  H2[tid] = fmaxf((h2v - m2)*inv2*ln2g[tid] + ln2b[tid], 0.f);
  __syncthreads();
  if (tid < 40) {
    const float4* wr = (const float4*)(outw + (size_t)tid*256);
    float t = 0.f;
    for (int c4 = 0; c4 < 64; c4++) {
      float4 w = wr[c4]; float4 vv = ((const float4*)H2)[c4];
      t = fmaf(w.x, vv.x, t); t = fmaf(w.y, vv.y, t);
      t = fmaf(w.z, vv.z, t); t = fmaf(w.w, vv.w, t);
    }
    red[tid] = t + outb[tid];
  }
  __syncthreads();
  if (tid == 0) {
    float mx = -__builtin_inff();
    for (int i2 = 0; i2 < 40; i2++) mx = fmaxf(mx, red[i2]);
    float se = 0.f;
    for (int i2 = 0; i2 < 40; i2++) se += expf(red[i2] - mx);
    float lse = mx + logf(se);
    for (int i2 = 0; i2 < 40; i2++) out[b*40 + i2] = red[i2] - lse;
  }
}

extern "C" void kernel_launch(void* const* d_in, const int* in_sizes, int n_in,
                              void* d_out, int out_size, void* d_ws, size_t ws_size,
                              hipStream_t stream) {
  (void)in_sizes; (void)n_in; (void)out_size; (void)ws_size;
  const float* x    = (const float*)d_in[0];
  const float* w1   = (const float*)d_in[1];
  const float* bn1g = (const float*)d_in[2];
  const float* bn1b = (const float*)d_in[3];
  const float* w2   = (const float*)d_in[4];
  const float* bn2g = (const float*)d_in[5];
  const float* bn2b = (const float*)d_in[6];
  const float* w3   = (const float*)d_in[7];
  const float* bn3g = (const float*)d_in[8];
  const float* bn3b = (const float*)d_in[9];
  const float* fc1w = (const float*)d_in[10];
  const float* fc1b = (const float*)d_in[11];
  const float* ln1g = (const float*)d_in[12];
  const float* ln1b = (const float*)d_in[13];
  const float* fc2w = (const float*)d_in[14];
  const float* fc2b = (const float*)d_in[15];
  const float* ln2g = (const float*)d_in[16];
  const float* ln2b = (const float*)d_in[17];
  const float* outw = (const float*)d_in[18];
  const float* outb = (const float*)d_in[19];
  float* out = (float*)d_out;

  float* ws = (float*)d_ws;
  size_t off = 0;
  float* xp1   = ws + off; off += 49152;
  int*   idx1  = (int*)(ws + off); off += 327680;
  float* hmax1 = ws + off; off += 1048576;
  float* hmin1 = ws + off; off += 1048576;
  float* xp2   = ws + off; off += 1048576;
  float* hmax2 = ws + off; off += 3145728;   // also keypart (knn partials)
  float* hmin2 = ws + off; off += 3145728;
  int*   idx2  = (int*)(ws + off); off += 327680;
  unsigned short* w2h = (unsigned short*)(ws + off); off += 24576;
  unsigned short* wt3h = (unsigned short*)(ws + off); off += 131072;
  float* x1T   = ws + off; off += 1048576;
  float* xx1   = ws + off; off += 16384;
  float* h1buf = ws + off; off += 8192;
  float* h2buf = ws + off; off += 4096;
  float* scale1 = ws + off; off += 64;
  float* shift1 = ws + off; off += 64;
  float* scale2 = ws + off; off += 192;
  float* shift2 = ws + off; off += 192;
  float* scale3 = ws + off; off += 1024;
  float* shift3 = ws + off; off += 1024;
  double* stats1sh = (double*)(ws + off);
  double* stats2sh = stats1sh + 64*64*2;
  double* stats3sh = stats2sh + 64*192*2;
  unsigned* hmax3u = (unsigned*)(stats3sh + (size_t)64*1024*2);
  unsigned* hmin3u = hmax3u + 16384;
  unsigned* keypart = (unsigned*)hmax2;

  size_t zero_bytes = ((size_t)64*64*2 + (size_t)64*192*2 + (size_t)64*1024*2)*8 + (size_t)16384*4;
  hipMemsetAsync(stats1sh, 0, zero_bytes, stream);
  hipMemsetAsync(hmin3u, 0xFF, (size_t)16384*4, stream);

  k_prep<<<1024, 256, 0, stream>>>(x, xp1, w2, w3, w2h, wt3h);
  k_knn1_part<<<512, 256, 0, stream>>>(x, keypart);
  k_knn_merge<8><<<256, 64, 0, stream>>>(keypart, idx1);
  k_conv1<<<1024, 256, 0, stream>>>(xp1, idx1, w1, hmax1, hmin1, stats1sh);
  k_bn_reduce<<<1, 64, 0, stream>>>(stats1sh, 64, 64, 327680.0, bn1g, bn1b, scale1, shift1);
  k_bn1_apply<<<256, 256, 0, stream>>>(hmax1, hmin1, scale1, shift1, xp2, x1T, xx1);
  k_knn2g<<<1024, 256, 0, stream>>>(x1T, xx1, keypart);
  k_knn_merge<4><<<256, 64, 0, stream>>>(keypart, idx2);
  k_conv2m<<<4096, 256, 0, stream>>>(xp2, idx2, w2h, hmax2, hmin2, stats2sh);
  k_bn_reduce<<<1, 192, 0, stream>>>(stats2sh, 64, 192, 327680.0, bn2g, bn2b, scale2, shift2);
  k_conv3m<<<1024, 256, 0, stream>>>(hmax1, hmin1, scale1, shift1, hmax2, hmin2, scale2, shift2,
                                     wt3h, stats3sh, hmax3u, hmin3u);
  k_bn_reduce<<<4, 256, 0, stream>>>(stats3sh, 64, 1024, 16384.0, bn3g, bn3b, scale3, shift3);
  k_head1<<<512, 256, 0, stream>>>(hmax3u, hmin3u, scale3, shift3, fc1w, fc1b, h1buf);
  k_head2<<<128, 256, 0, stream>>>(h1buf, ln1g, ln1b, fc2w, fc2b, h2buf);
  k_head3<<<16, 256, 0, stream>>>(h2buf, ln2g, ln2b, outw, outb, out);
}

// Round 14
// 410.046 us; speedup vs baseline: 1.6154x; 1.0556x over previous
//
#include <hip/hip_runtime.h>
#include <math.h>

#define B_ 16
#define N_ 1024
#define KNN 20
#define NPAIR (B_*N_)

typedef __attribute__((ext_vector_type(8))) short bf16x8;
typedef __attribute__((ext_vector_type(4))) float f32x4;

// ---------- helpers ----------
__device__ __forceinline__ unsigned fkey(float f) {
  unsigned u = __float_as_uint(f);
  return (u & 0x80000000u) ? ~u : (u | 0x80000000u);
}
__device__ __forceinline__ float fkeyinv(unsigned u) {
  unsigned b = (u & 0x80000000u) ? (u ^ 0x80000000u) : ~u;
  return __uint_as_float(b);
}
__device__ __forceinline__ unsigned short f2bf(float x) {  // RNE float->bf16
  unsigned u = __float_as_uint(x);
  unsigned r = (u + 0x7FFFu + ((u >> 16) & 1u)) >> 16;
  return (unsigned short)r;
}
__device__ __forceinline__ float bf2f(unsigned short u) {
  return __uint_as_float(((unsigned)u) << 16);
}
// packed knn key: top 22 bits of fkey(d) | (1023 - idx). u32 '>' == dist desc, idx asc.
__device__ __forceinline__ unsigned knnkey(float d, int idx) {
  return (fkey(d) & 0xFFFFFC00u) | (unsigned)(1023 - idx);
}

// Branchless sorted-insert (descending) of packed u32 key: 2 ops/stage.
__device__ __forceinline__ void topk_insert_u32(unsigned (&kl)[KNN], unsigned nk) {
  kl[KNN-1] = nk;
  #pragma unroll
  for (int i = KNN-1; i > 0; i--) {
    unsigned hi = max(kl[i-1], kl[i]);
    unsigned lo = min(kl[i-1], kl[i]);
    kl[i-1] = hi; kl[i] = lo;
  }
}

// ---------- 1) fused prep + knn1: blocks 0..511 = knn1 8-way split; 512..1535 = prep ----------
__global__ void __launch_bounds__(256) k_prep_knn1(const float* __restrict__ x,
        float* __restrict__ xp1, const float* __restrict__ w2, const float* __restrict__ w3,
        unsigned short* __restrict__ w2h, unsigned short* __restrict__ wt3h,
        unsigned* __restrict__ keypart) {
  __shared__ float P[N_*3];
  __shared__ float XX[N_];
  if (blockIdx.x >= 512) {
    int i = (blockIdx.x - 512) * 256 + threadIdx.x;
    if (i < NPAIR) {
      float a0 = x[i*3+0], a1 = x[i*3+1], a2 = x[i*3+2];
      float n = sqrtf(a0*a0 + a1*a1 + a2*a2);
      n = fmaxf(n, 1e-15f);
      float th = tanhf(0.1f * n);
      float sc = th / (0.1f * n);
      float ny = fmaxf(th * 10.0f, 1e-15f);
      float mxn = (1.0f - 4e-3f) / 0.1f;
      if (ny > mxn) sc *= mxn / ny;
      xp1[i*3+0] = sc*a0; xp1[i*3+1] = sc*a1; xp1[i*3+2] = sc*a2;
    }
    if (i < 192*128) w2h[i] = f2bf(w2[i]);
    wt3h[i] = f2bf(w3[i]);
    return;
  }
  int blk = blockIdx.x;
  int b = blk >> 5, rc = (blk >> 3) & 3, cc = blk & 7;
  const float* xb = x + b*N_*3;
  for (int e = threadIdx.x; e < N_*3; e += 256) P[e] = xb[e];
  __syncthreads();
  for (int j = threadIdx.x; j < N_; j += 256) {
    float q0 = P[j*3], q1 = P[j*3+1], q2 = P[j*3+2];
    XX[j] = q0*q0 + q1*q1 + q2*q2;
  }
  __syncthreads();
  int r = rc*256 + threadIdx.x;
  float q0 = P[r*3], q1 = P[r*3+1], q2 = P[r*3+2];
  float xxq = XX[r];
  unsigned kl[KNN];
  #pragma unroll
  for (int i = 0; i < KNN; i++) kl[i] = 0u;
  int cbase = cc*128;
  for (int jj = 0; jj < 128; jj++) {
    int j = cbase + jj;
    float dot = q0*P[j*3] + q1*P[j*3+1] + q2*P[j*3+2];
    float d = 2.0f*dot - xxq - XX[j];
    unsigned nk = knnkey(d, j);
    if (nk > kl[KNN-1]) topk_insert_u32(kl, nk);
  }
  int p = b*N_ + r;
  unsigned* pe = keypart + (size_t)p*160 + cc*20;
  #pragma unroll
  for (int i = 0; i < KNN; i++) pe[i] = kl[i];
}

// ---------- 3) conv1 fused (inline 8-way merge of knn1 key chunks) ----------
__global__ void __launch_bounds__(256) k_conv1(const float* __restrict__ xp1,
                        const unsigned* __restrict__ keypart,
                        const float* __restrict__ w1, float* __restrict__ hmax1,
                        float* __restrict__ hmin1, double* __restrict__ stats1sh) {
  __shared__ float F[4][KNN][6];
  __shared__ float red[4][64][2];
  __shared__ int idxs[16][KNN];
  int g = threadIdx.x >> 6, lane = threadIdx.x & 63;
  int pbase = blockIdx.x * 16;
  if (threadIdx.x < 16) {
    const unsigned* pe = keypart + (size_t)(pbase + threadIdx.x)*160;
    int pos[8];
    #pragma unroll
    for (int c = 0; c < 8; c++) pos[c] = 0;
    for (int t = 0; t < KNN; t++) {
      unsigned best = 0u; int bc = 0;
      #pragma unroll
      for (int c = 0; c < 8; c++) {
        if (pos[c] < KNN) {
          unsigned v = pe[c*20 + pos[c]];
          if (v > best) { best = v; bc = c; }
        }
      }
      idxs[threadIdx.x][t] = 1023 - (int)(best & 1023u);
      #pragma unroll
      for (int c = 0; c < 8; c++) if (bc == c) pos[c]++;
    }
  }
  float w[6];
  #pragma unroll
  for (int c = 0; c < 6; c++) w[c] = w1[lane*6 + c];
  float sum = 0.f, sumsq = 0.f;
  __syncthreads();
  for (int it = 0; it < 4; ++it) {
    int p = pbase + it*4 + g;
    if (lane < KNN) {
      int nb = idxs[it*4 + g][lane];
      int bb = p >> 10;
      const float* xc = xp1 + p*3;
      const float* ft = xp1 + (bb*N_ + nb)*3;
      float x0 = ft[0], x1 = ft[1], x2v = ft[2];
      float c0 = xc[0], c1 = xc[1], c2 = xc[2];
      float X2 = x0*x0 + x1*x1 + x2v*x2v;
      float Y2 = c0*c0 + c1*c1 + c2*c2;
      float XY = -(x0*c0 + x1*c1 + x2v*c2);
      float den = fmaxf(1.0f + 0.02f*XY + 1e-4f*X2*Y2, 1e-15f);
      float s1 = (1.0f + 0.02f*XY + 0.01f*Y2) / den;
      float s2 = (1.0f - 0.01f*X2) / den;
      F[g][lane][0] = s1*x0 - s2*c0;
      F[g][lane][1] = s1*x1 - s2*c1;
      F[g][lane][2] = s1*x2v - s2*c2;
      F[g][lane][3] = c0; F[g][lane][4] = c1; F[g][lane][5] = c2;
    }
    __syncthreads();
    float mx = -__builtin_inff(), mn = __builtin_inff();
    for (int k = 0; k < KNN; k++) {
      float h = 0.f;
      #pragma unroll
      for (int c = 0; c < 6; c++) h = fmaf(w[c], F[g][k][c], h);
      mx = fmaxf(mx, h); mn = fminf(mn, h);
      sum += h; sumsq += h*h;
    }
    hmax1[(pbase + it*4 + g)*64 + lane] = mx;
    hmin1[(pbase + it*4 + g)*64 + lane] = mn;
    __syncthreads();
  }
  red[g][lane][0] = sum; red[g][lane][1] = sumsq;
  __syncthreads();
  if (g == 0) {
    float s  = red[0][lane][0] + red[1][lane][0] + red[2][lane][0] + red[3][lane][0];
    float s2 = red[0][lane][1] + red[1][lane][1] + red[2][lane][1] + red[3][lane][1];
    double* dst = stats1sh + ((size_t)(blockIdx.x & 63)*64 + lane)*2;
    atomicAdd(dst, (double)s);
    atomicAdd(dst + 1, (double)s2);
  }
}

// ---------- BN stat reduce v2: one channel per block, 64 lanes = 64 shadows ----------
__global__ void __launch_bounds__(64) k_bn_reduce(const double* __restrict__ sh, int nch, double cnt,
                            const float* __restrict__ g, const float* __restrict__ bb,
                            float* __restrict__ scale, float* __restrict__ shift) {
  int o = blockIdx.x, t = threadIdx.x;
  double s  = sh[((size_t)t*nch + o)*2];
  double s2 = sh[((size_t)t*nch + o)*2 + 1];
  #pragma unroll
  for (int off = 32; off > 0; off >>= 1) { s += __shfl_xor(s, off); s2 += __shfl_xor(s2, off); }
  if (t == 0) {
    double m = s / cnt;
    double v = s2 / cnt - m*m;
    float a = g[o] / sqrtf((float)v + 1e-5f);
    scale[o] = a;
    shift[o] = bb[o] - a * (float)m;
  }
}

// ---------- 5) BN1 apply + relu + e2p + coalesced x1T transpose + |x1|^2 ----------
__global__ void __launch_bounds__(256) k_bn1_apply(const float* __restrict__ hmax1, const float* __restrict__ hmin1,
                            const float* __restrict__ scale1, const float* __restrict__ shift1,
                            float* __restrict__ xp2,
                            float* __restrict__ x1T, float* __restrict__ xx1) {
  int b = blockIdx.x >> 4, nc = blockIdx.x & 15;
  int c = threadIdx.x & 63, sub = threadIdx.x >> 6;
  int n0 = nc*64 + sub*16;
  float a = scale1[c], t = shift1[c];
  float xr[16];
  #pragma unroll
  for (int i = 0; i < 16; i++) {
    int p = b*1024 + n0 + i;
    float h = (a >= 0.f) ? hmax1[(size_t)p*64 + c] : hmin1[(size_t)p*64 + c];
    float x1 = fmaxf(fmaf(a, h, t), 0.f);
    xr[i] = x1;
    float n2 = x1*x1;
    #pragma unroll
    for (int off = 32; off > 0; off >>= 1) n2 += __shfl_xor(n2, off);
    if (c == 0) xx1[p] = n2;
    float n1 = fmaxf(sqrtf(n2), 1e-15f);
    float th = tanhf(0.1f * n1);
    float sc = th / (0.1f * n1);
    float ny = fmaxf(th * 10.0f, 1e-15f);
    float mxn = (1.0f - 4e-3f) / 0.1f;
    if (ny > mxn) sc *= mxn / ny;
    xp2[(size_t)p*64 + c] = sc * x1;
  }
  float* dst = x1T + ((size_t)(b*64 + c))*1024 + n0;
  #pragma unroll
  for (int q = 0; q < 4; q++) {
    float4 v; v.x = xr[q*4]; v.y = xr[q*4+1]; v.z = xr[q*4+2]; v.w = xr[q*4+3];
    *((float4*)(dst + q*4)) = v;
  }
}

// ---------- 6) knn2 v6: 4-way split, packed-u32 selection, register Bs prefetch ----------
__global__ void __launch_bounds__(256) k_knn2g(const float* __restrict__ x1T,
        const float* __restrict__ xx1, unsigned* __restrict__ keypart2) {
  __shared__ __align__(16) float SM[8192];   // As @0 (64x64), BsD @4096 (64x64)
  float* As = SM;
  float* BsD = SM + 4096;
  int tid = threadIdx.x;
  int blk = blockIdx.x;
  int b = blk >> 6, qc = (blk >> 2) & 15, cc = blk & 3;
  int qbase = qc*64, ccbase = cc*256;
  int tx = tid & 15, ty = tid >> 4;
  int wave = tid >> 6, lane = tid & 63;
  #pragma unroll
  for (int r = 0; r < 4; r++) {
    int e = tid + r*256;
    int k = e >> 4, qf = e & 15;
    *((float4*)(As + k*64 + qf*4)) =
      *((const float4*)(x1T + ((size_t)(b*64 + k))*1024 + qbase + qf*4));
  }
  // prefetch subtile 0 candidates into registers
  float4 breg[4];
  #pragma unroll
  for (int r = 0; r < 4; r++) {
    int e = tid + r*256;
    int k = e >> 4, cf = e & 15;
    breg[r] = *((const float4*)(x1T + ((size_t)(b*64 + k))*1024 + ccbase + cf*4));
  }
  float4 xxcreg = *((const float4*)(xx1 + b*1024 + ccbase + ty*4));
  unsigned kl[KNN];
  #pragma unroll
  for (int i = 0; i < KNN; i++) kl[i] = 0u;
  int cq = lane + (lane >> 2);

  for (int st = 0; st < 4; ++st) {
    int cb0 = ccbase + st*64;
    __syncthreads();    // previous select done (BsD free); st=0: As writes don't conflict (disjoint)
    #pragma unroll
    for (int r = 0; r < 4; r++) {
      int e = tid + r*256;
      int k = e >> 4, cf = e & 15;
      *((float4*)(BsD + k*64 + cf*4)) = breg[r];
    }
    float4 xxc = xxcreg;
    if (st < 3) {
      int cb1 = cb0 + 64;
      #pragma unroll
      for (int r = 0; r < 4; r++) {
        int e = tid + r*256;
        int k = e >> 4, cf = e & 15;
        breg[r] = *((const float4*)(x1T + ((size_t)(b*64 + k))*1024 + cb1 + cf*4));
      }
      xxcreg = *((const float4*)(xx1 + b*1024 + cb1 + ty*4));
    }
    __syncthreads();
    float acc[4][4];
    #pragma unroll
    for (int i = 0; i < 4; i++)
      #pragma unroll
      for (int j = 0; j < 4; j++) acc[i][j] = 0.f;
    #pragma unroll 4
    for (int k = 0; k < 64; k++) {
      float4 a4 = *((const float4*)(As + k*64 + tx*4));
      float4 b4 = *((const float4*)(BsD + k*64 + ty*4));
      float av[4] = {a4.x, a4.y, a4.z, a4.w};
      float bw[4] = {b4.x, b4.y, b4.z, b4.w};
      #pragma unroll
      for (int i = 0; i < 4; i++)
        #pragma unroll
        for (int j = 0; j < 4; j++) acc[i][j] = fmaf(av[i], bw[j], acc[i][j]);
    }
    __syncthreads();
    float xxv[4] = {xxc.x, xxc.y, xxc.z, xxc.w};
    #pragma unroll
    for (int i = 0; i < 4; i++) {
      int q = tx*4 + i;
      #pragma unroll
      for (int j = 0; j < 4; j++) {
        int c = ty*4 + j;
        BsD[q*64 + ((c + q + (q >> 2)) & 63)] = 2.0f*acc[i][j] - xxv[j];
      }
    }
    __syncthreads();
    #pragma unroll
    for (int j = 0; j < 16; j++) {
      int c = wave*16 + j;
      float d = BsD[lane*64 + ((c + cq) & 63)];
      unsigned nk = knnkey(d, cb0 + c);
      if (nk > kl[KNN-1]) topk_insert_u32(kl, nk);
    }
  }
  __syncthreads();
  unsigned* U = (unsigned*)SM;
  unsigned* L0 = U;
  unsigned* L1 = U + 1344;
  unsigned* M  = U + 2688;
  if (wave == 0) {
    #pragma unroll
    for (int i = 0; i < KNN; i++) L0[lane*21 + i] = kl[i];
  } else if (wave == 1) {
    #pragma unroll
    for (int i = 0; i < KNN; i++) L1[lane*21 + i] = kl[i];
  }
  __syncthreads();
  if (tid < 64) {
    int ia = 0, ib = 0;
    for (int t = 0; t < KNN; t++) {
      unsigned pa = L0[tid*21 + ia], pb = L1[tid*21 + ib];
      bool ta = pa > pb;
      M[tid*21 + t] = ta ? pa : pb;
      if (ta) ia++; else ib++;
    }
  }
  __syncthreads();
  if (wave == 2) {
    #pragma unroll
    for (int i = 0; i < KNN; i++) L0[lane*21 + i] = kl[i];
  } else if (wave == 3) {
    #pragma unroll
    for (int i = 0; i < KNN; i++) L1[lane*21 + i] = kl[i];
  }
  __syncthreads();
  if (tid < 64) {
    int p = b*N_ + qbase + tid;
    unsigned* pe = keypart2 + (size_t)p*80 + cc*20;
    int ia = 0, ib = 0, im = 0;
    for (int t = 0; t < KNN; t++) {
      unsigned pa = L0[tid*21 + ia], pb = L1[tid*21 + ib], pm = M[tid*21 + im];
      unsigned bp = pm; int sel = 2;
      if (pa > bp) { bp = pa; sel = 0; }
      if (pb > bp) { bp = pb; sel = 1; }
      pe[t] = bp;
      if (sel == 0) ia++; else if (sel == 1) ib++; else im++;
    }
  }
}

// ---------- 9) conv2 via bf16 MFMA v4: inline 4-way merge + permuted rows + register epilogue ----------
__global__ void __launch_bounds__(256) k_conv2m(const float* __restrict__ xp2,
    const unsigned* __restrict__ keypart2, const unsigned short* __restrict__ w2h,
    float* __restrict__ hmax2, float* __restrict__ hmin2, double* __restrict__ stats2sh) {
  __shared__ __align__(16) short Abf[80*136];
  __shared__ float s1s[80], s2s[80];
  __shared__ int nbr[80];                        // logical order [pt*20 + k]
  int tid = threadIdx.x;
  int p0 = blockIdx.x * 4;
  int b = p0 >> 10;
  if (tid < 4) {
    const unsigned* pe = keypart2 + (size_t)(p0 + tid)*80;
    int pos[4];
    #pragma unroll
    for (int c = 0; c < 4; c++) pos[c] = 0;
    for (int t = 0; t < KNN; t++) {
      unsigned best = 0u; int bc = 0;
      #pragma unroll
      for (int c = 0; c < 4; c++) {
        if (pos[c] < KNN) {
          unsigned v = pe[c*20 + pos[c]];
          if (v > best) { best = v; bc = c; }
        }
      }
      nbr[tid*20 + t] = 1023 - (int)(best & 1023u);
      #pragma unroll
      for (int c = 0; c < 4; c++) if (bc == c) pos[c]++;
    }
  }
  __syncthreads();
  for (int e = tid; e < 80*16; e += 256) {
    int r = e >> 4, qq = e & 15;
    int q = (r >> 2) & 3;
    int L = 20*q + 4*(r >> 4) + (r & 3);
    float4 f = *((const float4*)(xp2 + (size_t)(b*N_ + nbr[L])*64) + qq);
    float4 cv = *((const float4*)(xp2 + (size_t)(p0 + q)*64) + qq);
    ushort4 fb, cb;
    fb.x = f2bf(f.x); fb.y = f2bf(f.y); fb.z = f2bf(f.z); fb.w = f2bf(f.w);
    cb.x = f2bf(cv.x); cb.y = f2bf(cv.y); cb.z = f2bf(cv.z); cb.w = f2bf(cv.w);
    *((ushort4*)(Abf + r*136 + qq*4)) = fb;
    *((ushort4*)(Abf + r*136 + 64 + qq*4)) = cb;
  }
  __syncthreads();
  if (tid < 160) {
    int r = tid >> 1, h = tid & 1;
    const unsigned short* Ar = (const unsigned short*)(Abf + r*136) + h*32;
    const unsigned short* Xr = (const unsigned short*)(Abf + r*136 + 64) + h*32;
    float X2 = 0.f, XY = 0.f, Y2 = 0.f;
    for (int c2 = 0; c2 < 32; c2++) {
      float f = bf2f(Ar[c2]), xcv = bf2f(Xr[c2]);
      X2 = fmaf(f, f, X2); XY = fmaf(-f, xcv, XY); Y2 = fmaf(xcv, xcv, Y2);
    }
    X2 += __shfl_xor(X2, 1); XY += __shfl_xor(XY, 1); Y2 += __shfl_xor(Y2, 1);
    if (h == 0) {
      float den = fmaxf(1.0f + 0.02f*XY + 1e-4f*X2*Y2, 1e-15f);
      s1s[r] = (1.0f + 0.02f*XY + 0.01f*Y2) / den;
      s2s[r] = (1.0f - 0.01f*X2) / den;
    }
  }
  __syncthreads();
  for (int e = tid; e < 80*16; e += 256) {
    int r = e >> 4, qq = e & 15;
    ushort4 fr = *((const ushort4*)(Abf + r*136 + qq*4));
    ushort4 xr4 = *((const ushort4*)(Abf + r*136 + 64 + qq*4));
    float s1 = s1s[r], s2 = s2s[r];
    ushort4 mo;
    mo.x = f2bf(s1*bf2f(fr.x) - s2*bf2f(xr4.x));
    mo.y = f2bf(s1*bf2f(fr.y) - s2*bf2f(xr4.y));
    mo.z = f2bf(s1*bf2f(fr.z) - s2*bf2f(xr4.z));
    mo.w = f2bf(s1*bf2f(fr.w) - s2*bf2f(xr4.w));
    *((ushort4*)(Abf + r*136 + qq*4)) = mo;
  }
  __syncthreads();
  int wave = tid >> 6, lane = tid & 63;
  int quad = lane >> 4, lm = lane & 15;
  int colbase = wave*48;
  f32x4 acc[5][3];
  #pragma unroll
  for (int rt = 0; rt < 5; rt++)
    #pragma unroll
    for (int cj = 0; cj < 3; cj++) acc[rt][cj] = (f32x4){0.f, 0.f, 0.f, 0.f};
  #pragma unroll
  for (int kt = 0; kt < 4; kt++) {
    int k0 = kt*32 + quad*8;
    bf16x8 bf[3];
    #pragma unroll
    for (int cj = 0; cj < 3; cj++)
      bf[cj] = *((const bf16x8*)(w2h + (size_t)(colbase + cj*16 + lm)*128 + k0));
    bf16x8 af[5];
    #pragma unroll
    for (int rt = 0; rt < 5; rt++)
      af[rt] = *((const bf16x8*)(Abf + (rt*16 + lm)*136 + k0));
    #pragma unroll
    for (int rt = 0; rt < 5; rt++)
      #pragma unroll
      for (int cj = 0; cj < 3; cj++)
        acc[rt][cj] = __builtin_amdgcn_mfma_f32_16x16x32_bf16(af[rt], bf[cj], acc[rt][cj], 0, 0, 0);
  }
  #pragma unroll
  for (int cj = 0; cj < 3; cj++) {
    int o = colbase + cj*16 + lm;
    float s = 0.f, s2 = 0.f, mx = -__builtin_inff(), mn = __builtin_inff();
    #pragma unroll
    for (int rt = 0; rt < 5; rt++) {
      #pragma unroll
      for (int reg = 0; reg < 4; reg++) {
        float h = acc[rt][cj][reg];
        s += h; s2 += h*h;
        mx = fmaxf(mx, h); mn = fminf(mn, h);
      }
    }
    hmax2[(size_t)(p0 + quad)*192 + o] = mx;
    hmin2[(size_t)(p0 + quad)*192 + o] = mn;
    s  += __shfl_xor(s, 16);  s  += __shfl_xor(s, 32);
    s2 += __shfl_xor(s2, 16); s2 += __shfl_xor(s2, 32);
    if (lane < 16) {
      double* dst = stats2sh + ((size_t)(blockIdx.x & 63)*192 + o)*2;
      atomicAdd(dst, (double)s); atomicAdd(dst + 1, (double)s2);
    }
  }
}

// ---------- 11) conv3 via bf16 MFMA, A-tile staged directly from BN1/BN2 max/min ----------
__global__ void __launch_bounds__(256) k_conv3m(
   const float* __restrict__ hmax1, const float* __restrict__ hmin1,
   const float* __restrict__ scale1, const float* __restrict__ shift1,
   const float* __restrict__ hmax2, const float* __restrict__ hmin2,
   const float* __restrict__ scale2, const float* __restrict__ shift2,
   const unsigned short* __restrict__ wt3h, double* __restrict__ stats3sh,
   unsigned* __restrict__ hmax3u, unsigned* __restrict__ hmin3u) {
  __shared__ short As[64*264];
  int tid = threadIdx.x;
  int mt = blockIdx.x >> 2, cb = blockIdx.x & 3;
  int rowbase = mt*64;
  int b = rowbase >> 10;
  int c4 = tid & 63;
  float4 sc, sh;
  if (c4 < 16) {
    sc = *((const float4*)(scale1 + c4*4));
    sh = *((const float4*)(shift1 + c4*4));
  } else {
    sc = *((const float4*)(scale2 + (c4*4 - 64)));
    sh = *((const float4*)(shift2 + (c4*4 - 64)));
  }
  #pragma unroll 4
  for (int i = 0; i < 16; i++) {
    int r = (tid >> 6) + i*4;
    int p = rowbase + r;
    float4 hx, hn;
    if (c4 < 16) {
      hx = *((const float4*)(hmax1 + (size_t)p*64 + c4*4));
      hn = *((const float4*)(hmin1 + (size_t)p*64 + c4*4));
    } else {
      hx = *((const float4*)(hmax2 + (size_t)p*192 + (c4*4 - 64)));
      hn = *((const float4*)(hmin2 + (size_t)p*192 + (c4*4 - 64)));
    }
    ushort4 o4;
    o4.x = f2bf(fmaxf(fmaf(sc.x, (sc.x >= 0.f ? hx.x : hn.x), sh.x), 0.f));
    o4.y = f2bf(fmaxf(fmaf(sc.y, (sc.y >= 0.f ? hx.y : hn.y), sh.y), 0.f));
    o4.z = f2bf(fmaxf(fmaf(sc.z, (sc.z >= 0.f ? hx.z : hn.z), sh.z), 0.f));
    o4.w = f2bf(fmaxf(fmaf(sc.w, (sc.w >= 0.f ? hx.w : hn.w), sh.w), 0.f));
    *((ushort4*)(As + r*264 + c4*4)) = o4;
  }
  __syncthreads();
  int wave = tid >> 6, lane = tid & 63;
  int quad = lane >> 4, lm = lane & 15;
  int colbase = cb*256 + wave*64;
  f32x4 acc[4][4];
  #pragma unroll
  for (int ri = 0; ri < 4; ri++)
    #pragma unroll
    for (int cj = 0; cj < 4; cj++) acc[ri][cj] = (f32x4){0.f, 0.f, 0.f, 0.f};
  for (int kt = 0; kt < 8; kt++) {
    int k0 = kt*32 + quad*8;
    bf16x8 bf[4];
    #pragma unroll
    for (int cj = 0; cj < 4; cj++)
      bf[cj] = *((const bf16x8*)(wt3h + (size_t)(colbase + cj*16 + lm)*256 + k0));
    bf16x8 af[4];
    #pragma unroll
    for (int ri = 0; ri < 4; ri++)
      af[ri] = *((const bf16x8*)(As + (ri*16 + lm)*264 + k0));
    #pragma unroll
    for (int ri = 0; ri < 4; ri++)
      #pragma unroll
      for (int cj = 0; cj < 4; cj++)
        acc[ri][cj] = __builtin_amdgcn_mfma_f32_16x16x32_bf16(af[ri], bf[cj], acc[ri][cj], 0, 0, 0);
  }
  #pragma unroll
  for (int cj = 0; cj < 4; cj++) {
    float s = 0.f, s2 = 0.f, mx = -__builtin_inff(), mn = __builtin_inff();
    #pragma unroll
    for (int ri = 0; ri < 4; ri++) {
      #pragma unroll
      for (int reg = 0; reg < 4; reg++) {
        float h = acc[ri][cj][reg];
        s += h; s2 += h*h; mx = fmaxf(mx, h); mn = fminf(mn, h);
      }
    }
    s  += __shfl_xor(s, 16);  s  += __shfl_xor(s, 32);
    s2 += __shfl_xor(s2, 16); s2 += __shfl_xor(s2, 32);
    mx = fmaxf(mx, __shfl_xor(mx, 16)); mx = fmaxf(mx, __shfl_xor(mx, 32));
    mn = fminf(mn, __shfl_xor(mn, 16)); mn = fminf(mn, __shfl_xor(mn, 32));
    if (lane < 16) {
      int col = colbase + cj*16 + lane;
      double* dst = stats3sh + ((size_t)(blockIdx.x & 63)*1024 + col)*2;
      atomicAdd(dst, (double)s);
      atomicAdd(dst + 1, (double)s2);
      atomicMax(hmax3u + b*1024 + col, fkey(mx));
      atomicMin(hmin3u + b*1024 + col, fkey(mn));
    }
  }
}

// ---------- 12) head, split for weight-read parallelism ----------
__device__ float blk_reduce(float v, float* red, int tid) {
  red[tid] = v; __syncthreads();
  for (int st = 128; st > 0; st >>= 1) {
    if (tid < st) red[tid] += red[tid + st];
    __syncthreads();
  }
  float r = red[0]; __syncthreads();
  return r;
}

__global__ void __launch_bounds__(256) k_head1(const unsigned* __restrict__ hmax3u,
    const unsigned* __restrict__ hmin3u,
    const float* __restrict__ scale3, const float* __restrict__ shift3,
    const float* __restrict__ fc1w, const float* __restrict__ fc1b,
    float* __restrict__ h1buf) {
  __shared__ __align__(16) float V[1024];
  int b = blockIdx.x >> 5, oc = blockIdx.x & 31;
  int tid = threadIdx.x;
  for (int o = tid; o < 1024; o += 256) {
    float a = scale3[o];
    unsigned u = (a >= 0.f) ? hmax3u[b*1024 + o] : hmin3u[b*1024 + o];
    V[o] = fmaxf(fmaf(a, fkeyinv(u), shift3[o]), 0.f);
  }
  __syncthreads();
  int ty = tid >> 4, tx = tid & 15;
  int o = oc*16 + ty;
  const float4* wr = (const float4*)(fc1w + (size_t)o*1024) + tx*16;
  const float4* vv = (const float4*)V + tx*16;
  float s = 0.f;
  #pragma unroll
  for (int i = 0; i < 16; i++) {
    float4 w = wr[i]; float4 v = vv[i];
    s = fmaf(w.x, v.x, s); s = fmaf(w.y, v.y, s);
    s = fmaf(w.z, v.z, s); s = fmaf(w.w, v.w, s);
  }
  s += __shfl_xor(s, 1); s += __shfl_xor(s, 2);
  s += __shfl_xor(s, 4); s += __shfl_xor(s, 8);
  if (tx == 0) h1buf[b*512 + o] = s + fc1b[o];
}

__global__ void __launch_bounds__(256) k_head2(const float* __restrict__ h1buf,
    const float* __restrict__ ln1g, const float* __restrict__ ln1b,
    const float* __restrict__ fc2w, const float* __restrict__ fc2b,
    float* __restrict__ h2buf) {
  __shared__ __align__(16) float H1[512];
  __shared__ float red[256];
  int b = blockIdx.x >> 3, oc = blockIdx.x & 7;
  int tid = threadIdx.x;
  float v0 = h1buf[b*512 + tid], v1 = h1buf[b*512 + 256 + tid];
  float s = blk_reduce(v0 + v1, red, tid);
  float s2 = blk_reduce(v0*v0 + v1*v1, red, tid);
  float m = s / 512.f;
  float var = s2 / 512.f - m*m;
  float inv = 1.0f / sqrtf(var + 1e-5f);
  H1[tid] = fmaxf((v0 - m)*inv*ln1g[tid] + ln1b[tid], 0.f);
  H1[256 + tid] = fmaxf((v1 - m)*inv*ln1g[256 + tid] + ln1b[256 + tid], 0.f);
  __syncthreads();
  int ty = tid >> 3, tx = tid & 7;
  int o = oc*32 + ty;
  const float4* wr = (const float4*)(fc2w + (size_t)o*512) + tx*16;
  const float4* vv = (const float4*)H1 + tx*16;
  float t = 0.f;
  #pragma unroll
  for (int i = 0; i < 16; i++) {
    float4 w = wr[i]; float4 v = vv[i];
    t = fmaf(w.x, v.x, t); t = fmaf(w.y, v.y, t);
    t = fmaf(w.z, v.z, t); t = fmaf(w.w, v.w, t);
  }
  t += __shfl_xor(t, 1); t += __shfl_xor(t, 2); t += __shfl_xor(t, 4);
  if (tx == 0) h2buf[b*256 + o] = t + fc2b[o];
}

__global__ void __launch_bounds__(256) k_head3(const float* __restrict__ h2buf,
    const float* __restrict__ ln2g, const float* __restrict__ ln2b,
    const float* __restrict__ outw, const float* __restrict__ outb,
    float* __restrict__ out) {
  __shared__ __align__(16) float H2[256];
  __shared__ float red[256];
  int b = blockIdx.x, tid = threadIdx.x;
  float h2v = h2buf[b*256 + tid];
  float ss = blk_reduce(h2v, red, tid);
  float ss2 = blk_reduce(h2v*h2v, red, tid);
  float m2 = ss / 256.f;
  float var2 = ss2 / 256.f - m2*m2;
  float inv2 = 1.0f / sqrtf(var2 + 1e-5f);
  H2[tid] = fmaxf((h2v - m2)*inv2*ln2g[tid] + ln2b[tid], 0.f);
  __syncthreads();
  if (tid < 40) {
    const float4* wr = (const float4*)(outw + (size_t)tid*256);
    float t = 0.f;
    for (int c4 = 0; c4 < 64; c4++) {
      float4 w = wr[c4]; float4 vv = ((const float4*)H2)[c4];
      t = fmaf(w.x, vv.x, t); t = fmaf(w.y, vv.y, t);
      t = fmaf(w.z, vv.z, t); t = fmaf(w.w, vv.w, t);
    }
    red[tid] = t + outb[tid];
  }
  __syncthreads();
  if (tid == 0) {
    float mx = -__builtin_inff();
    for (int i2 = 0; i2 < 40; i2++) mx = fmaxf(mx, red[i2]);
    float se = 0.f;
    for (int i2 = 0; i2 < 40; i2++) se += expf(red[i2] - mx);
    float lse = mx + logf(se);
    for (int i2 = 0; i2 < 40; i2++) out[b*40 + i2] = red[i2] - lse;
  }
}

extern "C" void kernel_launch(void* const* d_in, const int* in_sizes, int n_in,
                              void* d_out, int out_size, void* d_ws, size_t ws_size,
                              hipStream_t stream) {
  (void)in_sizes; (void)n_in; (void)out_size; (void)ws_size;
  const float* x    = (const float*)d_in[0];
  const float* w1   = (const float*)d_in[1];
  const float* bn1g = (const float*)d_in[2];
  const float* bn1b = (const float*)d_in[3];
  const float* w2   = (const float*)d_in[4];
  const float* bn2g = (const float*)d_in[5];
  const float* bn2b = (const float*)d_in[6];
  const float* w3   = (const float*)d_in[7];
  const float* bn3g = (const float*)d_in[8];
  const float* bn3b = (const float*)d_in[9];
  const float* fc1w = (const float*)d_in[10];
  const float* fc1b = (const float*)d_in[11];
  const float* ln1g = (const float*)d_in[12];
  const float* ln1b = (const float*)d_in[13];
  const float* fc2w = (const float*)d_in[14];
  const float* fc2b = (const float*)d_in[15];
  const float* ln2g = (const float*)d_in[16];
  const float* ln2b = (const float*)d_in[17];
  const float* outw = (const float*)d_in[18];
  const float* outb = (const float*)d_in[19];
  float* out = (float*)d_out;

  float* ws = (float*)d_ws;
  size_t off = 0;
  float* xp1   = ws + off; off += 49152;
  float* hmax1 = ws + off; off += 1048576;
  float* hmin1 = ws + off; off += 1048576;
  float* xp2   = ws + off; off += 1048576;
  float* hmax2 = ws + off; off += 3145728;   // also keypartA (knn1 partials, 160/pt)
  float* hmin2 = ws + off; off += 3145728;
  unsigned* keypart2 = (unsigned*)(ws + off); off += 1310720;  // knn2 partials, 80/pt
  unsigned short* w2h = (unsigned short*)(ws + off); off += 24576;
  unsigned short* wt3h = (unsigned short*)(ws + off); off += 131072;
  float* x1T   = ws + off; off += 1048576;
  float* xx1   = ws + off; off += 16384;
  float* h1buf = ws + off; off += 8192;
  float* h2buf = ws + off; off += 4096;
  float* scale1 = ws + off; off += 64;
  float* shift1 = ws + off; off += 64;
  float* scale2 = ws + off; off += 192;
  float* shift2 = ws + off; off += 192;
  float* scale3 = ws + off; off += 1024;
  float* shift3 = ws + off; off += 1024;
  double* stats1sh = (double*)(ws + off);
  double* stats2sh = stats1sh + 64*64*2;
  double* stats3sh = stats2sh + 64*192*2;
  unsigned* hmax3u = (unsigned*)(stats3sh + (size_t)64*1024*2);
  unsigned* hmin3u = hmax3u + 16384;
  unsigned* keypartA = (unsigned*)hmax2;

  size_t zero_bytes = ((size_t)64*64*2 + (size_t)64*192*2 + (size_t)64*1024*2)*8 + (size_t)16384*4;
  hipMemsetAsync(stats1sh, 0, zero_bytes, stream);
  hipMemsetAsync(hmin3u, 0xFF, (size_t)16384*4, stream);

  k_prep_knn1<<<1536, 256, 0, stream>>>(x, xp1, w2, w3, w2h, wt3h, keypartA);
  k_conv1<<<1024, 256, 0, stream>>>(xp1, keypartA, w1, hmax1, hmin1, stats1sh);
  k_bn_reduce<<<64, 64, 0, stream>>>(stats1sh, 64, 327680.0, bn1g, bn1b, scale1, shift1);
  k_bn1_apply<<<256, 256, 0, stream>>>(hmax1, hmin1, scale1, shift1, xp2, x1T, xx1);
  k_knn2g<<<1024, 256, 0, stream>>>(x1T, xx1, keypart2);
  k_conv2m<<<4096, 256, 0, stream>>>(xp2, keypart2, w2h, hmax2, hmin2, stats2sh);
  k_bn_reduce<<<192, 64, 0, stream>>>(stats2sh, 192, 327680.0, bn2g, bn2b, scale2, shift2);
  k_conv3m<<<1024, 256, 0, stream>>>(hmax1, hmin1, scale1, shift1, hmax2, hmin2, scale2, shift2,
                                     wt3h, stats3sh, hmax3u, hmin3u);
  k_bn_reduce<<<1024, 64, 0, stream>>>(stats3sh, 1024, 16384.0, bn3g, bn3b, scale3, shift3);
  k_head1<<<512, 256, 0, stream>>>(hmax3u, hmin3u, scale3, shift3, fc1w, fc1b, h1buf);
  k_head2<<<128, 256, 0, stream>>>(h1buf, ln1g, ln1b, fc2w, fc2b, h2buf);
  k_head3<<<16, 256, 0, stream>>>(h2buf, ln2g, ln2b, outw, outb, out);
}

// Round 15
// 406.024 us; speedup vs baseline: 1.6314x; 1.0099x over previous
//
#include <hip/hip_runtime.h>
#include <math.h>

#define B_ 16
#define N_ 1024
#define KNN 20
#define NPAIR (B_*N_)

typedef __attribute__((ext_vector_type(8))) short bf16x8;
typedef __attribute__((ext_vector_type(4))) float f32x4;

// ---------- helpers ----------
__device__ __forceinline__ unsigned fkey(float f) {
  unsigned u = __float_as_uint(f);
  return (u & 0x80000000u) ? ~u : (u | 0x80000000u);
}
__device__ __forceinline__ float fkeyinv(unsigned u) {
  unsigned b = (u & 0x80000000u) ? (u ^ 0x80000000u) : ~u;
  return __uint_as_float(b);
}
__device__ __forceinline__ unsigned short f2bf(float x) {  // RNE float->bf16
  unsigned u = __float_as_uint(x);
  unsigned r = (u + 0x7FFFu + ((u >> 16) & 1u)) >> 16;
  return (unsigned short)r;
}
__device__ __forceinline__ float bf2f(unsigned short u) {
  return __uint_as_float(((unsigned)u) << 16);
}
// packed knn key: top 22 bits of fkey(d) | (1023 - idx). u32 '>' == dist desc, idx asc.
__device__ __forceinline__ unsigned knnkey(float d, int idx) {
  return (fkey(d) & 0xFFFFFC00u) | (unsigned)(1023 - idx);
}

// Branchless sorted-insert (descending) of packed u32 key: 2 ops/stage.
__device__ __forceinline__ void topk_insert_u32(unsigned (&kl)[KNN], unsigned nk) {
  kl[KNN-1] = nk;
  #pragma unroll
  for (int i = KNN-1; i > 0; i--) {
    unsigned hi = max(kl[i-1], kl[i]);
    unsigned lo = min(kl[i-1], kl[i]);
    kl[i-1] = hi; kl[i] = lo;
  }
}

// ---------- 1) fused prep + knn1: blocks 0..511 = knn1 8-way split; 512..1535 = prep ----------
__global__ void __launch_bounds__(256) k_prep_knn1(const float* __restrict__ x,
        float* __restrict__ xp1, const float* __restrict__ w2, const float* __restrict__ w3,
        unsigned short* __restrict__ w2h, unsigned short* __restrict__ wt3h,
        unsigned* __restrict__ keypart) {
  __shared__ float P[N_*3];
  __shared__ float XX[N_];
  if (blockIdx.x >= 512) {
    int i = (blockIdx.x - 512) * 256 + threadIdx.x;
    if (i < NPAIR) {
      float a0 = x[i*3+0], a1 = x[i*3+1], a2 = x[i*3+2];
      float n = sqrtf(a0*a0 + a1*a1 + a2*a2);
      n = fmaxf(n, 1e-15f);
      float th = tanhf(0.1f * n);
      float sc = th / (0.1f * n);
      float ny = fmaxf(th * 10.0f, 1e-15f);
      float mxn = (1.0f - 4e-3f) / 0.1f;
      if (ny > mxn) sc *= mxn / ny;
      xp1[i*3+0] = sc*a0; xp1[i*3+1] = sc*a1; xp1[i*3+2] = sc*a2;
    }
    if (i < 192*128) w2h[i] = f2bf(w2[i]);
    wt3h[i] = f2bf(w3[i]);
    return;
  }
  int blk = blockIdx.x;
  int b = blk >> 5, rc = (blk >> 3) & 3, cc = blk & 7;
  const float* xb = x + b*N_*3;
  for (int e = threadIdx.x; e < N_*3; e += 256) P[e] = xb[e];
  __syncthreads();
  for (int j = threadIdx.x; j < N_; j += 256) {
    float q0 = P[j*3], q1 = P[j*3+1], q2 = P[j*3+2];
    XX[j] = q0*q0 + q1*q1 + q2*q2;
  }
  __syncthreads();
  int r = rc*256 + threadIdx.x;
  float q0 = P[r*3], q1 = P[r*3+1], q2 = P[r*3+2];
  float xxq = XX[r];
  unsigned kl[KNN];
  #pragma unroll
  for (int i = 0; i < KNN; i++) kl[i] = 0u;
  int cbase = cc*128;
  for (int jj = 0; jj < 128; jj++) {
    int j = cbase + jj;
    float dot = q0*P[j*3] + q1*P[j*3+1] + q2*P[j*3+2];
    float d = 2.0f*dot - xxq - XX[j];
    unsigned nk = knnkey(d, j);
    if (nk > kl[KNN-1]) topk_insert_u32(kl, nk);
  }
  int p = b*N_ + r;
  unsigned* pe = keypart + (size_t)p*160 + cc*20;
  #pragma unroll
  for (int i = 0; i < KNN; i++) pe[i] = kl[i];
}

// ---------- 3) conv1 fused (inline 8-way merge of knn1 key chunks) ----------
__global__ void __launch_bounds__(256) k_conv1(const float* __restrict__ xp1,
                        const unsigned* __restrict__ keypart,
                        const float* __restrict__ w1, float* __restrict__ hmax1,
                        float* __restrict__ hmin1, double* __restrict__ stats1sh) {
  __shared__ float F[4][KNN][6];
  __shared__ float red[4][64][2];
  __shared__ int idxs[16][KNN];
  int g = threadIdx.x >> 6, lane = threadIdx.x & 63;
  int pbase = blockIdx.x * 16;
  if (threadIdx.x < 16) {
    const unsigned* pe = keypart + (size_t)(pbase + threadIdx.x)*160;
    int pos[8];
    #pragma unroll
    for (int c = 0; c < 8; c++) pos[c] = 0;
    for (int t = 0; t < KNN; t++) {
      unsigned best = 0u; int bc = 0;
      #pragma unroll
      for (int c = 0; c < 8; c++) {
        if (pos[c] < KNN) {
          unsigned v = pe[c*20 + pos[c]];
          if (v > best) { best = v; bc = c; }
        }
      }
      idxs[threadIdx.x][t] = 1023 - (int)(best & 1023u);
      #pragma unroll
      for (int c = 0; c < 8; c++) if (bc == c) pos[c]++;
    }
  }
  float w[6];
  #pragma unroll
  for (int c = 0; c < 6; c++) w[c] = w1[lane*6 + c];
  float sum = 0.f, sumsq = 0.f;
  __syncthreads();
  for (int it = 0; it < 4; ++it) {
    int p = pbase + it*4 + g;
    if (lane < KNN) {
      int nb = idxs[it*4 + g][lane];
      int bb = p >> 10;
      const float* xc = xp1 + p*3;
      const float* ft = xp1 + (bb*N_ + nb)*3;
      float x0 = ft[0], x1 = ft[1], x2v = ft[2];
      float c0 = xc[0], c1 = xc[1], c2 = xc[2];
      float X2 = x0*x0 + x1*x1 + x2v*x2v;
      float Y2 = c0*c0 + c1*c1 + c2*c2;
      float XY = -(x0*c0 + x1*c1 + x2v*c2);
      float den = fmaxf(1.0f + 0.02f*XY + 1e-4f*X2*Y2, 1e-15f);
      float s1 = (1.0f + 0.02f*XY + 0.01f*Y2) / den;
      float s2 = (1.0f - 0.01f*X2) / den;
      F[g][lane][0] = s1*x0 - s2*c0;
      F[g][lane][1] = s1*x1 - s2*c1;
      F[g][lane][2] = s1*x2v - s2*c2;
      F[g][lane][3] = c0; F[g][lane][4] = c1; F[g][lane][5] = c2;
    }
    __syncthreads();
    float mx = -__builtin_inff(), mn = __builtin_inff();
    for (int k = 0; k < KNN; k++) {
      float h = 0.f;
      #pragma unroll
      for (int c = 0; c < 6; c++) h = fmaf(w[c], F[g][k][c], h);
      mx = fmaxf(mx, h); mn = fminf(mn, h);
      sum += h; sumsq += h*h;
    }
    hmax1[(pbase + it*4 + g)*64 + lane] = mx;
    hmin1[(pbase + it*4 + g)*64 + lane] = mn;
    __syncthreads();
  }
  red[g][lane][0] = sum; red[g][lane][1] = sumsq;
  __syncthreads();
  if (g == 0) {
    float s  = red[0][lane][0] + red[1][lane][0] + red[2][lane][0] + red[3][lane][0];
    float s2 = red[0][lane][1] + red[1][lane][1] + red[2][lane][1] + red[3][lane][1];
    double* dst = stats1sh + ((size_t)(blockIdx.x & 63)*64 + lane)*2;
    atomicAdd(dst, (double)s);
    atomicAdd(dst + 1, (double)s2);
  }
}

// ---------- BN stat reduce v2: one channel per block, 64 lanes = 64 shadows ----------
__global__ void __launch_bounds__(64) k_bn_reduce(const double* __restrict__ sh, int nch, double cnt,
                            const float* __restrict__ g, const float* __restrict__ bb,
                            float* __restrict__ scale, float* __restrict__ shift) {
  int o = blockIdx.x, t = threadIdx.x;
  double s  = sh[((size_t)t*nch + o)*2];
  double s2 = sh[((size_t)t*nch + o)*2 + 1];
  #pragma unroll
  for (int off = 32; off > 0; off >>= 1) { s += __shfl_xor(s, off); s2 += __shfl_xor(s2, off); }
  if (t == 0) {
    double m = s / cnt;
    double v = s2 / cnt - m*m;
    float a = g[o] / sqrtf((float)v + 1e-5f);
    scale[o] = a;
    shift[o] = bb[o] - a * (float)m;
  }
}

// ---------- 5) BN1 apply + relu + e2p + coalesced x1T transpose + |x1|^2 ----------
__global__ void __launch_bounds__(256) k_bn1_apply(const float* __restrict__ hmax1, const float* __restrict__ hmin1,
                            const float* __restrict__ scale1, const float* __restrict__ shift1,
                            float* __restrict__ xp2,
                            float* __restrict__ x1T, float* __restrict__ xx1) {
  int b = blockIdx.x >> 4, nc = blockIdx.x & 15;
  int c = threadIdx.x & 63, sub = threadIdx.x >> 6;
  int n0 = nc*64 + sub*16;
  float a = scale1[c], t = shift1[c];
  float xr[16];
  #pragma unroll
  for (int i = 0; i < 16; i++) {
    int p = b*1024 + n0 + i;
    float h = (a >= 0.f) ? hmax1[(size_t)p*64 + c] : hmin1[(size_t)p*64 + c];
    float x1 = fmaxf(fmaf(a, h, t), 0.f);
    xr[i] = x1;
    float n2 = x1*x1;
    #pragma unroll
    for (int off = 32; off > 0; off >>= 1) n2 += __shfl_xor(n2, off);
    if (c == 0) xx1[p] = n2;
    float n1 = fmaxf(sqrtf(n2), 1e-15f);
    float th = tanhf(0.1f * n1);
    float sc = th / (0.1f * n1);
    float ny = fmaxf(th * 10.0f, 1e-15f);
    float mxn = (1.0f - 4e-3f) / 0.1f;
    if (ny > mxn) sc *= mxn / ny;
    xp2[(size_t)p*64 + c] = sc * x1;
  }
  float* dst = x1T + ((size_t)(b*64 + c))*1024 + n0;
  #pragma unroll
  for (int q = 0; q < 4; q++) {
    float4 v; v.x = xr[q*4]; v.y = xr[q*4+1]; v.z = xr[q*4+2]; v.w = xr[q*4+3];
    *((float4*)(dst + q*4)) = v;
  }
}

// ---------- 6) knn2 v7: 4-way split, packed-u32 selection, Bs prefetch, XCD-affine swizzle ----------
__global__ void __launch_bounds__(256) k_knn2g(const float* __restrict__ x1T,
        const float* __restrict__ xx1, unsigned* __restrict__ keypart2) {
  __shared__ __align__(16) float SM[8192];   // As @0 (64x64), BsD @4096 (64x64)
  float* As = SM;
  float* BsD = SM + 4096;
  int tid = threadIdx.x;
  // XCD-affine: XCD x (= i&7) owns blk in [x*128,(x+1)*128) -> b in {2x,2x+1} (512 KB x1T slice)
  int bi = blockIdx.x;
  int blk = ((bi & 7) << 7) + (bi >> 3);
  int b = blk >> 6, qc = (blk >> 2) & 15, cc = blk & 3;
  int qbase = qc*64, ccbase = cc*256;
  int tx = tid & 15, ty = tid >> 4;
  int wave = tid >> 6, lane = tid & 63;
  #pragma unroll
  for (int r = 0; r < 4; r++) {
    int e = tid + r*256;
    int k = e >> 4, qf = e & 15;
    *((float4*)(As + k*64 + qf*4)) =
      *((const float4*)(x1T + ((size_t)(b*64 + k))*1024 + qbase + qf*4));
  }
  float4 breg[4];
  #pragma unroll
  for (int r = 0; r < 4; r++) {
    int e = tid + r*256;
    int k = e >> 4, cf = e & 15;
    breg[r] = *((const float4*)(x1T + ((size_t)(b*64 + k))*1024 + ccbase + cf*4));
  }
  float4 xxcreg = *((const float4*)(xx1 + b*1024 + ccbase + ty*4));
  unsigned kl[KNN];
  #pragma unroll
  for (int i = 0; i < KNN; i++) kl[i] = 0u;
  int cq = lane + (lane >> 2);

  for (int st = 0; st < 4; ++st) {
    int cb0 = ccbase + st*64;
    __syncthreads();
    #pragma unroll
    for (int r = 0; r < 4; r++) {
      int e = tid + r*256;
      int k = e >> 4, cf = e & 15;
      *((float4*)(BsD + k*64 + cf*4)) = breg[r];
    }
    float4 xxc = xxcreg;
    if (st < 3) {
      int cb1 = cb0 + 64;
      #pragma unroll
      for (int r = 0; r < 4; r++) {
        int e = tid + r*256;
        int k = e >> 4, cf = e & 15;
        breg[r] = *((const float4*)(x1T + ((size_t)(b*64 + k))*1024 + cb1 + cf*4));
      }
      xxcreg = *((const float4*)(xx1 + b*1024 + cb1 + ty*4));
    }
    __syncthreads();
    float acc[4][4];
    #pragma unroll
    for (int i = 0; i < 4; i++)
      #pragma unroll
      for (int j = 0; j < 4; j++) acc[i][j] = 0.f;
    #pragma unroll 4
    for (int k = 0; k < 64; k++) {
      float4 a4 = *((const float4*)(As + k*64 + tx*4));
      float4 b4 = *((const float4*)(BsD + k*64 + ty*4));
      float av[4] = {a4.x, a4.y, a4.z, a4.w};
      float bw[4] = {b4.x, b4.y, b4.z, b4.w};
      #pragma unroll
      for (int i = 0; i < 4; i++)
        #pragma unroll
        for (int j = 0; j < 4; j++) acc[i][j] = fmaf(av[i], bw[j], acc[i][j]);
    }
    __syncthreads();
    float xxv[4] = {xxc.x, xxc.y, xxc.z, xxc.w};
    #pragma unroll
    for (int i = 0; i < 4; i++) {
      int q = tx*4 + i;
      #pragma unroll
      for (int j = 0; j < 4; j++) {
        int c = ty*4 + j;
        BsD[q*64 + ((c + q + (q >> 2)) & 63)] = 2.0f*acc[i][j] - xxv[j];
      }
    }
    __syncthreads();
    #pragma unroll
    for (int j = 0; j < 16; j++) {
      int c = wave*16 + j;
      float d = BsD[lane*64 + ((c + cq) & 63)];
      unsigned nk = knnkey(d, cb0 + c);
      if (nk > kl[KNN-1]) topk_insert_u32(kl, nk);
    }
  }
  __syncthreads();
  unsigned* U = (unsigned*)SM;
  unsigned* L0 = U;
  unsigned* L1 = U + 1344;
  unsigned* M  = U + 2688;
  if (wave == 0) {
    #pragma unroll
    for (int i = 0; i < KNN; i++) L0[lane*21 + i] = kl[i];
  } else if (wave == 1) {
    #pragma unroll
    for (int i = 0; i < KNN; i++) L1[lane*21 + i] = kl[i];
  }
  __syncthreads();
  if (tid < 64) {
    int ia = 0, ib = 0;
    for (int t = 0; t < KNN; t++) {
      unsigned pa = L0[tid*21 + ia], pb = L1[tid*21 + ib];
      bool ta = pa > pb;
      M[tid*21 + t] = ta ? pa : pb;
      if (ta) ia++; else ib++;
    }
  }
  __syncthreads();
  if (wave == 2) {
    #pragma unroll
    for (int i = 0; i < KNN; i++) L0[lane*21 + i] = kl[i];
  } else if (wave == 3) {
    #pragma unroll
    for (int i = 0; i < KNN; i++) L1[lane*21 + i] = kl[i];
  }
  __syncthreads();
  if (tid < 64) {
    int p = b*N_ + qbase + tid;
    unsigned* pe = keypart2 + (size_t)p*80 + cc*20;
    int ia = 0, ib = 0, im = 0;
    for (int t = 0; t < KNN; t++) {
      unsigned pa = L0[tid*21 + ia], pb = L1[tid*21 + ib], pm = M[tid*21 + im];
      unsigned bp = pm; int sel = 2;
      if (pa > bp) { bp = pa; sel = 0; }
      if (pb > bp) { bp = pb; sel = 1; }
      pe[t] = bp;
      if (sel == 0) ia++; else if (sel == 1) ib++; else im++;
    }
  }
}

// ---------- 9) conv2 via bf16 MFMA v5: XCD-affine swizzle + inline merge + register epilogue ----------
__global__ void __launch_bounds__(256) k_conv2m(const float* __restrict__ xp2,
    const unsigned* __restrict__ keypart2, const unsigned short* __restrict__ w2h,
    float* __restrict__ hmax2, float* __restrict__ hmin2, double* __restrict__ stats2sh) {
  __shared__ __align__(16) short Abf[80*136];
  __shared__ float s1s[80], s2s[80];
  __shared__ int nbr[80];                        // logical order [pt*20 + k]
  int tid = threadIdx.x;
  // XCD-affine: XCD x (= i&7) owns g in [x*512,(x+1)*512) -> b in {2x,2x+1} (512 KB xp2 slice)
  int bi = blockIdx.x;
  int g512 = ((bi & 7) << 9) + (bi >> 3);
  int p0 = g512 * 4;
  int b = p0 >> 10;
  if (tid < 4) {
    const unsigned* pe = keypart2 + (size_t)(p0 + tid)*80;
    int pos[4];
    #pragma unroll
    for (int c = 0; c < 4; c++) pos[c] = 0;
    for (int t = 0; t < KNN; t++) {
      unsigned best = 0u; int bc = 0;
      #pragma unroll
      for (int c = 0; c < 4; c++) {
        if (pos[c] < KNN) {
          unsigned v = pe[c*20 + pos[c]];
          if (v > best) { best = v; bc = c; }
        }
      }
      nbr[tid*20 + t] = 1023 - (int)(best & 1023u);
      #pragma unroll
      for (int c = 0; c < 4; c++) if (bc == c) pos[c]++;
    }
  }
  __syncthreads();
  for (int e = tid; e < 80*16; e += 256) {
    int r = e >> 4, qq = e & 15;
    int q = (r >> 2) & 3;
    int L = 20*q + 4*(r >> 4) + (r & 3);
    float4 f = *((const float4*)(xp2 + (size_t)(b*N_ + nbr[L])*64) + qq);
    float4 cv = *((const float4*)(xp2 + (size_t)(p0 + q)*64) + qq);
    ushort4 fb, cb;
    fb.x = f2bf(f.x); fb.y = f2bf(f.y); fb.z = f2bf(f.z); fb.w = f2bf(f.w);
    cb.x = f2bf(cv.x); cb.y = f2bf(cv.y); cb.z = f2bf(cv.z); cb.w = f2bf(cv.w);
    *((ushort4*)(Abf + r*136 + qq*4)) = fb;
    *((ushort4*)(Abf + r*136 + 64 + qq*4)) = cb;
  }
  __syncthreads();
  if (tid < 160) {
    int r = tid >> 1, h = tid & 1;
    const unsigned short* Ar = (const unsigned short*)(Abf + r*136) + h*32;
    const unsigned short* Xr = (const unsigned short*)(Abf + r*136 + 64) + h*32;
    float X2 = 0.f, XY = 0.f, Y2 = 0.f;
    for (int c2 = 0; c2 < 32; c2++) {
      float f = bf2f(Ar[c2]), xcv = bf2f(Xr[c2]);
      X2 = fmaf(f, f, X2); XY = fmaf(-f, xcv, XY); Y2 = fmaf(xcv, xcv, Y2);
    }
    X2 += __shfl_xor(X2, 1); XY += __shfl_xor(XY, 1); Y2 += __shfl_xor(Y2, 1);
    if (h == 0) {
      float den = fmaxf(1.0f + 0.02f*XY + 1e-4f*X2*Y2, 1e-15f);
      s1s[r] = (1.0f + 0.02f*XY + 0.01f*Y2) / den;
      s2s[r] = (1.0f - 0.01f*X2) / den;
    }
  }
  __syncthreads();
  for (int e = tid; e < 80*16; e += 256) {
    int r = e >> 4, qq = e & 15;
    ushort4 fr = *((const ushort4*)(Abf + r*136 + qq*4));
    ushort4 xr4 = *((const ushort4*)(Abf + r*136 + 64 + qq*4));
    float s1 = s1s[r], s2 = s2s[r];
    ushort4 mo;
    mo.x = f2bf(s1*bf2f(fr.x) - s2*bf2f(xr4.x));
    mo.y = f2bf(s1*bf2f(fr.y) - s2*bf2f(xr4.y));
    mo.z = f2bf(s1*bf2f(fr.z) - s2*bf2f(xr4.z));
    mo.w = f2bf(s1*bf2f(fr.w) - s2*bf2f(xr4.w));
    *((ushort4*)(Abf + r*136 + qq*4)) = mo;
  }
  __syncthreads();
  int wave = tid >> 6, lane = tid & 63;
  int quad = lane >> 4, lm = lane & 15;
  int colbase = wave*48;
  f32x4 acc[5][3];
  #pragma unroll
  for (int rt = 0; rt < 5; rt++)
    #pragma unroll
    for (int cj = 0; cj < 3; cj++) acc[rt][cj] = (f32x4){0.f, 0.f, 0.f, 0.f};
  #pragma unroll
  for (int kt = 0; kt < 4; kt++) {
    int k0 = kt*32 + quad*8;
    bf16x8 bf[3];
    #pragma unroll
    for (int cj = 0; cj < 3; cj++)
      bf[cj] = *((const bf16x8*)(w2h + (size_t)(colbase + cj*16 + lm)*128 + k0));
    bf16x8 af[5];
    #pragma unroll
    for (int rt = 0; rt < 5; rt++)
      af[rt] = *((const bf16x8*)(Abf + (rt*16 + lm)*136 + k0));
    #pragma unroll
    for (int rt = 0; rt < 5; rt++)
      #pragma unroll
      for (int cj = 0; cj < 3; cj++)
        acc[rt][cj] = __builtin_amdgcn_mfma_f32_16x16x32_bf16(af[rt], bf[cj], acc[rt][cj], 0, 0, 0);
  }
  #pragma unroll
  for (int cj = 0; cj < 3; cj++) {
    int o = colbase + cj*16 + lm;
    float s = 0.f, s2 = 0.f, mx = -__builtin_inff(), mn = __builtin_inff();
    #pragma unroll
    for (int rt = 0; rt < 5; rt++) {
      #pragma unroll
      for (int reg = 0; reg < 4; reg++) {
        float h = acc[rt][cj][reg];
        s += h; s2 += h*h;
        mx = fmaxf(mx, h); mn = fminf(mn, h);
      }
    }
    hmax2[(size_t)(p0 + quad)*192 + o] = mx;
    hmin2[(size_t)(p0 + quad)*192 + o] = mn;
    s  += __shfl_xor(s, 16);  s  += __shfl_xor(s, 32);
    s2 += __shfl_xor(s2, 16); s2 += __shfl_xor(s2, 32);
    if (lane < 16) {
      double* dst = stats2sh + ((size_t)(bi & 63)*192 + o)*2;
      atomicAdd(dst, (double)s); atomicAdd(dst + 1, (double)s2);
    }
  }
}

// ---------- 11) conv3 via bf16 MFMA, A-tile staged directly from BN1/BN2 max/min ----------
__global__ void __launch_bounds__(256) k_conv3m(
   const float* __restrict__ hmax1, const float* __restrict__ hmin1,
   const float* __restrict__ scale1, const float* __restrict__ shift1,
   const float* __restrict__ hmax2, const float* __restrict__ hmin2,
   const float* __restrict__ scale2, const float* __restrict__ shift2,
   const unsigned short* __restrict__ wt3h, double* __restrict__ stats3sh,
   unsigned* __restrict__ hmax3u, unsigned* __restrict__ hmin3u) {
  __shared__ short As[64*264];
  int tid = threadIdx.x;
  int mt = blockIdx.x >> 2, cb = blockIdx.x & 3;
  int rowbase = mt*64;
  int b = rowbase >> 10;
  int c4 = tid & 63;
  float4 sc, sh;
  if (c4 < 16) {
    sc = *((const float4*)(scale1 + c4*4));
    sh = *((const float4*)(shift1 + c4*4));
  } else {
    sc = *((const float4*)(scale2 + (c4*4 - 64)));
    sh = *((const float4*)(shift2 + (c4*4 - 64)));
  }
  #pragma unroll 4
  for (int i = 0; i < 16; i++) {
    int r = (tid >> 6) + i*4;
    int p = rowbase + r;
    float4 hx, hn;
    if (c4 < 16) {
      hx = *((const float4*)(hmax1 + (size_t)p*64 + c4*4));
      hn = *((const float4*)(hmin1 + (size_t)p*64 + c4*4));
    } else {
      hx = *((const float4*)(hmax2 + (size_t)p*192 + (c4*4 - 64)));
      hn = *((const float4*)(hmin2 + (size_t)p*192 + (c4*4 - 64)));
    }
    ushort4 o4;
    o4.x = f2bf(fmaxf(fmaf(sc.x, (sc.x >= 0.f ? hx.x : hn.x), sh.x), 0.f));
    o4.y = f2bf(fmaxf(fmaf(sc.y, (sc.y >= 0.f ? hx.y : hn.y), sh.y), 0.f));
    o4.z = f2bf(fmaxf(fmaf(sc.z, (sc.z >= 0.f ? hx.z : hn.z), sh.z), 0.f));
    o4.w = f2bf(fmaxf(fmaf(sc.w, (sc.w >= 0.f ? hx.w : hn.w), sh.w), 0.f));
    *((ushort4*)(As + r*264 + c4*4)) = o4;
  }
  __syncthreads();
  int wave = tid >> 6, lane = tid & 63;
  int quad = lane >> 4, lm = lane & 15;
  int colbase = cb*256 + wave*64;
  f32x4 acc[4][4];
  #pragma unroll
  for (int ri = 0; ri < 4; ri++)
    #pragma unroll
    for (int cj = 0; cj < 4; cj++) acc[ri][cj] = (f32x4){0.f, 0.f, 0.f, 0.f};
  for (int kt = 0; kt < 8; kt++) {
    int k0 = kt*32 + quad*8;
    bf16x8 bf[4];
    #pragma unroll
    for (int cj = 0; cj < 4; cj++)
      bf[cj] = *((const bf16x8*)(wt3h + (size_t)(colbase + cj*16 + lm)*256 + k0));
    bf16x8 af[4];
    #pragma unroll
    for (int ri = 0; ri < 4; ri++)
      af[ri] = *((const bf16x8*)(As + (ri*16 + lm)*264 + k0));
    #pragma unroll
    for (int ri = 0; ri < 4; ri++)
      #pragma unroll
      for (int cj = 0; cj < 4; cj++)
        acc[ri][cj] = __builtin_amdgcn_mfma_f32_16x16x32_bf16(af[ri], bf[cj], acc[ri][cj], 0, 0, 0);
  }
  #pragma unroll
  for (int cj = 0; cj < 4; cj++) {
    float s = 0.f, s2 = 0.f, mx = -__builtin_inff(), mn = __builtin_inff();
    #pragma unroll
    for (int ri = 0; ri < 4; ri++) {
      #pragma unroll
      for (int reg = 0; reg < 4; reg++) {
        float h = acc[ri][cj][reg];
        s += h; s2 += h*h; mx = fmaxf(mx, h); mn = fminf(mn, h);
      }
    }
    s  += __shfl_xor(s, 16);  s  += __shfl_xor(s, 32);
    s2 += __shfl_xor(s2, 16); s2 += __shfl_xor(s2, 32);
    mx = fmaxf(mx, __shfl_xor(mx, 16)); mx = fmaxf(mx, __shfl_xor(mx, 32));
    mn = fminf(mn, __shfl_xor(mn, 16)); mn = fminf(mn, __shfl_xor(mn, 32));
    if (lane < 16) {
      int col = colbase + cj*16 + lane;
      double* dst = stats3sh + ((size_t)(blockIdx.x & 63)*1024 + col)*2;
      atomicAdd(dst, (double)s);
      atomicAdd(dst + 1, (double)s2);
      atomicMax(hmax3u + b*1024 + col, fkey(mx));
      atomicMin(hmin3u + b*1024 + col, fkey(mn));
    }
  }
}

// ---------- 12) head, split for weight-read parallelism ----------
__device__ float blk_reduce(float v, float* red, int tid) {
  red[tid] = v; __syncthreads();
  for (int st = 128; st > 0; st >>= 1) {
    if (tid < st) red[tid] += red[tid + st];
    __syncthreads();
  }
  float r = red[0]; __syncthreads();
  return r;
}

__global__ void __launch_bounds__(256) k_head1(const unsigned* __restrict__ hmax3u,
    const unsigned* __restrict__ hmin3u,
    const float* __restrict__ scale3, const float* __restrict__ shift3,
    const float* __restrict__ fc1w, const float* __restrict__ fc1b,
    float* __restrict__ h1buf) {
  __shared__ __align__(16) float V[1024];
  int b = blockIdx.x >> 5, oc = blockIdx.x & 31;
  int tid = threadIdx.x;
  for (int o = tid; o < 1024; o += 256) {
    float a = scale3[o];
    unsigned u = (a >= 0.f) ? hmax3u[b*1024 + o] : hmin3u[b*1024 + o];
    V[o] = fmaxf(fmaf(a, fkeyinv(u), shift3[o]), 0.f);
  }
  __syncthreads();
  int ty = tid >> 4, tx = tid & 15;
  int o = oc*16 + ty;
  const float4* wr = (const float4*)(fc1w + (size_t)o*1024) + tx*16;
  const float4* vv = (const float4*)V + tx*16;
  float s = 0.f;
  #pragma unroll
  for (int i = 0; i < 16; i++) {
    float4 w = wr[i]; float4 v = vv[i];
    s = fmaf(w.x, v.x, s); s = fmaf(w.y, v.y, s);
    s = fmaf(w.z, v.z, s); s = fmaf(w.w, v.w, s);
  }
  s += __shfl_xor(s, 1); s += __shfl_xor(s, 2);
  s += __shfl_xor(s, 4); s += __shfl_xor(s, 8);
  if (tx == 0) h1buf[b*512 + o] = s + fc1b[o];
}

__global__ void __launch_bounds__(256) k_head2(const float* __restrict__ h1buf,
    const float* __restrict__ ln1g, const float* __restrict__ ln1b,
    const float* __restrict__ fc2w, const float* __restrict__ fc2b,
    float* __restrict__ h2buf) {
  __shared__ __align__(16) float H1[512];
  __shared__ float red[256];
  int b = blockIdx.x >> 3, oc = blockIdx.x & 7;
  int tid = threadIdx.x;
  float v0 = h1buf[b*512 + tid], v1 = h1buf[b*512 + 256 + tid];
  float s = blk_reduce(v0 + v1, red, tid);
  float s2 = blk_reduce(v0*v0 + v1*v1, red, tid);
  float m = s / 512.f;
  float var = s2 / 512.f - m*m;
  float inv = 1.0f / sqrtf(var + 1e-5f);
  H1[tid] = fmaxf((v0 - m)*inv*ln1g[tid] + ln1b[tid], 0.f);
  H1[256 + tid] = fmaxf((v1 - m)*inv*ln1g[256 + tid] + ln1b[256 + tid], 0.f);
  __syncthreads();
  int ty = tid >> 3, tx = tid & 7;
  int o = oc*32 + ty;
  const float4* wr = (const float4*)(fc2w + (size_t)o*512) + tx*16;
  const float4* vv = (const float4*)H1 + tx*16;
  float t = 0.f;
  #pragma unroll
  for (int i = 0; i < 16; i++) {
    float4 w = wr[i]; float4 v = vv[i];
    t = fmaf(w.x, v.x, t); t = fmaf(w.y, v.y, t);
    t = fmaf(w.z, v.z, t); t = fmaf(w.w, v.w, t);
  }
  t += __shfl_xor(t, 1); t += __shfl_xor(t, 2); t += __shfl_xor(t, 4);
  if (tx == 0) h2buf[b*256 + o] = t + fc2b[o];
}

__global__ void __launch_bounds__(256) k_head3(const float* __restrict__ h2buf,
    const float* __restrict__ ln2g, const float* __restrict__ ln2b,
    const float* __restrict__ outw, const float* __restrict__ outb,
    float* __restrict__ out) {
  __shared__ __align__(16) float H2[256];
  __shared__ float red[256];
  int b = blockIdx.x, tid = threadIdx.x;
  float h2v = h2buf[b*256 + tid];
  float ss = blk_reduce(h2v, red, tid);
  float ss2 = blk_reduce(h2v*h2v, red, tid);
  float m2 = ss / 256.f;
  float var2 = ss2 / 256.f - m2*m2;
  float inv2 = 1.0f / sqrtf(var2 + 1e-5f);
  H2[tid] = fmaxf((h2v - m2)*inv2*ln2g[tid] + ln2b[tid], 0.f);
  __syncthreads();
  if (tid < 40) {
    const float4* wr = (const float4*)(outw + (size_t)tid*256);
    float t = 0.f;
    for (int c4 = 0; c4 < 64; c4++) {
      float4 w = wr[c4]; float4 vv = ((const float4*)H2)[c4];
      t = fmaf(w.x, vv.x, t); t = fmaf(w.y, vv.y, t);
      t = fmaf(w.z, vv.z, t); t = fmaf(w.w, vv.w, t);
    }
    red[tid] = t + outb[tid];
  }
  __syncthreads();
  if (tid == 0) {
    float mx = -__builtin_inff();
    for (int i2 = 0; i2 < 40; i2++) mx = fmaxf(mx, red[i2]);
    float se = 0.f;
    for (int i2 = 0; i2 < 40; i2++) se += expf(red[i2] - mx);
    float lse = mx + logf(se);
    for (int i2 = 0; i2 < 40; i2++) out[b*40 + i2] = red[i2] - lse;
  }
}

extern "C" void kernel_launch(void* const* d_in, const int* in_sizes, int n_in,
                              void* d_out, int out_size, void* d_ws, size_t ws_size,
                              hipStream_t stream) {
  (void)in_sizes; (void)n_in; (void)out_size; (void)ws_size;
  const float* x    = (const float*)d_in[0];
  const float* w1   = (const float*)d_in[1];
  const float* bn1g = (const float*)d_in[2];
  const float* bn1b = (const float*)d_in[3];
  const float* w2   = (const float*)d_in[4];
  const float* bn2g = (const float*)d_in[5];
  const float* bn2b = (const float*)d_in[6];
  const float* w3   = (const float*)d_in[7];
  const float* bn3g = (const float*)d_in[8];
  const float* bn3b = (const float*)d_in[9];
  const float* fc1w = (const float*)d_in[10];
  const float* fc1b = (const float*)d_in[11];
  const float* ln1g = (const float*)d_in[12];
  const float* ln1b = (const float*)d_in[13];
  const float* fc2w = (const float*)d_in[14];
  const float* fc2b = (const float*)d_in[15];
  const float* ln2g = (const float*)d_in[16];
  const float* ln2b = (const float*)d_in[17];
  const float* outw = (const float*)d_in[18];
  const float* outb = (const float*)d_in[19];
  float* out = (float*)d_out;

  float* ws = (float*)d_ws;
  size_t off = 0;
  float* xp1   = ws + off; off += 49152;
  float* hmax1 = ws + off; off += 1048576;
  float* hmin1 = ws + off; off += 1048576;
  float* xp2   = ws + off; off += 1048576;
  float* hmax2 = ws + off; off += 3145728;   // also keypartA (knn1 partials, 160/pt)
  float* hmin2 = ws + off; off += 3145728;
  unsigned* keypart2 = (unsigned*)(ws + off); off += 1310720;  // knn2 partials, 80/pt
  unsigned short* w2h = (unsigned short*)(ws + off); off += 24576;
  unsigned short* wt3h = (unsigned short*)(ws + off); off += 131072;
  float* x1T   = ws + off; off += 1048576;
  float* xx1   = ws + off; off += 16384;
  float* h1buf = ws + off; off += 8192;
  float* h2buf = ws + off; off += 4096;
  float* scale1 = ws + off; off += 64;
  float* shift1 = ws + off; off += 64;
  float* scale2 = ws + off; off += 192;
  float* shift2 = ws + off; off += 192;
  float* scale3 = ws + off; off += 1024;
  float* shift3 = ws + off; off += 1024;
  double* stats1sh = (double*)(ws + off);
  double* stats2sh = stats1sh + 64*64*2;
  double* stats3sh = stats2sh + 64*192*2;
  unsigned* hmax3u = (unsigned*)(stats3sh + (size_t)64*1024*2);
  unsigned* hmin3u = hmax3u + 16384;
  unsigned* keypartA = (unsigned*)hmax2;

  size_t zero_bytes = ((size_t)64*64*2 + (size_t)64*192*2 + (size_t)64*1024*2)*8 + (size_t)16384*4;
  hipMemsetAsync(stats1sh, 0, zero_bytes, stream);
  hipMemsetAsync(hmin3u, 0xFF, (size_t)16384*4, stream);

  k_prep_knn1<<<1536, 256, 0, stream>>>(x, xp1, w2, w3, w2h, wt3h, keypartA);
  k_conv1<<<1024, 256, 0, stream>>>(xp1, keypartA, w1, hmax1, hmin1, stats1sh);
  k_bn_reduce<<<64, 64, 0, stream>>>(stats1sh, 64, 327680.0, bn1g, bn1b, scale1, shift1);
  k_bn1_apply<<<256, 256, 0, stream>>>(hmax1, hmin1, scale1, shift1, xp2, x1T, xx1);
  k_knn2g<<<1024, 256, 0, stream>>>(x1T, xx1, keypart2);
  k_conv2m<<<4096, 256, 0, stream>>>(xp2, keypart2, w2h, hmax2, hmin2, stats2sh);
  k_bn_reduce<<<192, 64, 0, stream>>>(stats2sh, 192, 327680.0, bn2g, bn2b, scale2, shift2);
  k_conv3m<<<1024, 256, 0, stream>>>(hmax1, hmin1, scale1, shift1, hmax2, hmin2, scale2, shift2,
                                     wt3h, stats3sh, hmax3u, hmin3u);
  k_bn_reduce<<<1024, 64, 0, stream>>>(stats3sh, 1024, 16384.0, bn3g, bn3b, scale3, shift3);
  k_head1<<<512, 256, 0, stream>>>(hmax3u, hmin3u, scale3, shift3, fc1w, fc1b, h1buf);
  k_head2<<<128, 256, 0, stream>>>(h1buf, ln1g, ln1b, fc2w, fc2b, h2buf);
  k_head3<<<16, 256, 0, stream>>>(h2buf, ln2g, ln2b, outw, outb, out);
}

// Round 17
// 387.642 us; speedup vs baseline: 1.7087x; 1.0474x over previous
//
#include <hip/hip_runtime.h>
#include <math.h>

#define B_ 16
#define N_ 1024
#define KNN 20
#define NPAIR (B_*N_)

typedef __attribute__((ext_vector_type(8))) short bf16x8;
typedef __attribute__((ext_vector_type(4))) float f32x4;

// ---------- helpers ----------
__device__ __forceinline__ unsigned fkey(float f) {
  unsigned u = __float_as_uint(f);
  return (u & 0x80000000u) ? ~u : (u | 0x80000000u);
}
__device__ __forceinline__ float fkeyinv(unsigned u) {
  unsigned b = (u & 0x80000000u) ? (u ^ 0x80000000u) : ~u;
  return __uint_as_float(b);
}
__device__ __forceinline__ unsigned short f2bf(float x) {  // RNE float->bf16
  unsigned u = __float_as_uint(x);
  unsigned r = (u + 0x7FFFu + ((u >> 16) & 1u)) >> 16;
  return (unsigned short)r;
}
__device__ __forceinline__ float bf2f(unsigned short u) {
  return __uint_as_float(((unsigned)u) << 16);
}
// packed knn key: top 22 bits of fkey(d) | (1023 - idx). u32 '>' == dist desc, idx asc.
__device__ __forceinline__ unsigned knnkey(float d, int idx) {
  return (fkey(d) & 0xFFFFFC00u) | (unsigned)(1023 - idx);
}

// Branchless sorted-insert (descending) of packed u32 key: 2 ops/stage.
__device__ __forceinline__ void topk_insert_u32(unsigned (&kl)[KNN], unsigned nk) {
  kl[KNN-1] = nk;
  #pragma unroll
  for (int i = KNN-1; i > 0; i--) {
    unsigned hi = max(kl[i-1], kl[i]);
    unsigned lo = min(kl[i-1], kl[i]);
    kl[i-1] = hi; kl[i] = lo;
  }
}

// ---------- 1) fused prep + knn1: blocks 0..511 = knn1 8-way split; 512..1535 = prep ----------
__global__ void __launch_bounds__(256) k_prep_knn1(const float* __restrict__ x,
        float* __restrict__ xp1, const float* __restrict__ w2, const float* __restrict__ w3,
        unsigned short* __restrict__ w2h, unsigned short* __restrict__ wt3h,
        unsigned* __restrict__ keypart) {
  __shared__ float P[N_*3];
  __shared__ float XX[N_];
  if (blockIdx.x >= 512) {
    int i = (blockIdx.x - 512) * 256 + threadIdx.x;
    if (i < NPAIR) {
      float a0 = x[i*3+0], a1 = x[i*3+1], a2 = x[i*3+2];
      float n = sqrtf(a0*a0 + a1*a1 + a2*a2);
      n = fmaxf(n, 1e-15f);
      float th = tanhf(0.1f * n);
      float sc = th / (0.1f * n);
      float ny = fmaxf(th * 10.0f, 1e-15f);
      float mxn = (1.0f - 4e-3f) / 0.1f;
      if (ny > mxn) sc *= mxn / ny;
      xp1[i*3+0] = sc*a0; xp1[i*3+1] = sc*a1; xp1[i*3+2] = sc*a2;
    }
    if (i < 192*128) w2h[i] = f2bf(w2[i]);
    wt3h[i] = f2bf(w3[i]);
    return;
  }
  int blk = blockIdx.x;
  int b = blk >> 5, rc = (blk >> 3) & 3, cc = blk & 7;
  const float* xb = x + b*N_*3;
  for (int e = threadIdx.x; e < N_*3; e += 256) P[e] = xb[e];
  __syncthreads();
  for (int j = threadIdx.x; j < N_; j += 256) {
    float q0 = P[j*3], q1 = P[j*3+1], q2 = P[j*3+2];
    XX[j] = q0*q0 + q1*q1 + q2*q2;
  }
  __syncthreads();
  int r = rc*256 + threadIdx.x;
  float q0 = P[r*3], q1 = P[r*3+1], q2 = P[r*3+2];
  float xxq = XX[r];
  unsigned kl[KNN];
  #pragma unroll
  for (int i = 0; i < KNN; i++) kl[i] = 0u;
  int cbase = cc*128;
  for (int jj = 0; jj < 128; jj++) {
    int j = cbase + jj;
    float dot = q0*P[j*3] + q1*P[j*3+1] + q2*P[j*3+2];
    float d = 2.0f*dot - xxq - XX[j];
    unsigned nk = knnkey(d, j);
    if (nk > kl[KNN-1]) topk_insert_u32(kl, nk);
  }
  int p = b*N_ + r;
  unsigned* pe = keypart + (size_t)p*160 + cc*20;
  #pragma unroll
  for (int i = 0; i < KNN; i++) pe[i] = kl[i];
}

// ---------- 3) conv1 fused (inline 8-way merge, inputs staged to LDS) ----------
__global__ void __launch_bounds__(256) k_conv1(const float* __restrict__ xp1,
                        const unsigned* __restrict__ keypart,
                        const float* __restrict__ w1, float* __restrict__ hmax1,
                        float* __restrict__ hmin1, double* __restrict__ stats1sh) {
  __shared__ float F[4][KNN][6];
  __shared__ float red[4][64][2];
  __shared__ int idxs[16][KNN];
  __shared__ unsigned keybuf[2560];   // 16 pairs x 160 keys, 10 KB
  int g = threadIdx.x >> 6, lane = threadIdx.x & 63;
  int pbase = blockIdx.x * 16;
  {
    const unsigned* src = keypart + (size_t)pbase*160;
    for (int e = threadIdx.x; e < 2560; e += 256) keybuf[e] = src[e];
  }
  float w[6];
  #pragma unroll
  for (int c = 0; c < 6; c++) w[c] = w1[lane*6 + c];
  __syncthreads();
  if (threadIdx.x < 16) {
    const unsigned* pe = keybuf + threadIdx.x*160;
    int pos[8];
    #pragma unroll
    for (int c = 0; c < 8; c++) pos[c] = 0;
    for (int t = 0; t < KNN; t++) {
      unsigned best = 0u; int bc = 0;
      #pragma unroll
      for (int c = 0; c < 8; c++) {
        if (pos[c] < KNN) {
          unsigned v = pe[c*20 + pos[c]];
          if (v > best) { best = v; bc = c; }
        }
      }
      idxs[threadIdx.x][t] = 1023 - (int)(best & 1023u);
      #pragma unroll
      for (int c = 0; c < 8; c++) if (bc == c) pos[c]++;
    }
  }
  float sum = 0.f, sumsq = 0.f;
  __syncthreads();
  for (int it = 0; it < 4; ++it) {
    int p = pbase + it*4 + g;
    if (lane < KNN) {
      int nb = idxs[it*4 + g][lane];
      int bb = p >> 10;
      const float* xc = xp1 + p*3;
      const float* ft = xp1 + (bb*N_ + nb)*3;
      float x0 = ft[0], x1 = ft[1], x2v = ft[2];
      float c0 = xc[0], c1 = xc[1], c2 = xc[2];
      float X2 = x0*x0 + x1*x1 + x2v*x2v;
      float Y2 = c0*c0 + c1*c1 + c2*c2;
      float XY = -(x0*c0 + x1*c1 + x2v*c2);
      float den = fmaxf(1.0f + 0.02f*XY + 1e-4f*X2*Y2, 1e-15f);
      float s1 = (1.0f + 0.02f*XY + 0.01f*Y2) / den;
      float s2 = (1.0f - 0.01f*X2) / den;
      F[g][lane][0] = s1*x0 - s2*c0;
      F[g][lane][1] = s1*x1 - s2*c1;
      F[g][lane][2] = s1*x2v - s2*c2;
      F[g][lane][3] = c0; F[g][lane][4] = c1; F[g][lane][5] = c2;
    }
    __syncthreads();
    float mx = -__builtin_inff(), mn = __builtin_inff();
    for (int k = 0; k < KNN; k++) {
      float h = 0.f;
      #pragma unroll
      for (int c = 0; c < 6; c++) h = fmaf(w[c], F[g][k][c], h);
      mx = fmaxf(mx, h); mn = fminf(mn, h);
      sum += h; sumsq += h*h;
    }
    hmax1[(pbase + it*4 + g)*64 + lane] = mx;
    hmin1[(pbase + it*4 + g)*64 + lane] = mn;
    __syncthreads();
  }
  red[g][lane][0] = sum; red[g][lane][1] = sumsq;
  __syncthreads();
  if (g == 0) {
    float s  = red[0][lane][0] + red[1][lane][0] + red[2][lane][0] + red[3][lane][0];
    float s2 = red[0][lane][1] + red[1][lane][1] + red[2][lane][1] + red[3][lane][1];
    double* dst = stats1sh + ((size_t)(blockIdx.x & 63)*64 + lane)*2;
    atomicAdd(dst, (double)s);
    atomicAdd(dst + 1, (double)s2);
  }
}

// ---------- BN stat reduce v2 ----------
__global__ void __launch_bounds__(64) k_bn_reduce(const double* __restrict__ sh, int nch, double cnt,
                            const float* __restrict__ g, const float* __restrict__ bb,
                            float* __restrict__ scale, float* __restrict__ shift) {
  int o = blockIdx.x, t = threadIdx.x;
  double s  = sh[((size_t)t*nch + o)*2];
  double s2 = sh[((size_t)t*nch + o)*2 + 1];
  #pragma unroll
  for (int off = 32; off > 0; off >>= 1) { s += __shfl_xor(s, off); s2 += __shfl_xor(s2, off); }
  if (t == 0) {
    double m = s / cnt;
    double v = s2 / cnt - m*m;
    float a = g[o] / sqrtf((float)v + 1e-5f);
    scale[o] = a;
    shift[o] = bb[o] - a * (float)m;
  }
}

// ---------- 5) BN1 apply + relu + e2p + coalesced x1T transpose + |x1|^2 ----------
__global__ void __launch_bounds__(256) k_bn1_apply(const float* __restrict__ hmax1, const float* __restrict__ hmin1,
                            const float* __restrict__ scale1, const float* __restrict__ shift1,
                            float* __restrict__ xp2,
                            float* __restrict__ x1T, float* __restrict__ xx1) {
  int b = blockIdx.x >> 4, nc = blockIdx.x & 15;
  int c = threadIdx.x & 63, sub = threadIdx.x >> 6;
  int n0 = nc*64 + sub*16;
  float a = scale1[c], t = shift1[c];
  float xr[16];
  #pragma unroll
  for (int i = 0; i < 16; i++) {
    int p = b*1024 + n0 + i;
    float h = (a >= 0.f) ? hmax1[(size_t)p*64 + c] : hmin1[(size_t)p*64 + c];
    float x1 = fmaxf(fmaf(a, h, t), 0.f);
    xr[i] = x1;
    float n2 = x1*x1;
    #pragma unroll
    for (int off = 32; off > 0; off >>= 1) n2 += __shfl_xor(n2, off);
    if (c == 0) xx1[p] = n2;
    float n1 = fmaxf(sqrtf(n2), 1e-15f);
    float th = tanhf(0.1f * n1);
    float sc = th / (0.1f * n1);
    float ny = fmaxf(th * 10.0f, 1e-15f);
    float mxn = (1.0f - 4e-3f) / 0.1f;
    if (ny > mxn) sc *= mxn / ny;
    xp2[(size_t)p*64 + c] = sc * x1;
  }
  float* dst = x1T + ((size_t)(b*64 + c))*1024 + n0;
  #pragma unroll
  for (int q = 0; q < 4; q++) {
    float4 v; v.x = xr[q*4]; v.y = xr[q*4+1]; v.z = xr[q*4+2]; v.w = xr[q*4+3];
    *((float4*)(dst + q*4)) = v;
  }
}

// ---------- 6) knn2 v7: 4-way split, packed-u32 selection, Bs prefetch, XCD-affine swizzle ----------
__global__ void __launch_bounds__(256) k_knn2g(const float* __restrict__ x1T,
        const float* __restrict__ xx1, unsigned* __restrict__ keypart2) {
  __shared__ __align__(16) float SM[8192];   // As @0 (64x64), BsD @4096 (64x64)
  float* As = SM;
  float* BsD = SM + 4096;
  int tid = threadIdx.x;
  int bi = blockIdx.x;
  int blk = ((bi & 7) << 7) + (bi >> 3);
  int b = blk >> 6, qc = (blk >> 2) & 15, cc = blk & 3;
  int qbase = qc*64, ccbase = cc*256;
  int tx = tid & 15, ty = tid >> 4;
  int wave = tid >> 6, lane = tid & 63;
  #pragma unroll
  for (int r = 0; r < 4; r++) {
    int e = tid + r*256;
    int k = e >> 4, qf = e & 15;
    *((float4*)(As + k*64 + qf*4)) =
      *((const float4*)(x1T + ((size_t)(b*64 + k))*1024 + qbase + qf*4));
  }
  float4 breg[4];
  #pragma unroll
  for (int r = 0; r < 4; r++) {
    int e = tid + r*256;
    int k = e >> 4, cf = e & 15;
    breg[r] = *((const float4*)(x1T + ((size_t)(b*64 + k))*1024 + ccbase + cf*4));
  }
  float4 xxcreg = *((const float4*)(xx1 + b*1024 + ccbase + ty*4));
  unsigned kl[KNN];
  #pragma unroll
  for (int i = 0; i < KNN; i++) kl[i] = 0u;
  int cq = lane + (lane >> 2);

  for (int st = 0; st < 4; ++st) {
    int cb0 = ccbase + st*64;
    __syncthreads();
    #pragma unroll
    for (int r = 0; r < 4; r++) {
      int e = tid + r*256;
      int k = e >> 4, cf = e & 15;
      *((float4*)(BsD + k*64 + cf*4)) = breg[r];
    }
    float4 xxc = xxcreg;
    if (st < 3) {
      int cb1 = cb0 + 64;
      #pragma unroll
      for (int r = 0; r < 4; r++) {
        int e = tid + r*256;
        int k = e >> 4, cf = e & 15;
        breg[r] = *((const float4*)(x1T + ((size_t)(b*64 + k))*1024 + cb1 + cf*4));
      }
      xxcreg = *((const float4*)(xx1 + b*1024 + cb1 + ty*4));
    }
    __syncthreads();
    float acc[4][4];
    #pragma unroll
    for (int i = 0; i < 4; i++)
      #pragma unroll
      for (int j = 0; j < 4; j++) acc[i][j] = 0.f;
    #pragma unroll 4
    for (int k = 0; k < 64; k++) {
      float4 a4 = *((const float4*)(As + k*64 + tx*4));
      float4 b4 = *((const float4*)(BsD + k*64 + ty*4));
      float av[4] = {a4.x, a4.y, a4.z, a4.w};
      float bw[4] = {b4.x, b4.y, b4.z, b4.w};
      #pragma unroll
      for (int i = 0; i < 4; i++)
        #pragma unroll
        for (int j = 0; j < 4; j++) acc[i][j] = fmaf(av[i], bw[j], acc[i][j]);
    }
    __syncthreads();
    float xxv[4] = {xxc.x, xxc.y, xxc.z, xxc.w};
    #pragma unroll
    for (int i = 0; i < 4; i++) {
      int q = tx*4 + i;
      #pragma unroll
      for (int j = 0; j < 4; j++) {
        int c = ty*4 + j;
        BsD[q*64 + ((c + q + (q >> 2)) & 63)] = 2.0f*acc[i][j] - xxv[j];
      }
    }
    __syncthreads();
    #pragma unroll
    for (int j = 0; j < 16; j++) {
      int c = wave*16 + j;
      float d = BsD[lane*64 + ((c + cq) & 63)];
      unsigned nk = knnkey(d, cb0 + c);
      if (nk > kl[KNN-1]) topk_insert_u32(kl, nk);
    }
  }
  __syncthreads();
  unsigned* U = (unsigned*)SM;
  unsigned* L0 = U;
  unsigned* L1 = U + 1344;
  unsigned* M  = U + 2688;
  if (wave == 0) {
    #pragma unroll
    for (int i = 0; i < KNN; i++) L0[lane*21 + i] = kl[i];
  } else if (wave == 1) {
    #pragma unroll
    for (int i = 0; i < KNN; i++) L1[lane*21 + i] = kl[i];
  }
  __syncthreads();
  if (tid < 64) {
    int ia = 0, ib = 0;
    for (int t = 0; t < KNN; t++) {
      unsigned pa = L0[tid*21 + ia], pb = L1[tid*21 + ib];
      bool ta = pa > pb;
      M[tid*21 + t] = ta ? pa : pb;
      if (ta) ia++; else ib++;
    }
  }
  __syncthreads();
  if (wave == 2) {
    #pragma unroll
    for (int i = 0; i < KNN; i++) L0[lane*21 + i] = kl[i];
  } else if (wave == 3) {
    #pragma unroll
    for (int i = 0; i < KNN; i++) L1[lane*21 + i] = kl[i];
  }
  __syncthreads();
  if (tid < 64) {
    int p = b*N_ + qbase + tid;
    unsigned* pe = keypart2 + (size_t)p*80 + cc*20;
    int ia = 0, ib = 0, im = 0;
    for (int t = 0; t < KNN; t++) {
      unsigned pa = L0[tid*21 + ia], pb = L1[tid*21 + ib], pm = M[tid*21 + im];
      unsigned bp = pm; int sel = 2;
      if (pa > bp) { bp = pa; sel = 0; }
      if (pb > bp) { bp = pb; sel = 1; }
      pe[t] = bp;
      if (sel == 0) ia++; else if (sel == 1) ib++; else im++;
    }
  }
}

// ---------- 9) conv2 via bf16 MFMA v6: LDS-staged merge + XCD swizzle + register epilogue ----------
__global__ void __launch_bounds__(256) k_conv2m(const float* __restrict__ xp2,
    const unsigned* __restrict__ keypart2, const unsigned short* __restrict__ w2h,
    float* __restrict__ hmax2, float* __restrict__ hmin2, double* __restrict__ stats2sh) {
  __shared__ __align__(16) short Abf[80*136];
  __shared__ float s1s[80], s2s[80];
  __shared__ int nbr[80];                        // logical order [pt*20 + k]
  __shared__ unsigned keybuf[320];               // 4 pairs x 80 keys
  int tid = threadIdx.x;
  int bi = blockIdx.x;
  int g512 = ((bi & 7) << 9) + (bi >> 3);
  int p0 = g512 * 4;
  int b = p0 >> 10;
  // bulk coalesced stage of merge inputs (strided: 320 > 256 threads!)
  for (int e = tid; e < 320; e += 256) keybuf[e] = keypart2[(size_t)p0*80 + e];
  __syncthreads();
  if (tid < 4) {
    const unsigned* pe = keybuf + tid*80;
    int pos[4];
    #pragma unroll
    for (int c = 0; c < 4; c++) pos[c] = 0;
    for (int t = 0; t < KNN; t++) {
      unsigned best = 0u; int bc = 0;
      #pragma unroll
      for (int c = 0; c < 4; c++) {
        if (pos[c] < KNN) {
          unsigned v = pe[c*20 + pos[c]];
          if (v > best) { best = v; bc = c; }
        }
      }
      nbr[tid*20 + t] = 1023 - (int)(best & 1023u);
      #pragma unroll
      for (int c = 0; c < 4; c++) if (bc == c) pos[c]++;
    }
  }
  __syncthreads();
  for (int e = tid; e < 80*16; e += 256) {
    int r = e >> 4, qq = e & 15;
    int q = (r >> 2) & 3;
    int L = 20*q + 4*(r >> 4) + (r & 3);
    float4 f = *((const float4*)(xp2 + (size_t)(b*N_ + nbr[L])*64) + qq);
    float4 cv = *((const float4*)(xp2 + (size_t)(p0 + q)*64) + qq);
    ushort4 fb, cb;
    fb.x = f2bf(f.x); fb.y = f2bf(f.y); fb.z = f2bf(f.z); fb.w = f2bf(f.w);
    cb.x = f2bf(cv.x); cb.y = f2bf(cv.y); cb.z = f2bf(cv.z); cb.w = f2bf(cv.w);
    *((ushort4*)(Abf + r*136 + qq*4)) = fb;
    *((ushort4*)(Abf + r*136 + 64 + qq*4)) = cb;
  }
  __syncthreads();
  if (tid < 160) {
    int r = tid >> 1, h = tid & 1;
    const unsigned short* Ar = (const unsigned short*)(Abf + r*136) + h*32;
    const unsigned short* Xr = (const unsigned short*)(Abf + r*136 + 64) + h*32;
    float X2 = 0.f, XY = 0.f, Y2 = 0.f;
    for (int c2 = 0; c2 < 32; c2++) {
      float f = bf2f(Ar[c2]), xcv = bf2f(Xr[c2]);
      X2 = fmaf(f, f, X2); XY = fmaf(-f, xcv, XY); Y2 = fmaf(xcv, xcv, Y2);
    }
    X2 += __shfl_xor(X2, 1); XY += __shfl_xor(XY, 1); Y2 += __shfl_xor(Y2, 1);
    if (h == 0) {
      float den = fmaxf(1.0f + 0.02f*XY + 1e-4f*X2*Y2, 1e-15f);
      s1s[r] = (1.0f + 0.02f*XY + 0.01f*Y2) / den;
      s2s[r] = (1.0f - 0.01f*X2) / den;
    }
  }
  __syncthreads();
  for (int e = tid; e < 80*16; e += 256) {
    int r = e >> 4, qq = e & 15;
    ushort4 fr = *((const ushort4*)(Abf + r*136 + qq*4));
    ushort4 xr4 = *((const ushort4*)(Abf + r*136 + 64 + qq*4));
    float s1 = s1s[r], s2 = s2s[r];
    ushort4 mo;
    mo.x = f2bf(s1*bf2f(fr.x) - s2*bf2f(xr4.x));
    mo.y = f2bf(s1*bf2f(fr.y) - s2*bf2f(xr4.y));
    mo.z = f2bf(s1*bf2f(fr.z) - s2*bf2f(xr4.z));
    mo.w = f2bf(s1*bf2f(fr.w) - s2*bf2f(xr4.w));
    *((ushort4*)(Abf + r*136 + qq*4)) = mo;
  }
  __syncthreads();
  int wave = tid >> 6, lane = tid & 63;
  int quad = lane >> 4, lm = lane & 15;
  int colbase = wave*48;
  f32x4 acc[5][3];
  #pragma unroll
  for (int rt = 0; rt < 5; rt++)
    #pragma unroll
    for (int cj = 0; cj < 3; cj++) acc[rt][cj] = (f32x4){0.f, 0.f, 0.f, 0.f};
  #pragma unroll
  for (int kt = 0; kt < 4; kt++) {
    int k0 = kt*32 + quad*8;
    bf16x8 bf[3];
    #pragma unroll
    for (int cj = 0; cj < 3; cj++)
      bf[cj] = *((const bf16x8*)(w2h + (size_t)(colbase + cj*16 + lm)*128 + k0));
    bf16x8 af[5];
    #pragma unroll
    for (int rt = 0; rt < 5; rt++)
      af[rt] = *((const bf16x8*)(Abf + (rt*16 + lm)*136 + k0));
    #pragma unroll
    for (int rt = 0; rt < 5; rt++)
      #pragma unroll
      for (int cj = 0; cj < 3; cj++)
        acc[rt][cj] = __builtin_amdgcn_mfma_f32_16x16x32_bf16(af[rt], bf[cj], acc[rt][cj], 0, 0, 0);
  }
  #pragma unroll
  for (int cj = 0; cj < 3; cj++) {
    int o = colbase + cj*16 + lm;
    float s = 0.f, s2 = 0.f, mx = -__builtin_inff(), mn = __builtin_inff();
    #pragma unroll
    for (int rt = 0; rt < 5; rt++) {
      #pragma unroll
      for (int reg = 0; reg < 4; reg++) {
        float h = acc[rt][cj][reg];
        s += h; s2 += h*h;
        mx = fmaxf(mx, h); mn = fminf(mn, h);
      }
    }
    hmax2[(size_t)(p0 + quad)*192 + o] = mx;
    hmin2[(size_t)(p0 + quad)*192 + o] = mn;
    s  += __shfl_xor(s, 16);  s  += __shfl_xor(s, 32);
    s2 += __shfl_xor(s2, 16); s2 += __shfl_xor(s2, 32);
    if (lane < 16) {
      double* dst = stats2sh + ((size_t)(bi & 63)*192 + o)*2;
      atomicAdd(dst, (double)s); atomicAdd(dst + 1, (double)s2);
    }
  }
}

// ---------- 11) conv3 via bf16 MFMA, A-tile staged directly from BN1/BN2 max/min ----------
__global__ void __launch_bounds__(256) k_conv3m(
   const float* __restrict__ hmax1, const float* __restrict__ hmin1,
   const float* __restrict__ scale1, const float* __restrict__ shift1,
   const float* __restrict__ hmax2, const float* __restrict__ hmin2,
   const float* __restrict__ scale2, const float* __restrict__ shift2,
   const unsigned short* __restrict__ wt3h, double* __restrict__ stats3sh,
   unsigned* __restrict__ hmax3u, unsigned* __restrict__ hmin3u) {
  __shared__ short As[64*264];
  int tid = threadIdx.x;
  int mt = blockIdx.x >> 2, cb = blockIdx.x & 3;
  int rowbase = mt*64;
  int b = rowbase >> 10;
  int c4 = tid & 63;
  float4 sc, sh;
  if (c4 < 16) {
    sc = *((const float4*)(scale1 + c4*4));
    sh = *((const float4*)(shift1 + c4*4));
  } else {
    sc = *((const float4*)(scale2 + (c4*4 - 64)));
    sh = *((const float4*)(shift2 + (c4*4 - 64)));
  }
  #pragma unroll 4
  for (int i = 0; i < 16; i++) {
    int r = (tid >> 6) + i*4;
    int p = rowbase + r;
    float4 hx, hn;
    if (c4 < 16) {
      hx = *((const float4*)(hmax1 + (size_t)p*64 + c4*4));
      hn = *((const float4*)(hmin1 + (size_t)p*64 + c4*4));
    } else {
      hx = *((const float4*)(hmax2 + (size_t)p*192 + (c4*4 - 64)));
      hn = *((const float4*)(hmin2 + (size_t)p*192 + (c4*4 - 64)));
    }
    ushort4 o4;
    o4.x = f2bf(fmaxf(fmaf(sc.x, (sc.x >= 0.f ? hx.x : hn.x), sh.x), 0.f));
    o4.y = f2bf(fmaxf(fmaf(sc.y, (sc.y >= 0.f ? hx.y : hn.y), sh.y), 0.f));
    o4.z = f2bf(fmaxf(fmaf(sc.z, (sc.z >= 0.f ? hx.z : hn.z), sh.z), 0.f));
    o4.w = f2bf(fmaxf(fmaf(sc.w, (sc.w >= 0.f ? hx.w : hn.w), sh.w), 0.f));
    *((ushort4*)(As + r*264 + c4*4)) = o4;
  }
  __syncthreads();
  int wave = tid >> 6, lane = tid & 63;
  int quad = lane >> 4, lm = lane & 15;
  int colbase = cb*256 + wave*64;
  f32x4 acc[4][4];
  #pragma unroll
  for (int ri = 0; ri < 4; ri++)
    #pragma unroll
    for (int cj = 0; cj < 4; cj++) acc[ri][cj] = (f32x4){0.f, 0.f, 0.f, 0.f};
  for (int kt = 0; kt < 8; kt++) {
    int k0 = kt*32 + quad*8;
    bf16x8 bf[4];
    #pragma unroll
    for (int cj = 0; cj < 4; cj++)
      bf[cj] = *((const bf16x8*)(wt3h + (size_t)(colbase + cj*16 + lm)*256 + k0));
    bf16x8 af[4];
    #pragma unroll
    for (int ri = 0; ri < 4; ri++)
      af[ri] = *((const bf16x8*)(As + (ri*16 + lm)*264 + k0));
    #pragma unroll
    for (int ri = 0; ri < 4; ri++)
      #pragma unroll
      for (int cj = 0; cj < 4; cj++)
        acc[ri][cj] = __builtin_amdgcn_mfma_f32_16x16x32_bf16(af[ri], bf[cj], acc[ri][cj], 0, 0, 0);
  }
  #pragma unroll
  for (int cj = 0; cj < 4; cj++) {
    float s = 0.f, s2 = 0.f, mx = -__builtin_inff(), mn = __builtin_inff();
    #pragma unroll
    for (int ri = 0; ri < 4; ri++) {
      #pragma unroll
      for (int reg = 0; reg < 4; reg++) {
        float h = acc[ri][cj][reg];
        s += h; s2 += h*h; mx = fmaxf(mx, h); mn = fminf(mn, h);
      }
    }
    s  += __shfl_xor(s, 16);  s  += __shfl_xor(s, 32);
    s2 += __shfl_xor(s2, 16); s2 += __shfl_xor(s2, 32);
    mx = fmaxf(mx, __shfl_xor(mx, 16)); mx = fmaxf(mx, __shfl_xor(mx, 32));
    mn = fminf(mn, __shfl_xor(mn, 16)); mn = fminf(mn, __shfl_xor(mn, 32));
    if (lane < 16) {
      int col = colbase + cj*16 + lane;
      double* dst = stats3sh + ((size_t)(blockIdx.x & 63)*1024 + col)*2;
      atomicAdd(dst, (double)s);
      atomicAdd(dst + 1, (double)s2);
      atomicMax(hmax3u + b*1024 + col, fkey(mx));
      atomicMin(hmin3u + b*1024 + col, fkey(mn));
    }
  }
}

// ---------- 12) head, split for weight-read parallelism ----------
__device__ float blk_reduce(float v, float* red, int tid) {
  red[tid] = v; __syncthreads();
  for (int st = 128; st > 0; st >>= 1) {
    if (tid < st) red[tid] += red[tid + st];
    __syncthreads();
  }
  float r = red[0]; __syncthreads();
  return r;
}

__global__ void __launch_bounds__(256) k_head1(const unsigned* __restrict__ hmax3u,
    const unsigned* __restrict__ hmin3u,
    const float* __restrict__ scale3, const float* __restrict__ shift3,
    const float* __restrict__ fc1w, const float* __restrict__ fc1b,
    float* __restrict__ h1buf) {
  __shared__ __align__(16) float V[1024];
  int b = blockIdx.x >> 5, oc = blockIdx.x & 31;
  int tid = threadIdx.x;
  for (int o = tid; o < 1024; o += 256) {
    float a = scale3[o];
    unsigned u = (a >= 0.f) ? hmax3u[b*1024 + o] : hmin3u[b*1024 + o];
    V[o] = fmaxf(fmaf(a, fkeyinv(u), shift3[o]), 0.f);
  }
  __syncthreads();
  int ty = tid >> 4, tx = tid & 15;
  int o = oc*16 + ty;
  const float4* wr = (const float4*)(fc1w + (size_t)o*1024) + tx*16;
  const float4* vv = (const float4*)V + tx*16;
  float s = 0.f;
  #pragma unroll
  for (int i = 0; i < 16; i++) {
    float4 w = wr[i]; float4 v = vv[i];
    s = fmaf(w.x, v.x, s); s = fmaf(w.y, v.y, s);
    s = fmaf(w.z, v.z, s); s = fmaf(w.w, v.w, s);
  }
  s += __shfl_xor(s, 1); s += __shfl_xor(s, 2);
  s += __shfl_xor(s, 4); s += __shfl_xor(s, 8);
  if (tx == 0) h1buf[b*512 + o] = s + fc1b[o];
}

__global__ void __launch_bounds__(256) k_head2(const float* __restrict__ h1buf,
    const float* __restrict__ ln1g, const float* __restrict__ ln1b,
    const float* __restrict__ fc2w, const float* __restrict__ fc2b,
    float* __restrict__ h2buf) {
  __shared__ __align__(16) float H1[512];
  __shared__ float red[256];
  int b = blockIdx.x >> 3, oc = blockIdx.x & 7;
  int tid = threadIdx.x;
  float v0 = h1buf[b*512 + tid], v1 = h1buf[b*512 + 256 + tid];
  float s = blk_reduce(v0 + v1, red, tid);
  float s2 = blk_reduce(v0*v0 + v1*v1, red, tid);
  float m = s / 512.f;
  float var = s2 / 512.f - m*m;
  float inv = 1.0f / sqrtf(var + 1e-5f);
  H1[tid] = fmaxf((v0 - m)*inv*ln1g[tid] + ln1b[tid], 0.f);
  H1[256 + tid] = fmaxf((v1 - m)*inv*ln1g[256 + tid] + ln1b[256 + tid], 0.f);
  __syncthreads();
  int ty = tid >> 3, tx = tid & 7;
  int o = oc*32 + ty;
  const float4* wr = (const float4*)(fc2w + (size_t)o*512) + tx*16;
  const float4* vv = (const float4*)H1 + tx*16;
  float t = 0.f;
  #pragma unroll
  for (int i = 0; i < 16; i++) {
    float4 w = wr[i]; float4 v = vv[i];
    t = fmaf(w.x, v.x, t); t = fmaf(w.y, v.y, t);
    t = fmaf(w.z, v.z, t); t = fmaf(w.w, v.w, t);
  }
  t += __shfl_xor(t, 1); t += __shfl_xor(t, 2); t += __shfl_xor(t, 4);
  if (tx == 0) h2buf[b*256 + o] = t + fc2b[o];
}

__global__ void __launch_bounds__(256) k_head3(const float* __restrict__ h2buf,
    const float* __restrict__ ln2g, const float* __restrict__ ln2b,
    const float* __restrict__ outw, const float* __restrict__ outb,
    float* __restrict__ out) {
  __shared__ __align__(16) float H2[256];
  __shared__ float red[256];
  int b = blockIdx.x, tid = threadIdx.x;
  float h2v = h2buf[b*256 + tid];
  float ss = blk_reduce(h2v, red, tid);
  float ss2 = blk_reduce(h2v*h2v, red, tid);
  float m2 = ss / 256.f;
  float var2 = ss2 / 256.f - m2*m2;
  float inv2 = 1.0f / sqrtf(var2 + 1e-5f);
  H2[tid] = fmaxf((h2v - m2)*inv2*ln2g[tid] + ln2b[tid], 0.f);
  __syncthreads();
  if (tid < 40) {
    const float4* wr = (const float4*)(outw + (size_t)tid*256);
    float t = 0.f;
    for (int c4 = 0; c4 < 64; c4++) {
      float4 w = wr[c4]; float4 vv = ((const float4*)H2)[c4];
      t = fmaf(w.x, vv.x, t); t = fmaf(w.y, vv.y, t);
      t = fmaf(w.z, vv.z, t); t = fmaf(w.w, vv.w, t);
    }
    red[tid] = t + outb[tid];
  }
  __syncthreads();
  if (tid == 0) {
    float mx = -__builtin_inff();
    for (int i2 = 0; i2 < 40; i2++) mx = fmaxf(mx, red[i2]);
    float se = 0.f;
    for (int i2 = 0; i2 < 40; i2++) se += expf(red[i2] - mx);
    float lse = mx + logf(se);
    for (int i2 = 0; i2 < 40; i2++) out[b*40 + i2] = red[i2] - lse;
  }
}

extern "C" void kernel_launch(void* const* d_in, const int* in_sizes, int n_in,
                              void* d_out, int out_size, void* d_ws, size_t ws_size,
                              hipStream_t stream) {
  (void)in_sizes; (void)n_in; (void)out_size; (void)ws_size;
  const float* x    = (const float*)d_in[0];
  const float* w1   = (const float*)d_in[1];
  const float* bn1g = (const float*)d_in[2];
  const float* bn1b = (const float*)d_in[3];
  const float* w2   = (const float*)d_in[4];
  const float* bn2g = (const float*)d_in[5];
  const float* bn2b = (const float*)d_in[6];
  const float* w3   = (const float*)d_in[7];
  const float* bn3g = (const float*)d_in[8];
  const float* bn3b = (const float*)d_in[9];
  const float* fc1w = (const float*)d_in[10];
  const float* fc1b = (const float*)d_in[11];
  const float* ln1g = (const float*)d_in[12];
  const float* ln1b = (const float*)d_in[13];
  const float* fc2w = (const float*)d_in[14];
  const float* fc2b = (const float*)d_in[15];
  const float* ln2g = (const float*)d_in[16];
  const float* ln2b = (const float*)d_in[17];
  const float* outw = (const float*)d_in[18];
  const float* outb = (const float*)d_in[19];
  float* out = (float*)d_out;

  float* ws = (float*)d_ws;
  size_t off = 0;
  float* xp1   = ws + off; off += 49152;
  float* hmax1 = ws + off; off += 1048576;
  float* hmin1 = ws + off; off += 1048576;
  float* xp2   = ws + off; off += 1048576;
  float* hmax2 = ws + off; off += 3145728;   // also keypartA (knn1 partials, 160/pt)
  float* hmin2 = ws + off; off += 3145728;
  unsigned* keypart2 = (unsigned*)(ws + off); off += 1310720;  // knn2 partials, 80/pt
  unsigned short* w2h = (unsigned short*)(ws + off); off += 24576;
  unsigned short* wt3h = (unsigned short*)(ws + off); off += 131072;
  float* x1T   = ws + off; off += 1048576;
  float* xx1   = ws + off; off += 16384;
  float* h1buf = ws + off; off += 8192;
  float* h2buf = ws + off; off += 4096;
  float* scale1 = ws + off; off += 64;
  float* shift1 = ws + off; off += 64;
  float* scale2 = ws + off; off += 192;
  float* shift2 = ws + off; off += 192;
  float* scale3 = ws + off; off += 1024;
  float* shift3 = ws + off; off += 1024;
  double* stats1sh = (double*)(ws + off);
  double* stats2sh = stats1sh + 64*64*2;
  double* stats3sh = stats2sh + 64*192*2;
  unsigned* hmax3u = (unsigned*)(stats3sh + (size_t)64*1024*2);
  unsigned* hmin3u = hmax3u + 16384;
  unsigned* keypartA = (unsigned*)hmax2;

  size_t zero_bytes = ((size_t)64*64*2 + (size_t)64*192*2 + (size_t)64*1024*2)*8 + (size_t)16384*4;
  hipMemsetAsync(stats1sh, 0, zero_bytes, stream);
  hipMemsetAsync(hmin3u, 0xFF, (size_t)16384*4, stream);

  k_prep_knn1<<<1536, 256, 0, stream>>>(x, xp1, w2, w3, w2h, wt3h, keypartA);
  k_conv1<<<1024, 256, 0, stream>>>(xp1, keypartA, w1, hmax1, hmin1, stats1sh);
  k_bn_reduce<<<64, 64, 0, stream>>>(stats1sh, 64, 327680.0, bn1g, bn1b, scale1, shift1);
  k_bn1_apply<<<256, 256, 0, stream>>>(hmax1, hmin1, scale1, shift1, xp2, x1T, xx1);
  k_knn2g<<<1024, 256, 0, stream>>>(x1T, xx1, keypart2);
  k_conv2m<<<4096, 256, 0, stream>>>(xp2, keypart2, w2h, hmax2, hmin2, stats2sh);
  k_bn_reduce<<<192, 64, 0, stream>>>(stats2sh, 192, 327680.0, bn2g, bn2b, scale2, shift2);
  k_conv3m<<<1024, 256, 0, stream>>>(hmax1, hmin1, scale1, shift1, hmax2, hmin2, scale2, shift2,
                                     wt3h, stats3sh, hmax3u, hmin3u);
  k_bn_reduce<<<1024, 64, 0, stream>>>(stats3sh, 1024, 16384.0, bn3g, bn3b, scale3, shift3);
  k_head1<<<512, 256, 0, stream>>>(hmax3u, hmin3u, scale3, shift3, fc1w, fc1b, h1buf);
  k_head2<<<128, 256, 0, stream>>>(h1buf, ln1g, ln1b, fc2w, fc2b, h2buf);
  k_head3<<<16, 256, 0, stream>>>(h2buf, ln2g, ln2b, outw, outb, out);
}